// Round 5
// baseline (370.550 us; speedup 1.0000x reference)
//
#include <hip/hip_runtime.h>
#include <hip/hip_bf16.h>
#include <math.h>

// Problem constants
#define BB 4
#define TT 1024
#define CCH 1024
#define HH 16
#define NNd 64
#define PAD 65      // fp32 LDS row pad (chunk_scan/outgn)
#define RS 72       // bf16 LDS row stride in shorts (144B = 9x16B, frag-aligned)
#define LBS 68      // bf16 L-matrix row stride in shorts (136B, 8B-aligned u4)

typedef short bf16x8 __attribute__((ext_vector_type(8)));
typedef float f32x4 __attribute__((ext_vector_type(4)));

__device__ __forceinline__ unsigned short f2bf(float f) {
  __hip_bfloat16 h = __float2bfloat16(f);
  return __builtin_bit_cast(unsigned short, h);
}
__device__ __forceinline__ float bf2f(unsigned short u) {
  unsigned int x = (unsigned int)u << 16;
  return __builtin_bit_cast(float, x);
}
// Native transcendentals: outputs all round through bf16 downstream, so
// v_exp/v_rcp/v_rsq (~1 ulp) precision is far below bf16 quantization.
__device__ __forceinline__ float sigmoidf_(float x) {
  return __builtin_amdgcn_rcpf(1.0f + __expf(-x));
}
__device__ __forceinline__ float ftanh_(float x) {
  // tanh(x) = 1 - 2/(e^{2x}+1); saturates correctly at +/-inf.
  return 1.0f - 2.0f * __builtin_amdgcn_rcpf(__expf(2.0f * x) + 1.0f);
}

// async global->LDS, 16B per lane; LDS dest must be wave-uniform base + 16*lane
__device__ __forceinline__ void gl2lds16(const unsigned short* g, unsigned short* l) {
  __builtin_amdgcn_global_load_lds(
      (const __attribute__((address_space(1))) unsigned int*)g,
      (__attribute__((address_space(3))) unsigned int*)l, 16, 0, 0);
}

// ---------------------------------------------------------------------------
// Transpose tile helper
// ---------------------------------------------------------------------------
__device__ __forceinline__ void transpose_tile(
    const float* __restrict__ in, unsigned short* __restrict__ out,
    int R, int Cc, int r0, int c0, unsigned short (*tile)[68], int t)
{
  const int rr = t >> 4;
  const int cc = (t & 15) * 4;
#pragma unroll
  for (int p = 0; p < 4; ++p) {
    int row = p * 16 + rr;
    float4 v = *(const float4*)(in + (size_t)(r0 + row) * Cc + c0 + cc);
    tile[row][cc]     = f2bf(v.x);
    tile[row][cc + 1] = f2bf(v.y);
    tile[row][cc + 2] = f2bf(v.z);
    tile[row][cc + 3] = f2bf(v.w);
  }
  __syncthreads();
#pragma unroll
  for (int p = 0; p < 4; ++p) {
    int row = p * 16 + rr;
    ushort4 o;
    o.x = tile[cc][row];
    o.y = tile[cc + 1][row];
    o.z = tile[cc + 2][row];
    o.w = tile[cc + 3][row];
    *(ushort4*)(out + (size_t)(c0 + row) * R + r0 + cc) = o;
  }
}

// ---------------------------------------------------------------------------
// prep_kernel (v4): weight transposes ONLY. Token-shift mix is fused into
// gemm_stage1's A-staging (saves ~70 MB of HBM round-trip + 4096 blocks).
// blocks 0..1023 = big4 transposes, 1024..1151 = lora transposes.
// ---------------------------------------------------------------------------
__global__ __launch_bounds__(256) void prep_kernel(
    const float* __restrict__ W0, const float* __restrict__ W1,
    const float* __restrict__ W2, const float* __restrict__ W3,
    unsigned short* __restrict__ T0, unsigned short* __restrict__ T1,
    unsigned short* __restrict__ T2, unsigned short* __restrict__ T3,
    const float* __restrict__ w1, const float* __restrict__ w2,
    const float* __restrict__ a1, const float* __restrict__ a2,
    const float* __restrict__ g1, const float* __restrict__ g2,
    unsigned short* __restrict__ w1T, unsigned short* __restrict__ w2T,
    unsigned short* __restrict__ a1T, unsigned short* __restrict__ a2T,
    unsigned short* __restrict__ g1T, unsigned short* __restrict__ g2T)
{
  __shared__ unsigned short tile[64][68];
  const int blk = blockIdx.x;
  const int tid = threadIdx.x;
  if (blk < 1024) {
    const int z = blk >> 8, rem = blk & 255;
    const int ty = rem >> 4, tx = rem & 15;
    const float* src = (z == 0) ? W0 : (z == 1) ? W1 : (z == 2) ? W2 : W3;
    unsigned short* dst = (z == 0) ? T0 : (z == 1) ? T1 : (z == 2) ? T2 : T3;
    transpose_tile(src, dst, 1024, 1024, tx * 64, ty * 64, tile, tid);
  } else {
    const int i = blk - 1024;
    const float* src; unsigned short* dst; int R, C, rt, ct;
    if (i < 16)      { src = w1; dst = w1T; R = 1024; C = 64;   rt = i;      ct = 0; }
    else if (i < 32) { src = w2; dst = w2T; R = 64;   C = 1024; rt = 0;      ct = i - 16; }
    else if (i < 48) { src = a1; dst = a1T; R = 1024; C = 64;   rt = i - 32; ct = 0; }
    else if (i < 64) { src = a2; dst = a2T; R = 64;   C = 1024; rt = 0;      ct = i - 48; }
    else if (i < 96) { int k = i - 64; src = g1; dst = g1T; R = 1024; C = 128; rt = k >> 1; ct = k & 1; }
    else             { int k = i - 96; src = g2; dst = g2T; R = 128; C = 1024; rt = k & 1;  ct = k >> 1; }
    transpose_tile(src, dst, R, C, rt * 64, ct * 64, tile, tid);
  }
}

// ---------------------------------------------------------------------------
// gemm_stage1 (v4): blocks 0..767 = r/k/v big GEMMs, 768..895 = lora1.
// Token-shift mix FUSED into A-staging: load x fp32 tile (+ row-shifted tile,
// L1-resident), fmaf-mix with per-z coef, ds_write bf16 into As. Bit-identical
// arithmetic to the old prep mix. B stays on global_load_lds.
// ---------------------------------------------------------------------------
__global__ __launch_bounds__(256) void gemm_stage1_kernel(
    const float* __restrict__ x,
    const float* __restrict__ cr, const float* __restrict__ ck,
    const float* __restrict__ cv,
    const unsigned short* __restrict__ WrT, const unsigned short* __restrict__ WkT,
    const unsigned short* __restrict__ WvT,
    unsigned short* __restrict__ r_btc, unsigned short* __restrict__ k_btc,
    float* __restrict__ v_btc,
    const float* __restrict__ cw, const float* __restrict__ ca,
    const float* __restrict__ cg,
    const unsigned short* __restrict__ w1T, const unsigned short* __restrict__ a1T,
    const unsigned short* __restrict__ g1T,
    unsigned short* __restrict__ hwB, unsigned short* __restrict__ haB,
    unsigned short* __restrict__ hgB)
{
  constexpr int K = 1024, SK = 32;
  __shared__ __align__(16) unsigned short As[128 * SK];
  __shared__ __align__(16) unsigned short Bs[128 * SK];
  const int blk = blockIdx.x;
  const int tid = threadIdx.x;
  const int wv = tid >> 6, lane = tid & 63;
  const int fr = lane & 15, q = lane >> 4;
  const int arow = tid >> 2;          // 0..63 (row within half-tile)
  const int kc = (tid & 3) * 8;       // col offset (elems) within 32-wide K-slab

  // fused token-shift mix A-staging: A[m][k] = fmaf(x[m-1][k]-x[m][k], coef[k], x[m][k])
  auto stageA = [&](const float* __restrict__ coef, int m0, int k0) {
    const int kk = k0 + kc;
    float4 cA = *(const float4*)(coef + kk);
    float4 cB = *(const float4*)(coef + kk + 4);
#pragma unroll
    for (int i = 0; i < 2; ++i) {
      const int m = m0 + arow + i * 64;
      const float* xc = x + (size_t)m * 1024 + kk;
      float4 a0 = *(const float4*)(xc);
      float4 a1 = *(const float4*)(xc + 4);
      float4 p0 = make_float4(0.f, 0.f, 0.f, 0.f), p1 = p0;
      if ((m & 1023) != 0) {      // first token of each sequence has xp = 0
        p0 = *(const float4*)(xc - 1024);
        p1 = *(const float4*)(xc - 1020);
      }
      bf16x8 ov;
      ov[0] = (short)f2bf(fmaf(p0.x - a0.x, cA.x, a0.x));
      ov[1] = (short)f2bf(fmaf(p0.y - a0.y, cA.y, a0.y));
      ov[2] = (short)f2bf(fmaf(p0.z - a0.z, cA.z, a0.z));
      ov[3] = (short)f2bf(fmaf(p0.w - a0.w, cA.w, a0.w));
      ov[4] = (short)f2bf(fmaf(p1.x - a1.x, cB.x, a1.x));
      ov[5] = (short)f2bf(fmaf(p1.y - a1.y, cB.y, a1.y));
      ov[6] = (short)f2bf(fmaf(p1.z - a1.z, cB.z, a1.z));
      ov[7] = (short)f2bf(fmaf(p1.w - a1.w, cB.w, a1.w));
      *(bf16x8*)(As + (size_t)(i * 64 + arow) * SK + kc) = ov;
    }
  };

  if (blk < 768) {
    // ---- big3 GEMM: z selects r/k/v ----
    const int z = blk >> 8, rem = blk & 255;
    const int m0 = (rem & 31) * 128;
    const int n0 = (rem >> 5) * 128;
    const float* coef = (z == 0) ? cr : (z == 1) ? ck : cv;
    const unsigned short* BT = (z == 0) ? WrT : (z == 1) ? WkT : WvT;
    const int wave_m = wv >> 1, wave_n = wv & 1;

    f32x4 acc[4][4];
#pragma unroll
    for (int i = 0; i < 4; i++)
#pragma unroll
      for (int j = 0; j < 4; j++) acc[i][j] = (f32x4){0.f, 0.f, 0.f, 0.f};

    for (int k0 = 0; k0 < K; k0 += 32) {
      stageA(coef, m0, k0);
#pragma unroll
      for (int i = 0; i < 2; ++i)
        gl2lds16(BT + (size_t)(n0 + arow + i * 64) * K + k0 + kc, Bs + i * 2048 + wv * 512);
      __syncthreads();
      bf16x8 af[4], bfv[4];
#pragma unroll
      for (int i = 0; i < 4; i++)
        af[i] = *(const bf16x8*)(&As[(wave_m * 64 + i * 16 + fr) * SK + q * 8]);
#pragma unroll
      for (int j = 0; j < 4; j++)
        bfv[j] = *(const bf16x8*)(&Bs[(wave_n * 64 + j * 16 + fr) * SK + q * 8]);
#pragma unroll
      for (int i = 0; i < 4; i++)
#pragma unroll
        for (int j = 0; j < 4; j++)
          acc[i][j] = __builtin_amdgcn_mfma_f32_16x16x32_bf16(af[i], bfv[j], acc[i][j], 0, 0, 0);
      __syncthreads();
    }
#pragma unroll
    for (int i = 0; i < 4; i++)
#pragma unroll
      for (int j = 0; j < 4; j++) {
        const int mb = m0 + wave_m * 64 + i * 16 + q * 4;
        const int n = n0 + wave_n * 64 + j * 16 + fr;
#pragma unroll
        for (int r = 0; r < 4; r++) {
          if (z == 0)      r_btc[(size_t)(mb + r) * 1024 + n] = f2bf(acc[i][j][r]);
          else if (z == 1) k_btc[(size_t)(mb + r) * 1024 + n] = f2bf(acc[i][j][r]);
          else             v_btc[(size_t)(mb + r) * 1024 + n] = acc[i][j][r];
        }
      }
  } else {
    // ---- lora1: y=0 hw=tanh, y=1 ha, y=2/3 hg sigmoid halves ----
    const int j2 = blk - 768;
    const int y = j2 >> 5;
    const int m0 = (j2 & 31) * 128;
    const float* coef = (y == 0) ? cw : (y == 1) ? ca : cg;
    const unsigned short* BT = (y == 0) ? w1T : (y == 1) ? a1T : (g1T + (size_t)(y - 2) * 64 * K);
    unsigned short* outb = (y == 0) ? hwB : (y == 1) ? haB : hgB;
    const int Nout = (y < 2) ? 64 : 128;
    const int ncol0 = (y < 2) ? 0 : (y - 2) * 64;

    f32x4 acc[2][4];
#pragma unroll
    for (int i = 0; i < 2; i++)
#pragma unroll
      for (int j = 0; j < 4; j++) acc[i][j] = (f32x4){0.f, 0.f, 0.f, 0.f};

    for (int k0 = 0; k0 < K; k0 += 32) {
      stageA(coef, m0, k0);
      gl2lds16(BT + (size_t)arow * K + k0 + kc, Bs + wv * 512);
      __syncthreads();
      bf16x8 af[2], bfv[4];
#pragma unroll
      for (int i = 0; i < 2; i++)
        af[i] = *(const bf16x8*)(&As[(wv * 32 + i * 16 + fr) * SK + q * 8]);
#pragma unroll
      for (int j = 0; j < 4; j++)
        bfv[j] = *(const bf16x8*)(&Bs[(j * 16 + fr) * SK + q * 8]);
#pragma unroll
      for (int i = 0; i < 2; i++)
#pragma unroll
        for (int j = 0; j < 4; j++)
          acc[i][j] = __builtin_amdgcn_mfma_f32_16x16x32_bf16(af[i], bfv[j], acc[i][j], 0, 0, 0);
      __syncthreads();
    }
#pragma unroll
    for (int i = 0; i < 2; i++)
#pragma unroll
      for (int j = 0; j < 4; j++) {
        const int mb = m0 + wv * 32 + i * 16 + q * 4;
        const int n = ncol0 + j * 16 + fr;
#pragma unroll
        for (int r = 0; r < 4; r++) {
          float val = acc[i][j][r];
          if (y == 0) val = ftanh_(val);
          else if (y >= 2) val = sigmoidf_(val);
          outb[(size_t)(mb + r) * Nout + n] = f2bf(val);
        }
      }
  }
}

// z-batched LoRA-2 GEMMs -> all bf16 outputs (wraw, araw, g).
__global__ __launch_bounds__(256) void lora2_kernel(
    const unsigned short* __restrict__ hwB, const unsigned short* __restrict__ haB,
    const unsigned short* __restrict__ hgB,
    const unsigned short* __restrict__ w2T, const unsigned short* __restrict__ a2T,
    const unsigned short* __restrict__ g2T,
    unsigned short* __restrict__ wraw, unsigned short* __restrict__ araw,
    unsigned short* __restrict__ gfB)
{
  constexpr int N = 1024, SK = 32;
  __shared__ __align__(16) unsigned short As[128 * SK];
  __shared__ __align__(16) unsigned short Bs[128 * SK];
  const int z = blockIdx.z;
  const unsigned short* A = (z == 0) ? hwB : (z == 1) ? haB : hgB;
  const unsigned short* BT = (z == 0) ? w2T : (z == 1) ? a2T : g2T;
  unsigned short* out = (z == 0) ? wraw : (z == 1) ? araw : gfB;
  const int K = (z == 2) ? 128 : 64;

  const int tid = threadIdx.x;
  const int wv = tid >> 6, lane = tid & 63;
  const int fr = lane & 15, q = lane >> 4;
  const int wave_m = wv >> 1, wave_n = wv & 1;
  const int m0 = blockIdx.x * 128;
  const int n0 = blockIdx.y * 128;

  f32x4 acc[4][4];
#pragma unroll
  for (int i = 0; i < 4; i++)
#pragma unroll
    for (int j = 0; j < 4; j++) acc[i][j] = (f32x4){0.f, 0.f, 0.f, 0.f};

  const int arow = tid >> 2;
  const int akc = (tid & 3) * 8;

  for (int k0 = 0; k0 < K; k0 += 32) {
#pragma unroll
    for (int i = 0; i < 2; ++i)
      gl2lds16(A + (size_t)(m0 + arow + i * 64) * K + k0 + akc, As + i * 2048 + wv * 512);
#pragma unroll
    for (int i = 0; i < 2; ++i)
      gl2lds16(BT + (size_t)(n0 + arow + i * 64) * K + k0 + akc, Bs + i * 2048 + wv * 512);
    __syncthreads();
    bf16x8 af[4], bfv[4];
#pragma unroll
    for (int i = 0; i < 4; i++)
      af[i] = *(const bf16x8*)(&As[(wave_m * 64 + i * 16 + fr) * SK + q * 8]);
#pragma unroll
    for (int j = 0; j < 4; j++)
      bfv[j] = *(const bf16x8*)(&Bs[(wave_n * 64 + j * 16 + fr) * SK + q * 8]);
#pragma unroll
    for (int i = 0; i < 4; i++)
#pragma unroll
      for (int j = 0; j < 4; j++)
        acc[i][j] = __builtin_amdgcn_mfma_f32_16x16x32_bf16(af[i], bfv[j], acc[i][j], 0, 0, 0);
    __syncthreads();
  }
#pragma unroll
  for (int i = 0; i < 4; i++)
#pragma unroll
    for (int j = 0; j < 4; j++) {
      const int mb = m0 + wave_m * 64 + i * 16 + q * 4;
      const int n = n0 + wave_n * 64 + j * 16 + fr;
#pragma unroll
      for (int r = 0; r < 4; r++)
        out[(size_t)(mb + r) * N + n] = f2bf(acc[i][j][r]);
    }
}

// Final projection GEMM (yg @ WoT -> out fp32)
__global__ __launch_bounds__(256) void gemm_out_kernel(
    const unsigned short* __restrict__ A,
    const unsigned short* __restrict__ BT,
    float* __restrict__ out)
{
  constexpr int K = 1024, N = 1024, SK = 32;
  __shared__ __align__(16) unsigned short As[128 * SK];
  __shared__ __align__(16) unsigned short Bs[128 * SK];
  const int tid = threadIdx.x;
  const int wv = tid >> 6, lane = tid & 63;
  const int fr = lane & 15, q = lane >> 4;
  const int wave_m = wv >> 1, wave_n = wv & 1;
  const int m0 = blockIdx.x * 128;
  const int n0 = blockIdx.y * 128;

  f32x4 acc[4][4];
#pragma unroll
  for (int i = 0; i < 4; i++)
#pragma unroll
    for (int j = 0; j < 4; j++) acc[i][j] = (f32x4){0.f, 0.f, 0.f, 0.f};

  const int arow = tid >> 2;
  const int akc = (tid & 3) * 8;

  for (int k0 = 0; k0 < K; k0 += 32) {
#pragma unroll
    for (int i = 0; i < 2; ++i)
      gl2lds16(A + (size_t)(m0 + arow + i * 64) * K + k0 + akc, As + i * 2048 + wv * 512);
#pragma unroll
    for (int i = 0; i < 2; ++i)
      gl2lds16(BT + (size_t)(n0 + arow + i * 64) * K + k0 + akc, Bs + i * 2048 + wv * 512);
    __syncthreads();
    bf16x8 af[4], bfv[4];
#pragma unroll
    for (int i = 0; i < 4; i++)
      af[i] = *(const bf16x8*)(&As[(wave_m * 64 + i * 16 + fr) * SK + q * 8]);
#pragma unroll
    for (int j = 0; j < 4; j++)
      bfv[j] = *(const bf16x8*)(&Bs[(wave_n * 64 + j * 16 + fr) * SK + q * 8]);
#pragma unroll
    for (int i = 0; i < 4; i++)
#pragma unroll
      for (int j = 0; j < 4; j++)
        acc[i][j] = __builtin_amdgcn_mfma_f32_16x16x32_bf16(af[i], bfv[j], acc[i][j], 0, 0, 0);
    __syncthreads();
  }
#pragma unroll
  for (int i = 0; i < 4; i++)
#pragma unroll
    for (int j = 0; j < 4; j++) {
      const int mb = m0 + wave_m * 64 + i * 16 + q * 4;
      const int n = n0 + wave_n * 64 + j * 16 + fr;
#pragma unroll
      for (int r = 0; r < 4; r++)
        out[(size_t)(mb + r) * N + n] = acc[i][j][r];
    }
}

// ---------------------------------------------------------------------------
// Phase 1 (MFMA): per-(bh,chunk) chunked-DPLR operators, postproc FUSED.
// v3: Y-solve eliminated via Qloc = (I-L)^-1 (LKA·V): W = LKA·V by MFMA, then
// a single dual-RHS blocked triangular solve (4x16 blocks). Cross-block terms
// via MFMA bridge reading XTb/QTb (col-major, K-contiguous); only 16x16
// diagonal recurrences stay on fp32 VALU. Solve is barrier-free (intra-wave).
// ---------------------------------------------------------------------------
__global__ __launch_bounds__(256, 2) void chunk_ops_kernel(
    const unsigned short* __restrict__ r_btc, const unsigned short* __restrict__ k_btc,
    const float* __restrict__ v_btc, const unsigned short* __restrict__ wraw,
    const unsigned short* __restrict__ araw,
    const float* __restrict__ w0, const float* __restrict__ a0,
    const float* __restrict__ k_k, const float* __restrict__ k_a,
    const float* __restrict__ r_k,
    unsigned short* __restrict__ McG, unsigned short* __restrict__ NcG,
    unsigned short* __restrict__ PcG, unsigned short* __restrict__ OlG,
    unsigned short* __restrict__ DkG, float* __restrict__ s3G)
{
  extern __shared__ char smraw[];
  unsigned short* AHb  = (unsigned short*)smraw;   // S1: Ahat -> XTb
  unsigned short* RHb  = AHb + 64 * RS;            // S2: Rhat (bf16, thru E)
  unsigned short* BPb  = RHb + 64 * RS;            // S3: Bp -> LKA -> W -> QTb
  unsigned short* KPb  = BPb + 64 * RS;            // S4: Kp -> DBR
  unsigned short* BPTb = KPb + 64 * RS;            // S5: Btil^T [i][t]
  unsigned short* KPTb = BPTb + 64 * RS;           // S6: Ktil^T [i][t]
  unsigned short* VSTb = KPTb + 64 * RS;           // S7: V^T [n][t]
  unsigned short* LBb  = VSTb + 64 * RS;           // S8: LBA bf16 (s68)
  float* GLs = (float*)(LBb + 64 * LBS);           // [64] total log-decay
  float* SS  = GLs + 64;                           // [4][64] strip sums
  unsigned short* XTb = AHb;                       // overlay after solve
  unsigned short* LKb = BPb;                       // overlay after Gram (LKA, then W)
  unsigned short* QTb = BPb;                       // overlay after Q-solve
  unsigned short* DBb = KPb;                       // overlay after Gram

  const int inst = blockIdx.x;
  const int bh = inst >> 4, c = inst & 15;
  const int b = bh >> 4, h = bh & 15;
  const int tid = threadIdx.x;
  const int lane = tid & 63;
  const int wv = tid >> 6;
  const int jl = lane;
  const int ch = h * 64 + jl;
  const size_t base = ((size_t)(b * 1024 + c * 64) * 1024) + ch;

  const float p_w0 = w0[ch], p_a0 = a0[ch];
  const float p_kk = k_k[ch], p_ka = k_a[ch], p_rk = r_k[ch];
  const float EM = 0.60653065971263342f;  // e^{-0.5}

  // ---- prefetch ALL per-token global inputs into registers (80 loads) ----
  unsigned short wr_u[16], kv_u[16], rv_u[16], ar_u[16];
  float vv_u[16];
#pragma unroll
  for (int u = 0; u < 16; ++u) {
    const size_t gi = base + (size_t)(16 * wv + u) * 1024;
    wr_u[u] = wraw[gi];
    kv_u[u] = k_btc[gi];
    rv_u[u] = r_btc[gi];
    ar_u[u] = araw[gi];
    vv_u[u] = v_btc[gi];
  }

  // ---- pass 1: inclusive log-decay prefix for my 16 rows + strip sum ----
  float lwv[16];
  {
    float run = 0.f;
#pragma unroll
    for (int u = 0; u < 16; ++u) {
      run += -EM * sigmoidf_(p_w0 + bf2f(wr_u[u]));
      lwv[u] = run;                       // inclusive prefix within strip
    }
    SS[wv * 64 + jl] = run;
  }
  __syncthreads();
  const float s0 = SS[0 * 64 + jl], s1 = SS[1 * 64 + jl];
  const float s2 = SS[2 * 64 + jl], s3s = SS[3 * 64 + jl];
  const float goff = (wv > 0 ? s0 : 0.f) + (wv > 1 ? s1 : 0.f) + (wv > 2 ? s2 : 0.f);
  const float gl = s0 + s1 + s2 + s3s;
  if (wv == 0) GLs[jl] = gl;

  // ---- pass 2: per-token transforms + factor matrices (independent u) ----
  float s3v[16];
  {
    const float e_gl = __expf(gl);
#pragma unroll
    for (int u = 0; u < 16; ++u) {
      const int t = 16 * wv + u;
      const float pre = goff + (u ? lwv[u - 1] : 0.f);   // g_{t-1}
      const float cur = goff + lwv[u];                   // g_t
      const float kv = bf2f(kv_u[u]), rv = bf2f(rv_u[u]);
      const float vv = vv_u[u];
      const float av = sigmoidf_(p_a0 + bf2f(ar_u[u]));
      const float kkx = kv * p_kk;
      float ssq = kkx * kkx;
#pragma unroll
      for (int m = 1; m < 64; m <<= 1) ssq += __shfl_xor(ssq, m);
      const float scale = __builtin_amdgcn_rsqf(fmaxf(ssq, 1e-24f));
      const float kkn = kkx * scale;
      const float bb = kkn * av;
      const float kmod = kv * (1.0f + (av - 1.0f) * p_ka);
      float s3 = rv * kmod * p_rk;
#pragma unroll
      for (int m = 1; m < 64; m <<= 1) s3 += __shfl_xor(s3, m);
      s3v[u] = s3;
      const float e_prev = __expf(pre);                  // exp(g_{t-1})
      const float e_gu   = __expf(cur);                  // exp(g_t), <= 1
      const float em     = __expf(-cur);                 // exp(-g_t)
      const float egl    = e_gl * em;                    // exp(gl-g_t) <= 1
      AHb[t * RS + jl] = f2bf(-kkn * e_prev);
      BPb[t * RS + jl] = f2bf(bb * em);
      KPb[t * RS + jl] = f2bf(kmod * em);
      BPTb[jl * RS + t] = f2bf(bb * egl);
      KPTb[jl * RS + t] = f2bf(kmod * egl);
      RHb[t * RS + jl] = f2bf(rv * e_gu);
      VSTb[jl * RS + t] = f2bf(vv);
    }
    if (jl == 0) {
      float* sp = s3G + (bh << 10) + (c << 6) + 16 * wv;
#pragma unroll
      for (int k2 = 0; k2 < 4; ++k2)
        *(float4*)(sp + 4 * k2) = make_float4(s3v[4 * k2], s3v[4 * k2 + 1],
                                              s3v[4 * k2 + 2], s3v[4 * k2 + 3]);
    }
  }
  __syncthreads();

  const int fr = lane & 15, q = lane >> 4;
  const int i0 = wv * 16;

  // ---- Gram products via MFMA: LBA, LKA, DBR, DKR(->global) ----
  {
    f32x4 aLB[4], aLK[4], aDB[4], aDK[4];
#pragma unroll
    for (int j = 0; j < 4; ++j) {
      aLB[j] = (f32x4){0.f, 0.f, 0.f, 0.f}; aLK[j] = (f32x4){0.f, 0.f, 0.f, 0.f};
      aDB[j] = (f32x4){0.f, 0.f, 0.f, 0.f}; aDK[j] = (f32x4){0.f, 0.f, 0.f, 0.f};
    }
#pragma unroll
    for (int ks = 0; ks < 2; ++ks) {
      const int ko = ks * 32 + q * 8;
      bf16x8 fA = *(const bf16x8*)(AHb + (i0 + fr) * RS + ko);
      bf16x8 fR = *(const bf16x8*)(RHb + (i0 + fr) * RS + ko);
#pragma unroll
      for (int j = 0; j < 4; ++j) {
        bf16x8 fB = *(const bf16x8*)(BPb + (j * 16 + fr) * RS + ko);
        bf16x8 fK = *(const bf16x8*)(KPb + (j * 16 + fr) * RS + ko);
        aLB[j] = __builtin_amdgcn_mfma_f32_16x16x32_bf16(fA, fB, aLB[j], 0, 0, 0);
        aLK[j] = __builtin_amdgcn_mfma_f32_16x16x32_bf16(fA, fK, aLK[j], 0, 0, 0);
        aDB[j] = __builtin_amdgcn_mfma_f32_16x16x32_bf16(fR, fB, aDB[j], 0, 0, 0);
        aDK[j] = __builtin_amdgcn_mfma_f32_16x16x32_bf16(fR, fK, aDK[j], 0, 0, 0);
      }
    }
    __syncthreads();   // all Gram fragment reads done before overlay stores
#pragma unroll
    for (int j = 0; j < 4; ++j) {
      const int s = j * 16 + fr;
#pragma unroll
      for (int r = 0; r < 4; ++r) {
        const int t = i0 + q * 4 + r;
        LBb[t * LBS + s] = f2bf((s < t) ? aLB[j][r] : 0.f);
        LKb[t * RS + s] = f2bf((s < t) ? aLK[j][r] : 0.f);
        DBb[t * RS + s] = f2bf((s <= t) ? aDB[j][r] : 0.f);
        DkG[(size_t)inst * 4096 + t * 64 + s] = f2bf((s <= t) ? aDK[j][r] : 0.f);
      }
    }
  }
  __syncthreads();

  // ---- W = LKA · V (MFMA, all waves; replaces Y-solve + Qloc) ----
  {
    f32x4 wacc[4];
#pragma unroll
    for (int j = 0; j < 4; ++j) wacc[j] = (f32x4){0.f, 0.f, 0.f, 0.f};
#pragma unroll
    for (int ks = 0; ks < 2; ++ks) {
      const int ko = ks * 32 + q * 8;
      bf16x8 fL = *(const bf16x8*)(LKb + (i0 + fr) * RS + ko);
#pragma unroll
      for (int j = 0; j < 4; ++j) {
        bf16x8 fV = *(const bf16x8*)(VSTb + (j * 16 + fr) * RS + ko);
        wacc[j] = __builtin_amdgcn_mfma_f32_16x16x32_bf16(fL, fV, wacc[j], 0, 0, 0);
      }
    }
#pragma unroll
    for (int j = 0; j < 4; ++j)
#pragma unroll
      for (int r = 0; r < 4; ++r)
        LKb[(i0 + q * 4 + r) * RS + j * 16 + fr] = f2bf(wacc[j][r]);
  }
  __syncthreads();

  // ---- prefetch DKR fragments from global (L2-hot: our own writes) ----
  bf16x8 fDK0, fDK1;
  {
    const unsigned short* dkp = DkG + (size_t)inst * 4096 + (i0 + fr) * 64 + q * 8;
    fDK0 = *(const bf16x8*)(dkp);
    fDK1 = *(const bf16x8*)(dkp + 32);
  }

  // ---- blocked dual triangular solve (barrier-free, intra-wave):
  //      wave0: (I-L)X = Ahat  -> XTb[jc][t];  wave1: (I-L)Q = W -> QTb[jc][t]
  if (wv < 2) {
    const int jc = lane;
    unsigned short* Sb = (wv == 0) ? AHb : LKb;    // RHS (consumed into regs)
    unsigned short* Tb = (wv == 0) ? XTb : QTb;    // col-major solution [jc][t]
    float x[64];
#pragma unroll
    for (int t = 0; t < 64; ++t) x[t] = bf2f(Sb[t * RS + jc]);
    // zero my solution row: bridge MFMAs read 0 for not-yet-solved t
#pragma unroll
    for (int z2 = 0; z2 < 8; ++z2)
      *(bf16x8*)(Tb + jc * RS + z2 * 8) = (bf16x8){0, 0, 0, 0, 0, 0, 0, 0};

    const int jf = jc & 15, tjm = jc >> 4;

#pragma unroll
    for (int I = 0; I < 4; ++I) {
      if (I > 0) {
        // bridge: x[16I+u] += sum_{s<16I} L[16I+u][s] * sol[s][jc]  (MFMA)
        f32x4 cU[4];
#pragma unroll
        for (int tj = 0; tj < 4; ++tj) cU[tj] = (f32x4){0.f, 0.f, 0.f, 0.f};
#pragma unroll
        for (int kw = 0; kw < 2; ++kw) {
          if (kw * 32 < 16 * I) {
            const int ko = kw * 32 + q * 8;
            bf16x8 fL;
            *(ushort4*)&fL = *(const ushort4*)(LBb + (16 * I + fr) * LBS + ko);
            *((ushort4*)&fL + 1) = *(const ushort4*)(LBb + (16 * I + fr) * LBS + ko + 4);
#pragma unroll
            for (int tj = 0; tj < 4; ++tj) {
              bf16x8 fX = *(const bf16x8*)(Tb + (tj * 16 + fr) * RS + ko);
              cU[tj] = __builtin_amdgcn_mfma_f32_16x16x32_bf16(fL, fX, cU[tj], 0, 0, 0);
            }
          }
        }
        // redistribute MFMA C-layout to column-owner lanes
#pragma unroll
        for (int qq = 0; qq < 4; ++qq) {
          const int saddr = (qq * 16 + jf) * 4;
#pragma unroll
          for (int r = 0; r < 4; ++r) {
            int g0 = __builtin_amdgcn_ds_bpermute(saddr, __builtin_bit_cast(int, cU[0][r]));
            int g1 = __builtin_amdgcn_ds_bpermute(saddr, __builtin_bit_cast(int, cU[1][r]));
            int g2 = __builtin_amdgcn_ds_bpermute(saddr, __builtin_bit_cast(int, cU[2][r]));
            int g3 = __builtin_amdgcn_ds_bpermute(saddr, __builtin_bit_cast(int, cU[3][r]));
            int gs = (tjm == 0) ? g0 : (tjm == 1) ? g1 : (tjm == 2) ? g2 : g3;
            x[16 * I + qq * 4 + r] += __builtin_bit_cast(float, gs);
          }
        }
      }
      // diagonal 16x16 unit-lower solve (fp32 chain, bf16 L)
#pragma unroll
      for (int u = 1; u < 16; ++u) {
        const unsigned short* lr = LBb + (16 * I + u) * LBS + 16 * I;
        float acc0 = 0.f, acc1 = 0.f;
#pragma unroll
        for (int s = 0; s + 2 <= u; s += 2) {
          acc0 = fmaf(bf2f(lr[s]), x[16 * I + s], acc0);
          acc1 = fmaf(bf2f(lr[s + 1]), x[16 * I + s + 1], acc1);
        }
        if (u & 1) acc0 = fmaf(bf2f(lr[u - 1]), x[16 * I + u - 1], acc0);
        x[16 * I + u] += acc0 + acc1;
      }
      // store solved block of my column (bf16 pairs)
#pragma unroll
      for (int t2 = 0; t2 < 16; t2 += 2) {
        unsigned int pk = (unsigned int)f2bf(x[16 * I + t2])
                        | ((unsigned int)f2bf(x[16 * I + t2 + 1]) << 16);
        *(unsigned int*)(Tb + jc * RS + 16 * I + t2) = pk;
      }
    }
  }
  __syncthreads();

  // ---- final operators: Mc, Ncc, Pc, Oloc (MFMA) -> global bf16 ----
  {
    f32x4 mA[4], nA[4], pA[4], oA[4];
#pragma unroll
    for (int j = 0; j < 4; ++j) {
      mA[j] = (f32x4){0.f, 0.f, 0.f, 0.f}; nA[j] = (f32x4){0.f, 0.f, 0.f, 0.f};
      pA[j] = (f32x4){0.f, 0.f, 0.f, 0.f}; oA[j] = (f32x4){0.f, 0.f, 0.f, 0.f};
    }
#pragma unroll
    for (int ks = 0; ks < 2; ++ks) {
      const int ko = ks * 32 + q * 8;
      bf16x8 fBT = *(const bf16x8*)(BPTb + (i0 + fr) * RS + ko);
      bf16x8 fKT = *(const bf16x8*)(KPTb + (i0 + fr) * RS + ko);
      bf16x8 fDB = *(const bf16x8*)(DBb + (i0 + fr) * RS + ko);
      bf16x8 fDK = ks ? fDK1 : fDK0;
#pragma unroll
      for (int j = 0; j < 4; ++j) {
        bf16x8 fXT = *(const bf16x8*)(XTb + (j * 16 + fr) * RS + ko);
        bf16x8 fQT = *(const bf16x8*)(QTb + (j * 16 + fr) * RS + ko);
        bf16x8 fVT = *(const bf16x8*)(VSTb + (j * 16 + fr) * RS + ko);
        mA[j] = __builtin_amdgcn_mfma_f32_16x16x32_bf16(fBT, fXT, mA[j], 0, 0, 0);
        nA[j] = __builtin_amdgcn_mfma_f32_16x16x32_bf16(fBT, fQT, nA[j], 0, 0, 0);
        nA[j] = __builtin_amdgcn_mfma_f32_16x16x32_bf16(fKT, fVT, nA[j], 0, 0, 0);
        pA[j] = __builtin_amdgcn_mfma_f32_16x16x32_bf16(fDB, fXT, pA[j], 0, 0, 0);
        oA[j] = __builtin_amdgcn_mfma_f32_16x16x32_bf16(fDB, fQT, oA[j], 0, 0, 0);
        oA[j] = __builtin_amdgcn_mfma_f32_16x16x32_bf16(fDK, fVT, oA[j], 0, 0, 0);
      }
    }
    const size_t ob = (size_t)inst * 4096;
    float eg[4];
#pragma unroll
    for (int r = 0; r < 4; ++r) eg[r] = __expf(GLs[i0 + q * 4 + r]);
#pragma unroll
    for (int j = 0; j < 4; ++j) {
      const int col = j * 16 + fr;
#pragma unroll
      for (int r = 0; r < 4; ++r) {
        const int row = i0 + q * 4 + r;
        const size_t oi = ob + (size_t)row * 64 + col;
        McG[oi] = f2bf(mA[j][r] + (row == col ? eg[r] : 0.f));
        NcG[oi] = f2bf(nA[j][r]);
        PcG[oi] = f2bf(pA[j][r] + bf2f(RHb[row * RS + col]));
        OlG[oi] = f2bf(oA[j][r]);
      }
    }
  }
}

// ---------------------------------------------------------------------------
// Phase 2: sequential chunk-state propagation per (b,h): ST' = Mc ST + Ncc.
// ---------------------------------------------------------------------------
__global__ __launch_bounds__(256) void chunk_scan_kernel(
    const unsigned short* __restrict__ McG, const unsigned short* __restrict__ NcG,
    unsigned short* __restrict__ Sch)
{
  __shared__ float ST[64 * PAD];
  __shared__ float MB[64 * PAD];
  const int bh = blockIdx.x;
  const int tid = threadIdx.x;
  const int it = tid >> 4, jt = tid & 15;

#pragma unroll
  for (int q = 0; q < 16; ++q) {
    int idx = q * 256 + tid;
    ST[(idx >> 6) * PAD + (idx & 63)] = 0.f;
  }
  __syncthreads();

  for (int c = 0; c < 16; ++c) {
    const size_t ob = ((((size_t)bh << 4) + c) << 12);
#pragma unroll
    for (int q = 0; q < 4; ++q) {
      int idx = q * 1024 + tid * 4;
      int row = idx >> 6, col = idx & 63;
      ushort4 sv;
      sv.x = f2bf(ST[row * PAD + col]);     sv.y = f2bf(ST[row * PAD + col + 1]);
      sv.z = f2bf(ST[row * PAD + col + 2]); sv.w = f2bf(ST[row * PAD + col + 3]);
      *(ushort4*)(Sch + ob + idx) = sv;
      ushort4 mv = *(const ushort4*)(McG + ob + idx);
      MB[row * PAD + col] = bf2f(mv.x);     MB[row * PAD + col + 1] = bf2f(mv.y);
      MB[row * PAD + col + 2] = bf2f(mv.z); MB[row * PAD + col + 3] = bf2f(mv.w);
    }
    __syncthreads();
    float acc[4][4];
#pragma unroll
    for (int u = 0; u < 4; ++u) {
      ushort4 n4 = *(const ushort4*)(NcG + ob + (size_t)(4 * it + u) * 64 + 4 * jt);
      acc[u][0] = bf2f(n4.x); acc[u][1] = bf2f(n4.y);
      acc[u][2] = bf2f(n4.z); acc[u][3] = bf2f(n4.w);
    }
#pragma unroll 4
    for (int pp = 0; pp < 64; ++pp) {
      float mv[4], sv[4];
#pragma unroll
      for (int u = 0; u < 4; ++u) mv[u] = MB[(4 * it + u) * PAD + pp];
#pragma unroll
      for (int v = 0; v < 4; ++v) sv[v] = ST[pp * PAD + 4 * jt + v];
#pragma unroll
      for (int u = 0; u < 4; ++u)
#pragma unroll
        for (int v = 0; v < 4; ++v) acc[u][v] = fmaf(mv[u], sv[v], acc[u][v]);
    }
    __syncthreads();
#pragma unroll
    for (int u = 0; u < 4; ++u)
#pragma unroll
      for (int v = 0; v < 4; ++v) ST[(4 * it + u) * PAD + 4 * jt + v] = acc[u][v];
    __syncthreads();
  }
}

// ---------------------------------------------------------------------------
// Phase 3 + GroupNorm fused: Out = Pc ST + Oloc; per-row norm; + s3*v; *g.
// ---------------------------------------------------------------------------
__global__ __launch_bounds__(256) void chunk_outgn_kernel(
    const unsigned short* __restrict__ PcG, const unsigned short* __restrict__ OlG,
    const unsigned short* __restrict__ Sch, const float* __restrict__ s3G,
    const float* __restrict__ v_btc, const unsigned short* __restrict__ g_f,
    const float* __restrict__ gamma, const float* __restrict__ beta,
    unsigned short* __restrict__ yg)
{
  __shared__ float ST[64 * PAD];
  __shared__ float PB[64 * PAD];
  const int inst = blockIdx.x;
  const int bh = inst >> 4, c = inst & 15;
  const int b = bh >> 4, h = bh & 15;
  const int tid = threadIdx.x;
  const int tt = tid >> 4, jt = tid & 15;
  const size_t ob = (size_t)inst << 12;

#pragma unroll
  for (int q = 0; q < 4; ++q) {
    int idx = q * 1024 + tid * 4;
    int row = idx >> 6, col = idx & 63;
    ushort4 sv = *(const ushort4*)(Sch + ob + idx);
    ST[row * PAD + col] = bf2f(sv.x);     ST[row * PAD + col + 1] = bf2f(sv.y);
    ST[row * PAD + col + 2] = bf2f(sv.z); ST[row * PAD + col + 3] = bf2f(sv.w);
    ushort4 pv = *(const ushort4*)(PcG + ob + idx);
    PB[row * PAD + col] = bf2f(pv.x);     PB[row * PAD + col + 1] = bf2f(pv.y);
    PB[row * PAD + col + 2] = bf2f(pv.z); PB[row * PAD + col + 3] = bf2f(pv.w);
  }
  __syncthreads();

  float acc[4][4];
#pragma unroll
  for (int u = 0; u < 4; ++u) {
    ushort4 o4 = *(const ushort4*)(OlG + ob + (size_t)(4 * tt + u) * 64 + 4 * jt);
    acc[u][0] = bf2f(o4.x); acc[u][1] = bf2f(o4.y);
    acc[u][2] = bf2f(o4.z); acc[u][3] = bf2f(o4.w);
  }
#pragma unroll 4
  for (int pp = 0; pp < 64; ++pp) {
    float pv[4], sv[4];
#pragma unroll
    for (int u = 0; u < 4; ++u) pv[u] = PB[(4 * tt + u) * PAD + pp];
#pragma unroll
    for (int v = 0; v < 4; ++v) sv[v] = ST[pp * PAD + 4 * jt + v];
#pragma unroll
    for (int u = 0; u < 4; ++u)
#pragma unroll
      for (int v = 0; v < 4; ++v) acc[u][v] = fmaf(pv[u], sv[v], acc[u][v]);
  }

  const int colb = h * 64 + 4 * jt;
  float4 ga4 = *(const float4*)(gamma + colb);
  float4 be4 = *(const float4*)(beta + colb);

#pragma unroll
  for (int u = 0; u < 4; ++u) {
    float sum1 = acc[u][0] + acc[u][1] + acc[u][2] + acc[u][3];
    float sum2 = acc[u][0] * acc[u][0] + acc[u][1] * acc[u][1]
               + acc[u][2] * acc[u][2] + acc[u][3] * acc[u][3];
#pragma unroll
    for (int m = 1; m < 16; m <<= 1) {
      sum1 += __shfl_xor(sum1, m);
      sum2 += __shfl_xor(sum2, m);
    }
    const float mean = sum1 * (1.0f / 64.0f);
    const float var = sum2 * (1.0f / 64.0f) - mean * mean;
    const float rstd = __builtin_amdgcn_rsqf(var + 0.00064f);
    const int tok = c * 64 + 4 * tt + u;
    const float s3 = s3G[(bh << 10) + tok];
    const size_t gaddr = ((size_t)(b * 1024 + tok) * 1024) + colb;
    float4 v4 = *(const float4*)(v_btc + gaddr);
    ushort4 g4b = *(const ushort4*)(g_f + gaddr);
    ushort4 ov;
    ov.x = f2bf(((acc[u][0] - mean) * rstd * ga4.x + be4.x + s3 * v4.x) * bf2f(g4b.x));
    ov.y = f2bf(((acc[u][1] - mean) * rstd * ga4.y + be4.y + s3 * v4.y) * bf2f(g4b.y));
    ov.z = f2bf(((acc[u][2] - mean) * rstd * ga4.z + be4.z + s3 * v4.z) * bf2f(g4b.z));
    ov.w = f2bf(((acc[u][3] - mean) * rstd * ga4.w + be4.w + s3 * v4.w) * bf2f(g4b.w));
    *(ushort4*)(yg + gaddr) = ov;
  }
}

// ---------------------------------------------------------------------------
extern "C" void kernel_launch(void* const* d_in, const int* in_sizes, int n_in,
                              void* d_out, int out_size, void* d_ws, size_t ws_size,
                              hipStream_t stream)
{
  (void)in_sizes; (void)n_in; (void)out_size;
  const float* x    = (const float*)d_in[0];
  const float* x_r  = (const float*)d_in[1];
  const float* x_w  = (const float*)d_in[2];
  const float* x_k  = (const float*)d_in[3];
  const float* x_v  = (const float*)d_in[4];
  const float* x_a  = (const float*)d_in[5];
  const float* x_g  = (const float*)d_in[6];
  const float* w0   = (const float*)d_in[7];
  const float* w1   = (const float*)d_in[8];
  const float* w2   = (const float*)d_in[9];
  const float* a0   = (const float*)d_in[10];
  const float* a1   = (const float*)d_in[11];
  const float* a2   = (const float*)d_in[12];
  const float* g1   = (const float*)d_in[16];
  const float* g2   = (const float*)d_in[17];
  const float* k_k  = (const float*)d_in[18];
  const float* k_a  = (const float*)d_in[19];
  const float* r_k  = (const float*)d_in[20];
  const float* Wr   = (const float*)d_in[21];
  const float* Wk   = (const float*)d_in[22];
  const float* Wv   = (const float*)d_in[23];
  const float* Wo   = (const float*)d_in[24];
  const float* ln_g = (const float*)d_in[25];
  const float* ln_b = (const float*)d_in[26];

  float* outp = (float*)d_out;
  float* vfirst = outp + (size_t)BB * TT * CCH;

  char* ws = (char*)d_ws;
  size_t off = 0;
  auto alloc = [&](size_t bytes) -> char* {
    char* p = ws + off;
    off += (bytes + 255) & ~(size_t)255;
    return p;
  };

  unsigned short* WrT = (unsigned short*)alloc(2097152);
  unsigned short* WkT = (unsigned short*)alloc(2097152);
  unsigned short* WvT = (unsigned short*)alloc(2097152);
  unsigned short* WoT = (unsigned short*)alloc(2097152);
  unsigned short* w1T = (unsigned short*)alloc(131072);
  unsigned short* w2T = (unsigned short*)alloc(131072);
  unsigned short* a1T = (unsigned short*)alloc(131072);
  unsigned short* a2T = (unsigned short*)alloc(131072);
  unsigned short* g1T = (unsigned short*)alloc(262144);
  unsigned short* g2T = (unsigned short*)alloc(262144);
  unsigned short* r_btc = (unsigned short*)alloc(8388608);
  unsigned short* k_btc = (unsigned short*)alloc(8388608);
  unsigned short* wraw  = (unsigned short*)alloc(8388608);
  unsigned short* araw  = (unsigned short*)alloc(8388608);
  unsigned short* gfB = (unsigned short*)alloc(8388608);
  unsigned short* OlG = (unsigned short*)alloc(8388608);
  unsigned short* DkG = (unsigned short*)alloc(8388608);
  unsigned short* McG = (unsigned short*)alloc(8388608);
  unsigned short* NcG = (unsigned short*)alloc(8388608);
  unsigned short* PcG = (unsigned short*)alloc(8388608);
  float* s3G   = (float*)alloc(262144);
  unsigned short* hwB = (unsigned short*)alloc(524288);
  unsigned short* haB = (unsigned short*)alloc(524288);
  unsigned short* hgB = (unsigned short*)alloc(1048576);
  unsigned short* ygB = (unsigned short*)alloc(8388608);

  // overlays (owners dead before the writer runs)
  unsigned short* Sch = k_btc;        // k_btc dead after chunk_ops

  if (off > ws_size) return;

  dim3 blk(256);

  // weight transposes only (mix fused into gemm_stage1)
  prep_kernel<<<1152, blk, 0, stream>>>(
      Wr, Wk, Wv, Wo, WrT, WkT, WvT, WoT,
      w1, w2, a1, a2, g1, g2, w1T, w2T, a1T, a2T, g1T, g2T);

  // r/k/v GEMMs + lora1 in one launch; mix fused; v straight into vfirst
  gemm_stage1_kernel<<<896, blk, 0, stream>>>(
      x, x_r, x_k, x_v, WrT, WkT, WvT, r_btc, k_btc, vfirst,
      x_w, x_a, x_g, w1T, a1T, g1T, hwB, haB, hgB);

  // LoRA stage 2 (w/a/g) in one launch
  lora2_kernel<<<dim3(32, 8, 3), blk, 0, stream>>>(
      hwB, haB, hgB, w2T, a2T, g2T, wraw, araw, gfB);

  // chunked-DPLR scan phase 1 (postproc fused, 2 blocks/CU)
  constexpr int CHUNK_LDS = 7 * 64 * RS * 2 + 64 * LBS * 2 + 64 * 4 + 4 * 64 * 4;
  hipFuncSetAttribute((const void*)chunk_ops_kernel,
                      hipFuncAttributeMaxDynamicSharedMemorySize, CHUNK_LDS);
  chunk_ops_kernel<<<1024, blk, CHUNK_LDS, stream>>>(
      r_btc, k_btc, vfirst, wraw, araw, w0, a0, k_k, k_a, r_k,
      McG, NcG, PcG, OlG, DkG, s3G);

  chunk_scan_kernel<<<64, blk, 0, stream>>>(McG, NcG, Sch);

  chunk_outgn_kernel<<<1024, blk, 0, stream>>>(PcG, OlG, Sch, s3G, vfirst, gfB,
                                               ln_g, ln_b, ygB);

  gemm_out_kernel<<<dim3(32, 8), blk, 0, stream>>>(ygB, WoT, outp);
}

// Round 6
// 350.905 us; speedup vs baseline: 1.0560x; 1.0560x over previous
//
#include <hip/hip_runtime.h>
#include <hip/hip_bf16.h>
#include <math.h>

// Problem constants
#define BB 4
#define TT 1024
#define CCH 1024
#define HH 16
#define NNd 64
#define PAD 65      // fp32 LDS row pad (chunk_scan/outgn)
#define RS 72       // bf16 LDS row stride in shorts (144B = 9x16B, frag-aligned)
#define LBS 68      // bf16 L-matrix row stride in shorts (136B, 8B-aligned u4)

typedef short bf16x8 __attribute__((ext_vector_type(8)));
typedef float f32x4 __attribute__((ext_vector_type(4)));

__device__ __forceinline__ unsigned short f2bf(float f) {
  __hip_bfloat16 h = __float2bfloat16(f);
  return __builtin_bit_cast(unsigned short, h);
}
__device__ __forceinline__ float bf2f(unsigned short u) {
  unsigned int x = (unsigned int)u << 16;
  return __builtin_bit_cast(float, x);
}
// Native transcendentals: outputs all round through bf16 downstream, so
// v_exp/v_rcp/v_rsq (~1 ulp) precision is far below bf16 quantization.
__device__ __forceinline__ float sigmoidf_(float x) {
  return __builtin_amdgcn_rcpf(1.0f + __expf(-x));
}
__device__ __forceinline__ float ftanh_(float x) {
  // tanh(x) = 1 - 2/(e^{2x}+1); saturates correctly at +/-inf.
  return 1.0f - 2.0f * __builtin_amdgcn_rcpf(__expf(2.0f * x) + 1.0f);
}

// async global->LDS, 16B per lane; LDS dest must be wave-uniform base + 16*lane
__device__ __forceinline__ void gl2lds16(const unsigned short* g, unsigned short* l) {
  __builtin_amdgcn_global_load_lds(
      (const __attribute__((address_space(1))) unsigned int*)g,
      (__attribute__((address_space(3))) unsigned int*)l, 16, 0, 0);
}

// ---------------------------------------------------------------------------
// Transpose tile helper
// ---------------------------------------------------------------------------
__device__ __forceinline__ void transpose_tile(
    const float* __restrict__ in, unsigned short* __restrict__ out,
    int R, int Cc, int r0, int c0, unsigned short (*tile)[68], int t)
{
  const int rr = t >> 4;
  const int cc = (t & 15) * 4;
#pragma unroll
  for (int p = 0; p < 4; ++p) {
    int row = p * 16 + rr;
    float4 v = *(const float4*)(in + (size_t)(r0 + row) * Cc + c0 + cc);
    tile[row][cc]     = f2bf(v.x);
    tile[row][cc + 1] = f2bf(v.y);
    tile[row][cc + 2] = f2bf(v.z);
    tile[row][cc + 3] = f2bf(v.w);
  }
  __syncthreads();
#pragma unroll
  for (int p = 0; p < 4; ++p) {
    int row = p * 16 + rr;
    ushort4 o;
    o.x = tile[cc][row];
    o.y = tile[cc + 1][row];
    o.z = tile[cc + 2][row];
    o.w = tile[cc + 3][row];
    *(ushort4*)(out + (size_t)(c0 + row) * R + r0 + cc) = o;
  }
}

// ---------------------------------------------------------------------------
// prep_kernel: mix (blocks 0..4095) + big4 transposes (4096..5119)
//            + lora transposes (5120..5247), one launch.
// [v5 note: round-5 A/B showed fusing the mix into gemm_stage1 regresses
//  (async global_load_lds staging beats reg-staged fp32 mix, 64->102us);
//  the separate mix pass is the measured-best structure.]
// ---------------------------------------------------------------------------
__global__ __launch_bounds__(256) void prep_kernel(
    const float* __restrict__ x,
    const float* __restrict__ cr, const float* __restrict__ cw,
    const float* __restrict__ ck, const float* __restrict__ cv,
    const float* __restrict__ ca, const float* __restrict__ cg,
    unsigned short* __restrict__ xr, unsigned short* __restrict__ xw,
    unsigned short* __restrict__ xk, unsigned short* __restrict__ xv,
    unsigned short* __restrict__ xa, unsigned short* __restrict__ xg,
    const float* __restrict__ W0, const float* __restrict__ W1,
    const float* __restrict__ W2, const float* __restrict__ W3,
    unsigned short* __restrict__ T0, unsigned short* __restrict__ T1,
    unsigned short* __restrict__ T2, unsigned short* __restrict__ T3,
    const float* __restrict__ w1, const float* __restrict__ w2,
    const float* __restrict__ a1, const float* __restrict__ a2,
    const float* __restrict__ g1, const float* __restrict__ g2,
    unsigned short* __restrict__ w1T, unsigned short* __restrict__ w2T,
    unsigned short* __restrict__ a1T, unsigned short* __restrict__ a2T,
    unsigned short* __restrict__ g1T, unsigned short* __restrict__ g2T)
{
  __shared__ unsigned short tile[64][68];
  const int blk = blockIdx.x;
  const int tid = threadIdx.x;
  if (blk < 4096) {
    // ---- token-shift mix ----
    const size_t idx = ((size_t)blk * 256 + tid) * 4;
    const int c = (int)(idx & 1023);
    const int t = (int)((idx >> 10) & 1023);
    float4 xc = *(const float4*)(x + idx);
    float4 xp = make_float4(0.f, 0.f, 0.f, 0.f);
    if (t > 0) xp = *(const float4*)(x + idx - 1024);
    float4 dx = make_float4(xp.x - xc.x, xp.y - xc.y, xp.z - xc.z, xp.w - xc.w);
    auto st = [&](unsigned short* dst, const float* coef) {
      float4 w = *(const float4*)(coef + c);
      ushort4 o;
      o.x = f2bf(fmaf(dx.x, w.x, xc.x));
      o.y = f2bf(fmaf(dx.y, w.y, xc.y));
      o.z = f2bf(fmaf(dx.z, w.z, xc.z));
      o.w = f2bf(fmaf(dx.w, w.w, xc.w));
      *(ushort4*)(dst + idx) = o;
    };
    st(xr, cr); st(xw, cw); st(xk, ck); st(xv, cv); st(xa, ca); st(xg, cg);
  } else if (blk < 5120) {
    const int j = blk - 4096;
    const int z = j >> 8, rem = j & 255;
    const int ty = rem >> 4, tx = rem & 15;
    const float* src = (z == 0) ? W0 : (z == 1) ? W1 : (z == 2) ? W2 : W3;
    unsigned short* dst = (z == 0) ? T0 : (z == 1) ? T1 : (z == 2) ? T2 : T3;
    transpose_tile(src, dst, 1024, 1024, tx * 64, ty * 64, tile, tid);
  } else {
    const int i = blk - 5120;
    const float* src; unsigned short* dst; int R, C, rt, ct;
    if (i < 16)      { src = w1; dst = w1T; R = 1024; C = 64;   rt = i;      ct = 0; }
    else if (i < 32) { src = w2; dst = w2T; R = 64;   C = 1024; rt = 0;      ct = i - 16; }
    else if (i < 48) { src = a1; dst = a1T; R = 1024; C = 64;   rt = i - 32; ct = 0; }
    else if (i < 64) { src = a2; dst = a2T; R = 64;   C = 1024; rt = 0;      ct = i - 48; }
    else if (i < 96) { int k = i - 64; src = g1; dst = g1T; R = 1024; C = 128; rt = k >> 1; ct = k & 1; }
    else             { int k = i - 96; src = g2; dst = g2T; R = 128; C = 1024; rt = k & 1;  ct = k >> 1; }
    transpose_tile(src, dst, R, C, rt * 64, ct * 64, tile, tid);
  }
}

// ---------------------------------------------------------------------------
// gemm_stage1: blocks 0..767 = r/k/v big GEMMs (z=blk/256), 768..895 = lora1.
// r,k outputs bf16 (chunk_ops-only consumers); v output fp32 (vfirst).
// ---------------------------------------------------------------------------
__global__ __launch_bounds__(256) void gemm_stage1_kernel(
    const unsigned short* __restrict__ xrB, const unsigned short* __restrict__ xkB,
    const unsigned short* __restrict__ xvB,
    const unsigned short* __restrict__ WrT, const unsigned short* __restrict__ WkT,
    const unsigned short* __restrict__ WvT,
    unsigned short* __restrict__ r_btc, unsigned short* __restrict__ k_btc,
    float* __restrict__ v_btc,
    const unsigned short* __restrict__ xwB, const unsigned short* __restrict__ xaB,
    const unsigned short* __restrict__ xgB,
    const unsigned short* __restrict__ w1T, const unsigned short* __restrict__ a1T,
    const unsigned short* __restrict__ g1T,
    unsigned short* __restrict__ hwB, unsigned short* __restrict__ haB,
    unsigned short* __restrict__ hgB)
{
  constexpr int K = 1024, SK = 32;
  __shared__ __align__(16) unsigned short As[128 * SK];
  __shared__ __align__(16) unsigned short Bs[128 * SK];
  const int blk = blockIdx.x;
  const int tid = threadIdx.x;
  const int wv = tid >> 6, lane = tid & 63;
  const int fr = lane & 15, q = lane >> 4;
  const int arow = tid >> 2;
  const int akc = (tid & 3) * 8;

  if (blk < 768) {
    // ---- big3 GEMM: z selects r/k/v ----
    const int z = blk >> 8, rem = blk & 255;
    const int m0 = (rem & 31) * 128;
    const int n0 = (rem >> 5) * 128;
    const unsigned short* A = (z == 0) ? xrB : (z == 1) ? xkB : xvB;
    const unsigned short* BT = (z == 0) ? WrT : (z == 1) ? WkT : WvT;
    const int wave_m = wv >> 1, wave_n = wv & 1;

    f32x4 acc[4][4];
#pragma unroll
    for (int i = 0; i < 4; i++)
#pragma unroll
      for (int j = 0; j < 4; j++) acc[i][j] = (f32x4){0.f, 0.f, 0.f, 0.f};

    for (int k0 = 0; k0 < K; k0 += 32) {
#pragma unroll
      for (int i = 0; i < 2; ++i)
        gl2lds16(A + (size_t)(m0 + arow + i * 64) * K + k0 + akc, As + i * 2048 + wv * 512);
#pragma unroll
      for (int i = 0; i < 2; ++i)
        gl2lds16(BT + (size_t)(n0 + arow + i * 64) * K + k0 + akc, Bs + i * 2048 + wv * 512);
      __syncthreads();
      bf16x8 af[4], bfv[4];
#pragma unroll
      for (int i = 0; i < 4; i++)
        af[i] = *(const bf16x8*)(&As[(wave_m * 64 + i * 16 + fr) * SK + q * 8]);
#pragma unroll
      for (int j = 0; j < 4; j++)
        bfv[j] = *(const bf16x8*)(&Bs[(wave_n * 64 + j * 16 + fr) * SK + q * 8]);
#pragma unroll
      for (int i = 0; i < 4; i++)
#pragma unroll
        for (int j = 0; j < 4; j++)
          acc[i][j] = __builtin_amdgcn_mfma_f32_16x16x32_bf16(af[i], bfv[j], acc[i][j], 0, 0, 0);
      __syncthreads();
    }
#pragma unroll
    for (int i = 0; i < 4; i++)
#pragma unroll
      for (int j = 0; j < 4; j++) {
        const int mb = m0 + wave_m * 64 + i * 16 + q * 4;
        const int n = n0 + wave_n * 64 + j * 16 + fr;
#pragma unroll
        for (int r = 0; r < 4; r++) {
          if (z == 0)      r_btc[(size_t)(mb + r) * 1024 + n] = f2bf(acc[i][j][r]);
          else if (z == 1) k_btc[(size_t)(mb + r) * 1024 + n] = f2bf(acc[i][j][r]);
          else             v_btc[(size_t)(mb + r) * 1024 + n] = acc[i][j][r];
        }
      }
  } else {
    // ---- lora1: y=0 hw=tanh, y=1 ha, y=2/3 hg sigmoid halves ----
    const int j2 = blk - 768;
    const int y = j2 >> 5;
    const int m0 = (j2 & 31) * 128;
    const unsigned short* A  = (y == 0) ? xwB : (y == 1) ? xaB : xgB;
    const unsigned short* BT = (y == 0) ? w1T : (y == 1) ? a1T : (g1T + (size_t)(y - 2) * 64 * K);
    unsigned short* outb = (y == 0) ? hwB : (y == 1) ? haB : hgB;
    const int Nout = (y < 2) ? 64 : 128;
    const int ncol0 = (y < 2) ? 0 : (y - 2) * 64;

    f32x4 acc[2][4];
#pragma unroll
    for (int i = 0; i < 2; i++)
#pragma unroll
      for (int j = 0; j < 4; j++) acc[i][j] = (f32x4){0.f, 0.f, 0.f, 0.f};

    for (int k0 = 0; k0 < K; k0 += 32) {
#pragma unroll
      for (int i = 0; i < 2; ++i)
        gl2lds16(A + (size_t)(m0 + arow + i * 64) * K + k0 + akc, As + i * 2048 + wv * 512);
      gl2lds16(BT + (size_t)arow * K + k0 + akc, Bs + wv * 512);
      __syncthreads();
      bf16x8 af[2], bfv[4];
#pragma unroll
      for (int i = 0; i < 2; i++)
        af[i] = *(const bf16x8*)(&As[(wv * 32 + i * 16 + fr) * SK + q * 8]);
#pragma unroll
      for (int j = 0; j < 4; j++)
        bfv[j] = *(const bf16x8*)(&Bs[(j * 16 + fr) * SK + q * 8]);
#pragma unroll
      for (int i = 0; i < 2; i++)
#pragma unroll
        for (int j = 0; j < 4; j++)
          acc[i][j] = __builtin_amdgcn_mfma_f32_16x16x32_bf16(af[i], bfv[j], acc[i][j], 0, 0, 0);
      __syncthreads();
    }
#pragma unroll
    for (int i = 0; i < 2; i++)
#pragma unroll
      for (int j = 0; j < 4; j++) {
        const int mb = m0 + wv * 32 + i * 16 + q * 4;
        const int n = ncol0 + j * 16 + fr;
#pragma unroll
        for (int r = 0; r < 4; r++) {
          float val = acc[i][j][r];
          if (y == 0) val = ftanh_(val);
          else if (y >= 2) val = sigmoidf_(val);
          outb[(size_t)(mb + r) * Nout + n] = f2bf(val);
        }
      }
  }
}

// z-batched LoRA-2 GEMMs -> all bf16 outputs (wraw, araw, g).
__global__ __launch_bounds__(256) void lora2_kernel(
    const unsigned short* __restrict__ hwB, const unsigned short* __restrict__ haB,
    const unsigned short* __restrict__ hgB,
    const unsigned short* __restrict__ w2T, const unsigned short* __restrict__ a2T,
    const unsigned short* __restrict__ g2T,
    unsigned short* __restrict__ wraw, unsigned short* __restrict__ araw,
    unsigned short* __restrict__ gfB)
{
  constexpr int N = 1024, SK = 32;
  __shared__ __align__(16) unsigned short As[128 * SK];
  __shared__ __align__(16) unsigned short Bs[128 * SK];
  const int z = blockIdx.z;
  const unsigned short* A = (z == 0) ? hwB : (z == 1) ? haB : hgB;
  const unsigned short* BT = (z == 0) ? w2T : (z == 1) ? a2T : g2T;
  unsigned short* out = (z == 0) ? wraw : (z == 1) ? araw : gfB;
  const int K = (z == 2) ? 128 : 64;

  const int tid = threadIdx.x;
  const int wv = tid >> 6, lane = tid & 63;
  const int fr = lane & 15, q = lane >> 4;
  const int wave_m = wv >> 1, wave_n = wv & 1;
  const int m0 = blockIdx.x * 128;
  const int n0 = blockIdx.y * 128;

  f32x4 acc[4][4];
#pragma unroll
  for (int i = 0; i < 4; i++)
#pragma unroll
    for (int j = 0; j < 4; j++) acc[i][j] = (f32x4){0.f, 0.f, 0.f, 0.f};

  const int arow = tid >> 2;
  const int akc = (tid & 3) * 8;

  for (int k0 = 0; k0 < K; k0 += 32) {
#pragma unroll
    for (int i = 0; i < 2; ++i)
      gl2lds16(A + (size_t)(m0 + arow + i * 64) * K + k0 + akc, As + i * 2048 + wv * 512);
#pragma unroll
    for (int i = 0; i < 2; ++i)
      gl2lds16(BT + (size_t)(n0 + arow + i * 64) * K + k0 + akc, Bs + i * 2048 + wv * 512);
    __syncthreads();
    bf16x8 af[4], bfv[4];
#pragma unroll
    for (int i = 0; i < 4; i++)
      af[i] = *(const bf16x8*)(&As[(wave_m * 64 + i * 16 + fr) * SK + q * 8]);
#pragma unroll
    for (int j = 0; j < 4; j++)
      bfv[j] = *(const bf16x8*)(&Bs[(wave_n * 64 + j * 16 + fr) * SK + q * 8]);
#pragma unroll
    for (int i = 0; i < 4; i++)
#pragma unroll
      for (int j = 0; j < 4; j++)
        acc[i][j] = __builtin_amdgcn_mfma_f32_16x16x32_bf16(af[i], bfv[j], acc[i][j], 0, 0, 0);
    __syncthreads();
  }
#pragma unroll
  for (int i = 0; i < 4; i++)
#pragma unroll
    for (int j = 0; j < 4; j++) {
      const int mb = m0 + wave_m * 64 + i * 16 + q * 4;
      const int n = n0 + wave_n * 64 + j * 16 + fr;
#pragma unroll
      for (int r = 0; r < 4; r++)
        out[(size_t)(mb + r) * N + n] = f2bf(acc[i][j][r]);
    }
}

// Final projection GEMM (yg @ WoT -> out fp32)
__global__ __launch_bounds__(256) void gemm_out_kernel(
    const unsigned short* __restrict__ A,
    const unsigned short* __restrict__ BT,
    float* __restrict__ out)
{
  constexpr int K = 1024, N = 1024, SK = 32;
  __shared__ __align__(16) unsigned short As[128 * SK];
  __shared__ __align__(16) unsigned short Bs[128 * SK];
  const int tid = threadIdx.x;
  const int wv = tid >> 6, lane = tid & 63;
  const int fr = lane & 15, q = lane >> 4;
  const int wave_m = wv >> 1, wave_n = wv & 1;
  const int m0 = blockIdx.x * 128;
  const int n0 = blockIdx.y * 128;

  f32x4 acc[4][4];
#pragma unroll
  for (int i = 0; i < 4; i++)
#pragma unroll
    for (int j = 0; j < 4; j++) acc[i][j] = (f32x4){0.f, 0.f, 0.f, 0.f};

  const int arow = tid >> 2;
  const int akc = (tid & 3) * 8;

  for (int k0 = 0; k0 < K; k0 += 32) {
#pragma unroll
    for (int i = 0; i < 2; ++i)
      gl2lds16(A + (size_t)(m0 + arow + i * 64) * K + k0 + akc, As + i * 2048 + wv * 512);
#pragma unroll
    for (int i = 0; i < 2; ++i)
      gl2lds16(BT + (size_t)(n0 + arow + i * 64) * K + k0 + akc, Bs + i * 2048 + wv * 512);
    __syncthreads();
    bf16x8 af[4], bfv[4];
#pragma unroll
    for (int i = 0; i < 4; i++)
      af[i] = *(const bf16x8*)(&As[(wave_m * 64 + i * 16 + fr) * SK + q * 8]);
#pragma unroll
    for (int j = 0; j < 4; j++)
      bfv[j] = *(const bf16x8*)(&Bs[(wave_n * 64 + j * 16 + fr) * SK + q * 8]);
#pragma unroll
    for (int i = 0; i < 4; i++)
#pragma unroll
      for (int j = 0; j < 4; j++)
        acc[i][j] = __builtin_amdgcn_mfma_f32_16x16x32_bf16(af[i], bfv[j], acc[i][j], 0, 0, 0);
    __syncthreads();
  }
#pragma unroll
  for (int i = 0; i < 4; i++)
#pragma unroll
    for (int j = 0; j < 4; j++) {
      const int mb = m0 + wave_m * 64 + i * 16 + q * 4;
      const int n = n0 + wave_n * 64 + j * 16 + fr;
#pragma unroll
      for (int r = 0; r < 4; r++)
        out[(size_t)(mb + r) * N + n] = acc[i][j][r];
    }
}

// ---------------------------------------------------------------------------
// Phase 1 (MFMA): per-(bh,chunk) chunked-DPLR operators, postproc FUSED.
// v3: Y-solve eliminated via Qloc = (I-L)^-1 (LKA·V): W = LKA·V by MFMA, then
// a single dual-RHS blocked triangular solve (4x16 blocks). Cross-block terms
// via MFMA bridge reading XTb/QTb (col-major, K-contiguous); only 16x16
// diagonal recurrences stay on fp32 VALU. Solve is barrier-free (intra-wave).
// ---------------------------------------------------------------------------
__global__ __launch_bounds__(256, 2) void chunk_ops_kernel(
    const unsigned short* __restrict__ r_btc, const unsigned short* __restrict__ k_btc,
    const float* __restrict__ v_btc, const unsigned short* __restrict__ wraw,
    const unsigned short* __restrict__ araw,
    const float* __restrict__ w0, const float* __restrict__ a0,
    const float* __restrict__ k_k, const float* __restrict__ k_a,
    const float* __restrict__ r_k,
    unsigned short* __restrict__ McG, unsigned short* __restrict__ NcG,
    unsigned short* __restrict__ PcG, unsigned short* __restrict__ OlG,
    unsigned short* __restrict__ DkG, float* __restrict__ s3G)
{
  extern __shared__ char smraw[];
  unsigned short* AHb  = (unsigned short*)smraw;   // S1: Ahat -> XTb
  unsigned short* RHb  = AHb + 64 * RS;            // S2: Rhat (bf16, thru E)
  unsigned short* BPb  = RHb + 64 * RS;            // S3: Bp -> LKA -> W -> QTb
  unsigned short* KPb  = BPb + 64 * RS;            // S4: Kp -> DBR
  unsigned short* BPTb = KPb + 64 * RS;            // S5: Btil^T [i][t]
  unsigned short* KPTb = BPTb + 64 * RS;           // S6: Ktil^T [i][t]
  unsigned short* VSTb = KPTb + 64 * RS;           // S7: V^T [n][t]
  unsigned short* LBb  = VSTb + 64 * RS;           // S8: LBA bf16 (s68)
  float* GLs = (float*)(LBb + 64 * LBS);           // [64] total log-decay
  float* SS  = GLs + 64;                           // [4][64] strip sums
  unsigned short* XTb = AHb;                       // overlay after solve
  unsigned short* LKb = BPb;                       // overlay after Gram (LKA, then W)
  unsigned short* QTb = BPb;                       // overlay after Q-solve
  unsigned short* DBb = KPb;                       // overlay after Gram

  const int inst = blockIdx.x;
  const int bh = inst >> 4, c = inst & 15;
  const int b = bh >> 4, h = bh & 15;
  const int tid = threadIdx.x;
  const int lane = tid & 63;
  const int wv = tid >> 6;
  const int jl = lane;
  const int ch = h * 64 + jl;
  const size_t base = ((size_t)(b * 1024 + c * 64) * 1024) + ch;

  const float p_w0 = w0[ch], p_a0 = a0[ch];
  const float p_kk = k_k[ch], p_ka = k_a[ch], p_rk = r_k[ch];
  const float EM = 0.60653065971263342f;  // e^{-0.5}

  // ---- prefetch ALL per-token global inputs into registers (80 loads) ----
  unsigned short wr_u[16], kv_u[16], rv_u[16], ar_u[16];
  float vv_u[16];
#pragma unroll
  for (int u = 0; u < 16; ++u) {
    const size_t gi = base + (size_t)(16 * wv + u) * 1024;
    wr_u[u] = wraw[gi];
    kv_u[u] = k_btc[gi];
    rv_u[u] = r_btc[gi];
    ar_u[u] = araw[gi];
    vv_u[u] = v_btc[gi];
  }

  // ---- pass 1: inclusive log-decay prefix for my 16 rows + strip sum ----
  float lwv[16];
  {
    float run = 0.f;
#pragma unroll
    for (int u = 0; u < 16; ++u) {
      run += -EM * sigmoidf_(p_w0 + bf2f(wr_u[u]));
      lwv[u] = run;                       // inclusive prefix within strip
    }
    SS[wv * 64 + jl] = run;
  }
  __syncthreads();
  const float s0 = SS[0 * 64 + jl], s1 = SS[1 * 64 + jl];
  const float s2 = SS[2 * 64 + jl], s3s = SS[3 * 64 + jl];
  const float goff = (wv > 0 ? s0 : 0.f) + (wv > 1 ? s1 : 0.f) + (wv > 2 ? s2 : 0.f);
  const float gl = s0 + s1 + s2 + s3s;
  if (wv == 0) GLs[jl] = gl;

  // ---- pass 2: per-token transforms + factor matrices (independent u) ----
  float s3v[16];
  {
    const float e_gl = __expf(gl);
#pragma unroll
    for (int u = 0; u < 16; ++u) {
      const int t = 16 * wv + u;
      const float pre = goff + (u ? lwv[u - 1] : 0.f);   // g_{t-1}
      const float cur = goff + lwv[u];                   // g_t
      const float kv = bf2f(kv_u[u]), rv = bf2f(rv_u[u]);
      const float vv = vv_u[u];
      const float av = sigmoidf_(p_a0 + bf2f(ar_u[u]));
      const float kkx = kv * p_kk;
      float ssq = kkx * kkx;
#pragma unroll
      for (int m = 1; m < 64; m <<= 1) ssq += __shfl_xor(ssq, m);
      const float scale = __builtin_amdgcn_rsqf(fmaxf(ssq, 1e-24f));
      const float kkn = kkx * scale;
      const float bb = kkn * av;
      const float kmod = kv * (1.0f + (av - 1.0f) * p_ka);
      float s3 = rv * kmod * p_rk;
#pragma unroll
      for (int m = 1; m < 64; m <<= 1) s3 += __shfl_xor(s3, m);
      s3v[u] = s3;
      const float e_prev = __expf(pre);                  // exp(g_{t-1})
      const float e_gu   = __expf(cur);                  // exp(g_t), <= 1
      const float em     = __expf(-cur);                 // exp(-g_t)
      const float egl    = e_gl * em;                    // exp(gl-g_t) <= 1
      AHb[t * RS + jl] = f2bf(-kkn * e_prev);
      BPb[t * RS + jl] = f2bf(bb * em);
      KPb[t * RS + jl] = f2bf(kmod * em);
      BPTb[jl * RS + t] = f2bf(bb * egl);
      KPTb[jl * RS + t] = f2bf(kmod * egl);
      RHb[t * RS + jl] = f2bf(rv * e_gu);
      VSTb[jl * RS + t] = f2bf(vv);
    }
    if (jl == 0) {
      float* sp = s3G + (bh << 10) + (c << 6) + 16 * wv;
#pragma unroll
      for (int k2 = 0; k2 < 4; ++k2)
        *(float4*)(sp + 4 * k2) = make_float4(s3v[4 * k2], s3v[4 * k2 + 1],
                                              s3v[4 * k2 + 2], s3v[4 * k2 + 3]);
    }
  }
  __syncthreads();

  const int fr = lane & 15, q = lane >> 4;
  const int i0 = wv * 16;

  // ---- Gram products via MFMA: LBA, LKA, DBR, DKR(->global) ----
  {
    f32x4 aLB[4], aLK[4], aDB[4], aDK[4];
#pragma unroll
    for (int j = 0; j < 4; ++j) {
      aLB[j] = (f32x4){0.f, 0.f, 0.f, 0.f}; aLK[j] = (f32x4){0.f, 0.f, 0.f, 0.f};
      aDB[j] = (f32x4){0.f, 0.f, 0.f, 0.f}; aDK[j] = (f32x4){0.f, 0.f, 0.f, 0.f};
    }
#pragma unroll
    for (int ks = 0; ks < 2; ++ks) {
      const int ko = ks * 32 + q * 8;
      bf16x8 fA = *(const bf16x8*)(AHb + (i0 + fr) * RS + ko);
      bf16x8 fR = *(const bf16x8*)(RHb + (i0 + fr) * RS + ko);
#pragma unroll
      for (int j = 0; j < 4; ++j) {
        bf16x8 fB = *(const bf16x8*)(BPb + (j * 16 + fr) * RS + ko);
        bf16x8 fK = *(const bf16x8*)(KPb + (j * 16 + fr) * RS + ko);
        aLB[j] = __builtin_amdgcn_mfma_f32_16x16x32_bf16(fA, fB, aLB[j], 0, 0, 0);
        aLK[j] = __builtin_amdgcn_mfma_f32_16x16x32_bf16(fA, fK, aLK[j], 0, 0, 0);
        aDB[j] = __builtin_amdgcn_mfma_f32_16x16x32_bf16(fR, fB, aDB[j], 0, 0, 0);
        aDK[j] = __builtin_amdgcn_mfma_f32_16x16x32_bf16(fR, fK, aDK[j], 0, 0, 0);
      }
    }
    __syncthreads();   // all Gram fragment reads done before overlay stores
#pragma unroll
    for (int j = 0; j < 4; ++j) {
      const int s = j * 16 + fr;
#pragma unroll
      for (int r = 0; r < 4; ++r) {
        const int t = i0 + q * 4 + r;
        LBb[t * LBS + s] = f2bf((s < t) ? aLB[j][r] : 0.f);
        LKb[t * RS + s] = f2bf((s < t) ? aLK[j][r] : 0.f);
        DBb[t * RS + s] = f2bf((s <= t) ? aDB[j][r] : 0.f);
        DkG[(size_t)inst * 4096 + t * 64 + s] = f2bf((s <= t) ? aDK[j][r] : 0.f);
      }
    }
  }
  __syncthreads();

  // ---- W = LKA · V (MFMA, all waves; replaces Y-solve + Qloc) ----
  {
    f32x4 wacc[4];
#pragma unroll
    for (int j = 0; j < 4; ++j) wacc[j] = (f32x4){0.f, 0.f, 0.f, 0.f};
#pragma unroll
    for (int ks = 0; ks < 2; ++ks) {
      const int ko = ks * 32 + q * 8;
      bf16x8 fL = *(const bf16x8*)(LKb + (i0 + fr) * RS + ko);
#pragma unroll
      for (int j = 0; j < 4; ++j) {
        bf16x8 fV = *(const bf16x8*)(VSTb + (j * 16 + fr) * RS + ko);
        wacc[j] = __builtin_amdgcn_mfma_f32_16x16x32_bf16(fL, fV, wacc[j], 0, 0, 0);
      }
    }
#pragma unroll
    for (int j = 0; j < 4; ++j)
#pragma unroll
      for (int r = 0; r < 4; ++r)
        LKb[(i0 + q * 4 + r) * RS + j * 16 + fr] = f2bf(wacc[j][r]);
  }
  __syncthreads();

  // ---- prefetch DKR fragments from global (L2-hot: our own writes) ----
  bf16x8 fDK0, fDK1;
  {
    const unsigned short* dkp = DkG + (size_t)inst * 4096 + (i0 + fr) * 64 + q * 8;
    fDK0 = *(const bf16x8*)(dkp);
    fDK1 = *(const bf16x8*)(dkp + 32);
  }

  // ---- blocked dual triangular solve (barrier-free, intra-wave):
  //      wave0: (I-L)X = Ahat  -> XTb[jc][t];  wave1: (I-L)Q = W -> QTb[jc][t]
  if (wv < 2) {
    const int jc = lane;
    unsigned short* Sb = (wv == 0) ? AHb : LKb;    // RHS (consumed into regs)
    unsigned short* Tb = (wv == 0) ? XTb : QTb;    // col-major solution [jc][t]
    float x[64];
#pragma unroll
    for (int t = 0; t < 64; ++t) x[t] = bf2f(Sb[t * RS + jc]);
    // zero my solution row: bridge MFMAs read 0 for not-yet-solved t
#pragma unroll
    for (int z2 = 0; z2 < 8; ++z2)
      *(bf16x8*)(Tb + jc * RS + z2 * 8) = (bf16x8){0, 0, 0, 0, 0, 0, 0, 0};

    const int jf = jc & 15, tjm = jc >> 4;

#pragma unroll
    for (int I = 0; I < 4; ++I) {
      if (I > 0) {
        // bridge: x[16I+u] += sum_{s<16I} L[16I+u][s] * sol[s][jc]  (MFMA)
        f32x4 cU[4];
#pragma unroll
        for (int tj = 0; tj < 4; ++tj) cU[tj] = (f32x4){0.f, 0.f, 0.f, 0.f};
#pragma unroll
        for (int kw = 0; kw < 2; ++kw) {
          if (kw * 32 < 16 * I) {
            const int ko = kw * 32 + q * 8;
            bf16x8 fL;
            *(ushort4*)&fL = *(const ushort4*)(LBb + (16 * I + fr) * LBS + ko);
            *((ushort4*)&fL + 1) = *(const ushort4*)(LBb + (16 * I + fr) * LBS + ko + 4);
#pragma unroll
            for (int tj = 0; tj < 4; ++tj) {
              bf16x8 fX = *(const bf16x8*)(Tb + (tj * 16 + fr) * RS + ko);
              cU[tj] = __builtin_amdgcn_mfma_f32_16x16x32_bf16(fL, fX, cU[tj], 0, 0, 0);
            }
          }
        }
        // redistribute MFMA C-layout to column-owner lanes
#pragma unroll
        for (int qq = 0; qq < 4; ++qq) {
          const int saddr = (qq * 16 + jf) * 4;
#pragma unroll
          for (int r = 0; r < 4; ++r) {
            int g0 = __builtin_amdgcn_ds_bpermute(saddr, __builtin_bit_cast(int, cU[0][r]));
            int g1 = __builtin_amdgcn_ds_bpermute(saddr, __builtin_bit_cast(int, cU[1][r]));
            int g2 = __builtin_amdgcn_ds_bpermute(saddr, __builtin_bit_cast(int, cU[2][r]));
            int g3 = __builtin_amdgcn_ds_bpermute(saddr, __builtin_bit_cast(int, cU[3][r]));
            int gs = (tjm == 0) ? g0 : (tjm == 1) ? g1 : (tjm == 2) ? g2 : g3;
            x[16 * I + qq * 4 + r] += __builtin_bit_cast(float, gs);
          }
        }
      }
      // diagonal 16x16 unit-lower solve (fp32 chain, bf16 L)
#pragma unroll
      for (int u = 1; u < 16; ++u) {
        const unsigned short* lr = LBb + (16 * I + u) * LBS + 16 * I;
        float acc0 = 0.f, acc1 = 0.f;
#pragma unroll
        for (int s = 0; s + 2 <= u; s += 2) {
          acc0 = fmaf(bf2f(lr[s]), x[16 * I + s], acc0);
          acc1 = fmaf(bf2f(lr[s + 1]), x[16 * I + s + 1], acc1);
        }
        if (u & 1) acc0 = fmaf(bf2f(lr[u - 1]), x[16 * I + u - 1], acc0);
        x[16 * I + u] += acc0 + acc1;
      }
      // store solved block of my column (bf16 pairs)
#pragma unroll
      for (int t2 = 0; t2 < 16; t2 += 2) {
        unsigned int pk = (unsigned int)f2bf(x[16 * I + t2])
                        | ((unsigned int)f2bf(x[16 * I + t2 + 1]) << 16);
        *(unsigned int*)(Tb + jc * RS + 16 * I + t2) = pk;
      }
    }
  }
  __syncthreads();

  // ---- final operators: Mc, Ncc, Pc, Oloc (MFMA) -> global bf16 ----
  {
    f32x4 mA[4], nA[4], pA[4], oA[4];
#pragma unroll
    for (int j = 0; j < 4; ++j) {
      mA[j] = (f32x4){0.f, 0.f, 0.f, 0.f}; nA[j] = (f32x4){0.f, 0.f, 0.f, 0.f};
      pA[j] = (f32x4){0.f, 0.f, 0.f, 0.f}; oA[j] = (f32x4){0.f, 0.f, 0.f, 0.f};
    }
#pragma unroll
    for (int ks = 0; ks < 2; ++ks) {
      const int ko = ks * 32 + q * 8;
      bf16x8 fBT = *(const bf16x8*)(BPTb + (i0 + fr) * RS + ko);
      bf16x8 fKT = *(const bf16x8*)(KPTb + (i0 + fr) * RS + ko);
      bf16x8 fDB = *(const bf16x8*)(DBb + (i0 + fr) * RS + ko);
      bf16x8 fDK = ks ? fDK1 : fDK0;
#pragma unroll
      for (int j = 0; j < 4; ++j) {
        bf16x8 fXT = *(const bf16x8*)(XTb + (j * 16 + fr) * RS + ko);
        bf16x8 fQT = *(const bf16x8*)(QTb + (j * 16 + fr) * RS + ko);
        bf16x8 fVT = *(const bf16x8*)(VSTb + (j * 16 + fr) * RS + ko);
        mA[j] = __builtin_amdgcn_mfma_f32_16x16x32_bf16(fBT, fXT, mA[j], 0, 0, 0);
        nA[j] = __builtin_amdgcn_mfma_f32_16x16x32_bf16(fBT, fQT, nA[j], 0, 0, 0);
        nA[j] = __builtin_amdgcn_mfma_f32_16x16x32_bf16(fKT, fVT, nA[j], 0, 0, 0);
        pA[j] = __builtin_amdgcn_mfma_f32_16x16x32_bf16(fDB, fXT, pA[j], 0, 0, 0);
        oA[j] = __builtin_amdgcn_mfma_f32_16x16x32_bf16(fDB, fQT, oA[j], 0, 0, 0);
        oA[j] = __builtin_amdgcn_mfma_f32_16x16x32_bf16(fDK, fVT, oA[j], 0, 0, 0);
      }
    }
    const size_t ob = (size_t)inst * 4096;
    float eg[4];
#pragma unroll
    for (int r = 0; r < 4; ++r) eg[r] = __expf(GLs[i0 + q * 4 + r]);
#pragma unroll
    for (int j = 0; j < 4; ++j) {
      const int col = j * 16 + fr;
#pragma unroll
      for (int r = 0; r < 4; ++r) {
        const int row = i0 + q * 4 + r;
        const size_t oi = ob + (size_t)row * 64 + col;
        McG[oi] = f2bf(mA[j][r] + (row == col ? eg[r] : 0.f));
        NcG[oi] = f2bf(nA[j][r]);
        PcG[oi] = f2bf(pA[j][r] + bf2f(RHb[row * RS + col]));
        OlG[oi] = f2bf(oA[j][r]);
      }
    }
  }
}

// ---------------------------------------------------------------------------
// Phase 2: sequential chunk-state propagation per (b,h): ST' = Mc ST + Ncc.
// ---------------------------------------------------------------------------
__global__ __launch_bounds__(256) void chunk_scan_kernel(
    const unsigned short* __restrict__ McG, const unsigned short* __restrict__ NcG,
    unsigned short* __restrict__ Sch)
{
  __shared__ float ST[64 * PAD];
  __shared__ float MB[64 * PAD];
  const int bh = blockIdx.x;
  const int tid = threadIdx.x;
  const int it = tid >> 4, jt = tid & 15;

#pragma unroll
  for (int q = 0; q < 16; ++q) {
    int idx = q * 256 + tid;
    ST[(idx >> 6) * PAD + (idx & 63)] = 0.f;
  }
  __syncthreads();

  for (int c = 0; c < 16; ++c) {
    const size_t ob = ((((size_t)bh << 4) + c) << 12);
#pragma unroll
    for (int q = 0; q < 4; ++q) {
      int idx = q * 1024 + tid * 4;
      int row = idx >> 6, col = idx & 63;
      ushort4 sv;
      sv.x = f2bf(ST[row * PAD + col]);     sv.y = f2bf(ST[row * PAD + col + 1]);
      sv.z = f2bf(ST[row * PAD + col + 2]); sv.w = f2bf(ST[row * PAD + col + 3]);
      *(ushort4*)(Sch + ob + idx) = sv;
      ushort4 mv = *(const ushort4*)(McG + ob + idx);
      MB[row * PAD + col] = bf2f(mv.x);     MB[row * PAD + col + 1] = bf2f(mv.y);
      MB[row * PAD + col + 2] = bf2f(mv.z); MB[row * PAD + col + 3] = bf2f(mv.w);
    }
    __syncthreads();
    float acc[4][4];
#pragma unroll
    for (int u = 0; u < 4; ++u) {
      ushort4 n4 = *(const ushort4*)(NcG + ob + (size_t)(4 * it + u) * 64 + 4 * jt);
      acc[u][0] = bf2f(n4.x); acc[u][1] = bf2f(n4.y);
      acc[u][2] = bf2f(n4.z); acc[u][3] = bf2f(n4.w);
    }
#pragma unroll 4
    for (int pp = 0; pp < 64; ++pp) {
      float mv[4], sv[4];
#pragma unroll
      for (int u = 0; u < 4; ++u) mv[u] = MB[(4 * it + u) * PAD + pp];
#pragma unroll
      for (int v = 0; v < 4; ++v) sv[v] = ST[pp * PAD + 4 * jt + v];
#pragma unroll
      for (int u = 0; u < 4; ++u)
#pragma unroll
        for (int v = 0; v < 4; ++v) acc[u][v] = fmaf(mv[u], sv[v], acc[u][v]);
    }
    __syncthreads();
#pragma unroll
    for (int u = 0; u < 4; ++u)
#pragma unroll
      for (int v = 0; v < 4; ++v) ST[(4 * it + u) * PAD + 4 * jt + v] = acc[u][v];
    __syncthreads();
  }
}

// ---------------------------------------------------------------------------
// Phase 3 + GroupNorm fused: Out = Pc ST + Oloc; per-row norm; + s3*v; *g.
// ---------------------------------------------------------------------------
__global__ __launch_bounds__(256) void chunk_outgn_kernel(
    const unsigned short* __restrict__ PcG, const unsigned short* __restrict__ OlG,
    const unsigned short* __restrict__ Sch, const float* __restrict__ s3G,
    const float* __restrict__ v_btc, const unsigned short* __restrict__ g_f,
    const float* __restrict__ gamma, const float* __restrict__ beta,
    unsigned short* __restrict__ yg)
{
  __shared__ float ST[64 * PAD];
  __shared__ float PB[64 * PAD];
  const int inst = blockIdx.x;
  const int bh = inst >> 4, c = inst & 15;
  const int b = bh >> 4, h = bh & 15;
  const int tid = threadIdx.x;
  const int tt = tid >> 4, jt = tid & 15;
  const size_t ob = (size_t)inst << 12;

#pragma unroll
  for (int q = 0; q < 4; ++q) {
    int idx = q * 1024 + tid * 4;
    int row = idx >> 6, col = idx & 63;
    ushort4 sv = *(const ushort4*)(Sch + ob + idx);
    ST[row * PAD + col] = bf2f(sv.x);     ST[row * PAD + col + 1] = bf2f(sv.y);
    ST[row * PAD + col + 2] = bf2f(sv.z); ST[row * PAD + col + 3] = bf2f(sv.w);
    ushort4 pv = *(const ushort4*)(PcG + ob + idx);
    PB[row * PAD + col] = bf2f(pv.x);     PB[row * PAD + col + 1] = bf2f(pv.y);
    PB[row * PAD + col + 2] = bf2f(pv.z); PB[row * PAD + col + 3] = bf2f(pv.w);
  }
  __syncthreads();

  float acc[4][4];
#pragma unroll
  for (int u = 0; u < 4; ++u) {
    ushort4 o4 = *(const ushort4*)(OlG + ob + (size_t)(4 * tt + u) * 64 + 4 * jt);
    acc[u][0] = bf2f(o4.x); acc[u][1] = bf2f(o4.y);
    acc[u][2] = bf2f(o4.z); acc[u][3] = bf2f(o4.w);
  }
#pragma unroll 4
  for (int pp = 0; pp < 64; ++pp) {
    float pv[4], sv[4];
#pragma unroll
    for (int u = 0; u < 4; ++u) pv[u] = PB[(4 * tt + u) * PAD + pp];
#pragma unroll
    for (int v = 0; v < 4; ++v) sv[v] = ST[pp * PAD + 4 * jt + v];
#pragma unroll
    for (int u = 0; u < 4; ++u)
#pragma unroll
      for (int v = 0; v < 4; ++v) acc[u][v] = fmaf(pv[u], sv[v], acc[u][v]);
  }

  const int colb = h * 64 + 4 * jt;
  float4 ga4 = *(const float4*)(gamma + colb);
  float4 be4 = *(const float4*)(beta + colb);

#pragma unroll
  for (int u = 0; u < 4; ++u) {
    float sum1 = acc[u][0] + acc[u][1] + acc[u][2] + acc[u][3];
    float sum2 = acc[u][0] * acc[u][0] + acc[u][1] * acc[u][1]
               + acc[u][2] * acc[u][2] + acc[u][3] * acc[u][3];
#pragma unroll
    for (int m = 1; m < 16; m <<= 1) {
      sum1 += __shfl_xor(sum1, m);
      sum2 += __shfl_xor(sum2, m);
    }
    const float mean = sum1 * (1.0f / 64.0f);
    const float var = sum2 * (1.0f / 64.0f) - mean * mean;
    const float rstd = __builtin_amdgcn_rsqf(var + 0.00064f);
    const int tok = c * 64 + 4 * tt + u;
    const float s3 = s3G[(bh << 10) + tok];
    const size_t gaddr = ((size_t)(b * 1024 + tok) * 1024) + colb;
    float4 v4 = *(const float4*)(v_btc + gaddr);
    ushort4 g4b = *(const ushort4*)(g_f + gaddr);
    ushort4 ov;
    ov.x = f2bf(((acc[u][0] - mean) * rstd * ga4.x + be4.x + s3 * v4.x) * bf2f(g4b.x));
    ov.y = f2bf(((acc[u][1] - mean) * rstd * ga4.y + be4.y + s3 * v4.y) * bf2f(g4b.y));
    ov.z = f2bf(((acc[u][2] - mean) * rstd * ga4.z + be4.z + s3 * v4.z) * bf2f(g4b.z));
    ov.w = f2bf(((acc[u][3] - mean) * rstd * ga4.w + be4.w + s3 * v4.w) * bf2f(g4b.w));
    *(ushort4*)(yg + gaddr) = ov;
  }
}

// ---------------------------------------------------------------------------
extern "C" void kernel_launch(void* const* d_in, const int* in_sizes, int n_in,
                              void* d_out, int out_size, void* d_ws, size_t ws_size,
                              hipStream_t stream)
{
  (void)in_sizes; (void)n_in; (void)out_size;
  const float* x    = (const float*)d_in[0];
  const float* x_r  = (const float*)d_in[1];
  const float* x_w  = (const float*)d_in[2];
  const float* x_k  = (const float*)d_in[3];
  const float* x_v  = (const float*)d_in[4];
  const float* x_a  = (const float*)d_in[5];
  const float* x_g  = (const float*)d_in[6];
  const float* w0   = (const float*)d_in[7];
  const float* w1   = (const float*)d_in[8];
  const float* w2   = (const float*)d_in[9];
  const float* a0   = (const float*)d_in[10];
  const float* a1   = (const float*)d_in[11];
  const float* a2   = (const float*)d_in[12];
  const float* g1   = (const float*)d_in[16];
  const float* g2   = (const float*)d_in[17];
  const float* k_k  = (const float*)d_in[18];
  const float* k_a  = (const float*)d_in[19];
  const float* r_k  = (const float*)d_in[20];
  const float* Wr   = (const float*)d_in[21];
  const float* Wk   = (const float*)d_in[22];
  const float* Wv   = (const float*)d_in[23];
  const float* Wo   = (const float*)d_in[24];
  const float* ln_g = (const float*)d_in[25];
  const float* ln_b = (const float*)d_in[26];

  float* outp = (float*)d_out;
  float* vfirst = outp + (size_t)BB * TT * CCH;

  char* ws = (char*)d_ws;
  size_t off = 0;
  auto alloc = [&](size_t bytes) -> char* {
    char* p = ws + off;
    off += (bytes + 255) & ~(size_t)255;
    return p;
  };

  unsigned short* WrT = (unsigned short*)alloc(2097152);
  unsigned short* WkT = (unsigned short*)alloc(2097152);
  unsigned short* WvT = (unsigned short*)alloc(2097152);
  unsigned short* WoT = (unsigned short*)alloc(2097152);
  unsigned short* w1T = (unsigned short*)alloc(131072);
  unsigned short* w2T = (unsigned short*)alloc(131072);
  unsigned short* a1T = (unsigned short*)alloc(131072);
  unsigned short* a2T = (unsigned short*)alloc(131072);
  unsigned short* g1T = (unsigned short*)alloc(262144);
  unsigned short* g2T = (unsigned short*)alloc(262144);
  unsigned short* xrB = (unsigned short*)alloc(8388608);
  unsigned short* xwB = (unsigned short*)alloc(8388608);
  unsigned short* xkB = (unsigned short*)alloc(8388608);
  unsigned short* xvB = (unsigned short*)alloc(8388608);
  unsigned short* xaB = (unsigned short*)alloc(8388608);
  unsigned short* xgB = (unsigned short*)alloc(8388608);
  unsigned short* r_btc = (unsigned short*)alloc(8388608);
  unsigned short* k_btc = (unsigned short*)alloc(8388608);
  unsigned short* wraw  = (unsigned short*)alloc(8388608);
  unsigned short* araw  = (unsigned short*)alloc(8388608);
  unsigned short* gfB = (unsigned short*)alloc(8388608);
  unsigned short* OlG = (unsigned short*)alloc(8388608);
  unsigned short* DkG = (unsigned short*)alloc(8388608);
  float* s3G   = (float*)alloc(262144);
  unsigned short* hwB = (unsigned short*)alloc(524288);
  unsigned short* haB = (unsigned short*)alloc(524288);
  unsigned short* hgB = (unsigned short*)alloc(1048576);
  unsigned short* ygB = (unsigned short*)alloc(8388608);

  // overlays (owners dead before the writer runs)
  unsigned short* McG = xrB;          // over xrB (dead after gemm_stage1)
  unsigned short* NcG = xkB;          // over xkB
  unsigned short* PcG = xaB;          // over xaB
  unsigned short* Sch = k_btc;        // k_btc dead after chunk_ops

  if (off > ws_size) return;

  dim3 blk(256);

  // transposes + mix in one launch
  prep_kernel<<<5248, blk, 0, stream>>>(
      x, x_r, x_w, x_k, x_v, x_a, x_g,
      xrB, xwB, xkB, xvB, xaB, xgB,
      Wr, Wk, Wv, Wo, WrT, WkT, WvT, WoT,
      w1, w2, a1, a2, g1, g2, w1T, w2T, a1T, a2T, g1T, g2T);

  // r/k/v GEMMs + lora1 in one launch; v straight into vfirst (output 1)
  gemm_stage1_kernel<<<896, blk, 0, stream>>>(
      xrB, xkB, xvB, WrT, WkT, WvT, r_btc, k_btc, vfirst,
      xwB, xaB, xgB, w1T, a1T, g1T, hwB, haB, hgB);

  // LoRA stage 2 (w/a/g) in one launch
  lora2_kernel<<<dim3(32, 8, 3), blk, 0, stream>>>(
      hwB, haB, hgB, w2T, a2T, g2T, wraw, araw, gfB);

  // chunked-DPLR scan phase 1 (postproc fused, 2 blocks/CU)
  constexpr int CHUNK_LDS = 7 * 64 * RS * 2 + 64 * LBS * 2 + 64 * 4 + 4 * 64 * 4;
  hipFuncSetAttribute((const void*)chunk_ops_kernel,
                      hipFuncAttributeMaxDynamicSharedMemorySize, CHUNK_LDS);
  chunk_ops_kernel<<<1024, blk, CHUNK_LDS, stream>>>(
      r_btc, k_btc, vfirst, wraw, araw, w0, a0, k_k, k_a, r_k,
      McG, NcG, PcG, OlG, DkG, s3G);

  chunk_scan_kernel<<<64, blk, 0, stream>>>(McG, NcG, Sch);

  chunk_outgn_kernel<<<1024, blk, 0, stream>>>(PcG, OlG, Sch, s3G, vfirst, gfB,
                                               ln_g, ln_b, ygB);

  gemm_out_kernel<<<dim3(32, 8), blk, 0, stream>>>(ygB, WoT, outp);
}

// Round 9
// 317.587 us; speedup vs baseline: 1.1668x; 1.1049x over previous
//
#include <hip/hip_runtime.h>
#include <hip/hip_bf16.h>
#include <math.h>

// Problem constants
#define BB 4
#define TT 1024
#define CCH 1024
#define HH 16
#define NNd 64
#define PAD 65      // fp32 LDS row pad (outgn)
#define RS 72       // bf16 LDS row stride in shorts (144B = 9x16B, frag-aligned)
#define LBS 68      // bf16 L-matrix row stride in shorts (136B, 8B-aligned u4)

typedef short bf16x8 __attribute__((ext_vector_type(8)));
typedef float f32x4 __attribute__((ext_vector_type(4)));

__device__ __forceinline__ unsigned short f2bf(float f) {
  __hip_bfloat16 h = __float2bfloat16(f);
  return __builtin_bit_cast(unsigned short, h);
}
__device__ __forceinline__ float bf2f(unsigned short u) {
  unsigned int x = (unsigned int)u << 16;
  return __builtin_bit_cast(float, x);
}
// Native transcendentals: outputs all round through bf16 downstream, so
// v_exp/v_rcp/v_rsq (~1 ulp) precision is far below bf16 quantization.
__device__ __forceinline__ float sigmoidf_(float x) {
  return __builtin_amdgcn_rcpf(1.0f + __expf(-x));
}
__device__ __forceinline__ float ftanh_(float x) {
  // tanh(x) = 1 - 2/(e^{2x}+1); saturates correctly at +/-inf.
  return 1.0f - 2.0f * __builtin_amdgcn_rcpf(__expf(2.0f * x) + 1.0f);
}

// async global->LDS, 16B per lane; LDS dest must be wave-uniform base + 16*lane
__device__ __forceinline__ void gl2lds16(const unsigned short* g, unsigned short* l) {
  __builtin_amdgcn_global_load_lds(
      (const __attribute__((address_space(1))) unsigned int*)g,
      (__attribute__((address_space(3))) unsigned int*)l, 16, 0, 0);
}

// ---------------------------------------------------------------------------
// Transpose tile helper
// ---------------------------------------------------------------------------
__device__ __forceinline__ void transpose_tile(
    const float* __restrict__ in, unsigned short* __restrict__ out,
    int R, int Cc, int r0, int c0, unsigned short (*tile)[68], int t)
{
  const int rr = t >> 4;
  const int cc = (t & 15) * 4;
#pragma unroll
  for (int p = 0; p < 4; ++p) {
    int row = p * 16 + rr;
    float4 v = *(const float4*)(in + (size_t)(r0 + row) * Cc + c0 + cc);
    tile[row][cc]     = f2bf(v.x);
    tile[row][cc + 1] = f2bf(v.y);
    tile[row][cc + 2] = f2bf(v.z);
    tile[row][cc + 3] = f2bf(v.w);
  }
  __syncthreads();
#pragma unroll
  for (int p = 0; p < 4; ++p) {
    int row = p * 16 + rr;
    ushort4 o;
    o.x = tile[cc][row];
    o.y = tile[cc + 1][row];
    o.z = tile[cc + 2][row];
    o.w = tile[cc + 3][row];
    *(ushort4*)(out + (size_t)(c0 + row) * R + r0 + cc) = o;
  }
}

// ---------------------------------------------------------------------------
// prep_kernel: mix (blocks 0..4095) + big4 transposes (4096..5119)
//            + lora transposes (5120..5247), one launch.
// [v5 note: round-5 A/B showed fusing the mix into gemm_stage1 regresses
//  (async global_load_lds staging beats reg-staged fp32 mix, 64->102us);
//  the separate mix pass is the measured-best structure.]
// ---------------------------------------------------------------------------
__global__ __launch_bounds__(256) void prep_kernel(
    const float* __restrict__ x,
    const float* __restrict__ cr, const float* __restrict__ cw,
    const float* __restrict__ ck, const float* __restrict__ cv,
    const float* __restrict__ ca, const float* __restrict__ cg,
    unsigned short* __restrict__ xr, unsigned short* __restrict__ xw,
    unsigned short* __restrict__ xk, unsigned short* __restrict__ xv,
    unsigned short* __restrict__ xa, unsigned short* __restrict__ xg,
    const float* __restrict__ W0, const float* __restrict__ W1,
    const float* __restrict__ W2, const float* __restrict__ W3,
    unsigned short* __restrict__ T0, unsigned short* __restrict__ T1,
    unsigned short* __restrict__ T2, unsigned short* __restrict__ T3,
    const float* __restrict__ w1, const float* __restrict__ w2,
    const float* __restrict__ a1, const float* __restrict__ a2,
    const float* __restrict__ g1, const float* __restrict__ g2,
    unsigned short* __restrict__ w1T, unsigned short* __restrict__ w2T,
    unsigned short* __restrict__ a1T, unsigned short* __restrict__ a2T,
    unsigned short* __restrict__ g1T, unsigned short* __restrict__ g2T)
{
  __shared__ unsigned short tile[64][68];
  const int blk = blockIdx.x;
  const int tid = threadIdx.x;
  if (blk < 4096) {
    // ---- token-shift mix ----
    const size_t idx = ((size_t)blk * 256 + tid) * 4;
    const int c = (int)(idx & 1023);
    const int t = (int)((idx >> 10) & 1023);
    float4 xc = *(const float4*)(x + idx);
    float4 xp = make_float4(0.f, 0.f, 0.f, 0.f);
    if (t > 0) xp = *(const float4*)(x + idx - 1024);
    float4 dx = make_float4(xp.x - xc.x, xp.y - xc.y, xp.z - xc.z, xp.w - xc.w);
    auto st = [&](unsigned short* dst, const float* coef) {
      float4 w = *(const float4*)(coef + c);
      ushort4 o;
      o.x = f2bf(fmaf(dx.x, w.x, xc.x));
      o.y = f2bf(fmaf(dx.y, w.y, xc.y));
      o.z = f2bf(fmaf(dx.z, w.z, xc.z));
      o.w = f2bf(fmaf(dx.w, w.w, xc.w));
      *(ushort4*)(dst + idx) = o;
    };
    st(xr, cr); st(xw, cw); st(xk, ck); st(xv, cv); st(xa, ca); st(xg, cg);
  } else if (blk < 5120) {
    const int j = blk - 4096;
    const int z = j >> 8, rem = j & 255;
    const int ty = rem >> 4, tx = rem & 15;
    const float* src = (z == 0) ? W0 : (z == 1) ? W1 : (z == 2) ? W2 : W3;
    unsigned short* dst = (z == 0) ? T0 : (z == 1) ? T1 : (z == 2) ? T2 : T3;
    transpose_tile(src, dst, 1024, 1024, tx * 64, ty * 64, tile, tid);
  } else {
    const int i = blk - 5120;
    const float* src; unsigned short* dst; int R, C, rt, ct;
    if (i < 16)      { src = w1; dst = w1T; R = 1024; C = 64;   rt = i;      ct = 0; }
    else if (i < 32) { src = w2; dst = w2T; R = 64;   C = 1024; rt = 0;      ct = i - 16; }
    else if (i < 48) { src = a1; dst = a1T; R = 1024; C = 64;   rt = i - 32; ct = 0; }
    else if (i < 64) { src = a2; dst = a2T; R = 64;   C = 1024; rt = 0;      ct = i - 48; }
    else if (i < 96) { int k = i - 64; src = g1; dst = g1T; R = 1024; C = 128; rt = k >> 1; ct = k & 1; }
    else             { int k = i - 96; src = g2; dst = g2T; R = 128; C = 1024; rt = k & 1;  ct = k >> 1; }
    transpose_tile(src, dst, R, C, rt * 64, ct * 64, tile, tid);
  }
}

// ---------------------------------------------------------------------------
// gemm_stage1: blocks 0..767 = r/k/v big GEMMs (z=blk/256), 768..895 = lora1.
// r,k outputs bf16 (chunk_ops-only consumers); v output fp32 (vfirst).
// ---------------------------------------------------------------------------
__global__ __launch_bounds__(256) void gemm_stage1_kernel(
    const unsigned short* __restrict__ xrB, const unsigned short* __restrict__ xkB,
    const unsigned short* __restrict__ xvB,
    const unsigned short* __restrict__ WrT, const unsigned short* __restrict__ WkT,
    const unsigned short* __restrict__ WvT,
    unsigned short* __restrict__ r_btc, unsigned short* __restrict__ k_btc,
    float* __restrict__ v_btc,
    const unsigned short* __restrict__ xwB, const unsigned short* __restrict__ xaB,
    const unsigned short* __restrict__ xgB,
    const unsigned short* __restrict__ w1T, const unsigned short* __restrict__ a1T,
    const unsigned short* __restrict__ g1T,
    unsigned short* __restrict__ hwB, unsigned short* __restrict__ haB,
    unsigned short* __restrict__ hgB)
{
  constexpr int K = 1024, SK = 32;
  __shared__ __align__(16) unsigned short As[128 * SK];
  __shared__ __align__(16) unsigned short Bs[128 * SK];
  const int blk = blockIdx.x;
  const int tid = threadIdx.x;
  const int wv = tid >> 6, lane = tid & 63;
  const int fr = lane & 15, q = lane >> 4;
  const int arow = tid >> 2;
  const int akc = (tid & 3) * 8;

  if (blk < 768) {
    // ---- big3 GEMM: z selects r/k/v ----
    const int z = blk >> 8, rem = blk & 255;
    const int m0 = (rem & 31) * 128;
    const int n0 = (rem >> 5) * 128;
    const unsigned short* A = (z == 0) ? xrB : (z == 1) ? xkB : xvB;
    const unsigned short* BT = (z == 0) ? WrT : (z == 1) ? WkT : WvT;
    const int wave_m = wv >> 1, wave_n = wv & 1;

    f32x4 acc[4][4];
#pragma unroll
    for (int i = 0; i < 4; i++)
#pragma unroll
      for (int j = 0; j < 4; j++) acc[i][j] = (f32x4){0.f, 0.f, 0.f, 0.f};

    for (int k0 = 0; k0 < K; k0 += 32) {
#pragma unroll
      for (int i = 0; i < 2; ++i)
        gl2lds16(A + (size_t)(m0 + arow + i * 64) * K + k0 + akc, As + i * 2048 + wv * 512);
#pragma unroll
      for (int i = 0; i < 2; ++i)
        gl2lds16(BT + (size_t)(n0 + arow + i * 64) * K + k0 + akc, Bs + i * 2048 + wv * 512);
      __syncthreads();
      bf16x8 af[4], bfv[4];
#pragma unroll
      for (int i = 0; i < 4; i++)
        af[i] = *(const bf16x8*)(&As[(wave_m * 64 + i * 16 + fr) * SK + q * 8]);
#pragma unroll
      for (int j = 0; j < 4; j++)
        bfv[j] = *(const bf16x8*)(&Bs[(wave_n * 64 + j * 16 + fr) * SK + q * 8]);
#pragma unroll
      for (int i = 0; i < 4; i++)
#pragma unroll
        for (int j = 0; j < 4; j++)
          acc[i][j] = __builtin_amdgcn_mfma_f32_16x16x32_bf16(af[i], bfv[j], acc[i][j], 0, 0, 0);
      __syncthreads();
    }
#pragma unroll
    for (int i = 0; i < 4; i++)
#pragma unroll
      for (int j = 0; j < 4; j++) {
        const int mb = m0 + wave_m * 64 + i * 16 + q * 4;
        const int n = n0 + wave_n * 64 + j * 16 + fr;
#pragma unroll
        for (int r = 0; r < 4; r++) {
          if (z == 0)      r_btc[(size_t)(mb + r) * 1024 + n] = f2bf(acc[i][j][r]);
          else if (z == 1) k_btc[(size_t)(mb + r) * 1024 + n] = f2bf(acc[i][j][r]);
          else             v_btc[(size_t)(mb + r) * 1024 + n] = acc[i][j][r];
        }
      }
  } else {
    // ---- lora1: y=0 hw=tanh, y=1 ha, y=2/3 hg sigmoid halves ----
    const int j2 = blk - 768;
    const int y = j2 >> 5;
    const int m0 = (j2 & 31) * 128;
    const unsigned short* A  = (y == 0) ? xwB : (y == 1) ? xaB : xgB;
    const unsigned short* BT = (y == 0) ? w1T : (y == 1) ? a1T : (g1T + (size_t)(y - 2) * 64 * K);
    unsigned short* outb = (y == 0) ? hwB : (y == 1) ? haB : hgB;
    const int Nout = (y < 2) ? 64 : 128;
    const int ncol0 = (y < 2) ? 0 : (y - 2) * 64;

    f32x4 acc[2][4];
#pragma unroll
    for (int i = 0; i < 2; i++)
#pragma unroll
      for (int j = 0; j < 4; j++) acc[i][j] = (f32x4){0.f, 0.f, 0.f, 0.f};

    for (int k0 = 0; k0 < K; k0 += 32) {
#pragma unroll
      for (int i = 0; i < 2; ++i)
        gl2lds16(A + (size_t)(m0 + arow + i * 64) * K + k0 + akc, As + i * 2048 + wv * 512);
      gl2lds16(BT + (size_t)arow * K + k0 + akc, Bs + wv * 512);
      __syncthreads();
      bf16x8 af[2], bfv[4];
#pragma unroll
      for (int i = 0; i < 2; i++)
        af[i] = *(const bf16x8*)(&As[(wv * 32 + i * 16 + fr) * SK + q * 8]);
#pragma unroll
      for (int j = 0; j < 4; j++)
        bfv[j] = *(const bf16x8*)(&Bs[(j * 16 + fr) * SK + q * 8]);
#pragma unroll
      for (int i = 0; i < 2; i++)
#pragma unroll
        for (int j = 0; j < 4; j++)
          acc[i][j] = __builtin_amdgcn_mfma_f32_16x16x32_bf16(af[i], bfv[j], acc[i][j], 0, 0, 0);
      __syncthreads();
    }
#pragma unroll
    for (int i = 0; i < 2; i++)
#pragma unroll
      for (int j = 0; j < 4; j++) {
        const int mb = m0 + wv * 32 + i * 16 + q * 4;
        const int n = ncol0 + j * 16 + fr;
#pragma unroll
        for (int r = 0; r < 4; r++) {
          float val = acc[i][j][r];
          if (y == 0) val = ftanh_(val);
          else if (y >= 2) val = sigmoidf_(val);
          outb[(size_t)(mb + r) * Nout + n] = f2bf(val);
        }
      }
  }
}

// z-batched LoRA-2 GEMMs -> all bf16 outputs (wraw, araw, g).
__global__ __launch_bounds__(256) void lora2_kernel(
    const unsigned short* __restrict__ hwB, const unsigned short* __restrict__ haB,
    const unsigned short* __restrict__ hgB,
    const unsigned short* __restrict__ w2T, const unsigned short* __restrict__ a2T,
    const unsigned short* __restrict__ g2T,
    unsigned short* __restrict__ wraw, unsigned short* __restrict__ araw,
    unsigned short* __restrict__ gfB)
{
  constexpr int N = 1024, SK = 32;
  __shared__ __align__(16) unsigned short As[128 * SK];
  __shared__ __align__(16) unsigned short Bs[128 * SK];
  const int z = blockIdx.z;
  const unsigned short* A = (z == 0) ? hwB : (z == 1) ? haB : hgB;
  const unsigned short* BT = (z == 0) ? w2T : (z == 1) ? a2T : g2T;
  unsigned short* out = (z == 0) ? wraw : (z == 1) ? araw : gfB;
  const int K = (z == 2) ? 128 : 64;

  const int tid = threadIdx.x;
  const int wv = tid >> 6, lane = tid & 63;
  const int fr = lane & 15, q = lane >> 4;
  const int wave_m = wv >> 1, wave_n = wv & 1;
  const int m0 = blockIdx.x * 128;
  const int n0 = blockIdx.y * 128;

  f32x4 acc[4][4];
#pragma unroll
  for (int i = 0; i < 4; i++)
#pragma unroll
    for (int j = 0; j < 4; j++) acc[i][j] = (f32x4){0.f, 0.f, 0.f, 0.f};

  const int arow = tid >> 2;
  const int akc = (tid & 3) * 8;

  for (int k0 = 0; k0 < K; k0 += 32) {
#pragma unroll
    for (int i = 0; i < 2; ++i)
      gl2lds16(A + (size_t)(m0 + arow + i * 64) * K + k0 + akc, As + i * 2048 + wv * 512);
#pragma unroll
    for (int i = 0; i < 2; ++i)
      gl2lds16(BT + (size_t)(n0 + arow + i * 64) * K + k0 + akc, Bs + i * 2048 + wv * 512);
    __syncthreads();
    bf16x8 af[4], bfv[4];
#pragma unroll
    for (int i = 0; i < 4; i++)
      af[i] = *(const bf16x8*)(&As[(wave_m * 64 + i * 16 + fr) * SK + q * 8]);
#pragma unroll
    for (int j = 0; j < 4; j++)
      bfv[j] = *(const bf16x8*)(&Bs[(wave_n * 64 + j * 16 + fr) * SK + q * 8]);
#pragma unroll
    for (int i = 0; i < 4; i++)
#pragma unroll
      for (int j = 0; j < 4; j++)
        acc[i][j] = __builtin_amdgcn_mfma_f32_16x16x32_bf16(af[i], bfv[j], acc[i][j], 0, 0, 0);
    __syncthreads();
  }
#pragma unroll
  for (int i = 0; i < 4; i++)
#pragma unroll
    for (int j = 0; j < 4; j++) {
      const int mb = m0 + wave_m * 64 + i * 16 + q * 4;
      const int n = n0 + wave_n * 64 + j * 16 + fr;
#pragma unroll
      for (int r = 0; r < 4; r++)
        out[(size_t)(mb + r) * N + n] = f2bf(acc[i][j][r]);
    }
}

// Final projection GEMM (yg @ WoT -> out fp32)
__global__ __launch_bounds__(256) void gemm_out_kernel(
    const unsigned short* __restrict__ A,
    const unsigned short* __restrict__ BT,
    float* __restrict__ out)
{
  constexpr int K = 1024, N = 1024, SK = 32;
  __shared__ __align__(16) unsigned short As[128 * SK];
  __shared__ __align__(16) unsigned short Bs[128 * SK];
  const int tid = threadIdx.x;
  const int wv = tid >> 6, lane = tid & 63;
  const int fr = lane & 15, q = lane >> 4;
  const int wave_m = wv >> 1, wave_n = wv & 1;
  const int m0 = blockIdx.x * 128;
  const int n0 = blockIdx.y * 128;

  f32x4 acc[4][4];
#pragma unroll
  for (int i = 0; i < 4; i++)
#pragma unroll
    for (int j = 0; j < 4; j++) acc[i][j] = (f32x4){0.f, 0.f, 0.f, 0.f};

  const int arow = tid >> 2;
  const int akc = (tid & 3) * 8;

  for (int k0 = 0; k0 < K; k0 += 32) {
#pragma unroll
    for (int i = 0; i < 2; ++i)
      gl2lds16(A + (size_t)(m0 + arow + i * 64) * K + k0 + akc, As + i * 2048 + wv * 512);
#pragma unroll
    for (int i = 0; i < 2; ++i)
      gl2lds16(BT + (size_t)(n0 + arow + i * 64) * K + k0 + akc, Bs + i * 2048 + wv * 512);
    __syncthreads();
    bf16x8 af[4], bfv[4];
#pragma unroll
    for (int i = 0; i < 4; i++)
      af[i] = *(const bf16x8*)(&As[(wave_m * 64 + i * 16 + fr) * SK + q * 8]);
#pragma unroll
    for (int j = 0; j < 4; j++)
      bfv[j] = *(const bf16x8*)(&Bs[(wave_n * 64 + j * 16 + fr) * SK + q * 8]);
#pragma unroll
    for (int i = 0; i < 4; i++)
#pragma unroll
      for (int j = 0; j < 4; j++)
        acc[i][j] = __builtin_amdgcn_mfma_f32_16x16x32_bf16(af[i], bfv[j], acc[i][j], 0, 0, 0);
    __syncthreads();
  }
#pragma unroll
  for (int i = 0; i < 4; i++)
#pragma unroll
    for (int j = 0; j < 4; j++) {
      const int mb = m0 + wave_m * 64 + i * 16 + q * 4;
      const int n = n0 + wave_n * 64 + j * 16 + fr;
#pragma unroll
      for (int r = 0; r < 4; r++)
        out[(size_t)(mb + r) * N + n] = acc[i][j][r];
    }
}

// ---------------------------------------------------------------------------
// Phase 1 (MFMA): per-(bh,chunk) chunked-DPLR operators, postproc FUSED.
// v3: Y-solve eliminated via Qloc = (I-L)^-1 (LKA·V): W = LKA·V by MFMA, then
// a single dual-RHS blocked triangular solve (4x16 blocks). Cross-block terms
// via MFMA bridge reading XTb/QTb (col-major, K-contiguous); only 16x16
// diagonal recurrences stay on fp32 VALU. Solve is barrier-free (intra-wave).
// ---------------------------------------------------------------------------
__global__ __launch_bounds__(256, 2) void chunk_ops_kernel(
    const unsigned short* __restrict__ r_btc, const unsigned short* __restrict__ k_btc,
    const float* __restrict__ v_btc, const unsigned short* __restrict__ wraw,
    const unsigned short* __restrict__ araw,
    const float* __restrict__ w0, const float* __restrict__ a0,
    const float* __restrict__ k_k, const float* __restrict__ k_a,
    const float* __restrict__ r_k,
    unsigned short* __restrict__ McG, unsigned short* __restrict__ NcG,
    unsigned short* __restrict__ PcG, unsigned short* __restrict__ OlG,
    unsigned short* __restrict__ DkG, float* __restrict__ s3G)
{
  extern __shared__ char smraw[];
  unsigned short* AHb  = (unsigned short*)smraw;   // S1: Ahat -> XTb
  unsigned short* RHb  = AHb + 64 * RS;            // S2: Rhat (bf16, thru E)
  unsigned short* BPb  = RHb + 64 * RS;            // S3: Bp -> LKA -> W -> QTb
  unsigned short* KPb  = BPb + 64 * RS;            // S4: Kp -> DBR
  unsigned short* BPTb = KPb + 64 * RS;            // S5: Btil^T [i][t]
  unsigned short* KPTb = BPTb + 64 * RS;           // S6: Ktil^T [i][t]
  unsigned short* VSTb = KPTb + 64 * RS;           // S7: V^T [n][t]
  unsigned short* LBb  = VSTb + 64 * RS;           // S8: LBA bf16 (s68)
  float* GLs = (float*)(LBb + 64 * LBS);           // [64] total log-decay
  float* SS  = GLs + 64;                           // [4][64] strip sums
  unsigned short* XTb = AHb;                       // overlay after solve
  unsigned short* LKb = BPb;                       // overlay after Gram (LKA, then W)
  unsigned short* QTb = BPb;                       // overlay after Q-solve
  unsigned short* DBb = KPb;                       // overlay after Gram

  const int inst = blockIdx.x;
  const int bh = inst >> 4, c = inst & 15;
  const int b = bh >> 4, h = bh & 15;
  const int tid = threadIdx.x;
  const int lane = tid & 63;
  const int wv = tid >> 6;
  const int jl = lane;
  const int ch = h * 64 + jl;
  const size_t base = ((size_t)(b * 1024 + c * 64) * 1024) + ch;

  const float p_w0 = w0[ch], p_a0 = a0[ch];
  const float p_kk = k_k[ch], p_ka = k_a[ch], p_rk = r_k[ch];
  const float EM = 0.60653065971263342f;  // e^{-0.5}

  // ---- prefetch ALL per-token global inputs into registers (80 loads) ----
  unsigned short wr_u[16], kv_u[16], rv_u[16], ar_u[16];
  float vv_u[16];
#pragma unroll
  for (int u = 0; u < 16; ++u) {
    const size_t gi = base + (size_t)(16 * wv + u) * 1024;
    wr_u[u] = wraw[gi];
    kv_u[u] = k_btc[gi];
    rv_u[u] = r_btc[gi];
    ar_u[u] = araw[gi];
    vv_u[u] = v_btc[gi];
  }

  // ---- pass 1: inclusive log-decay prefix for my 16 rows + strip sum ----
  float lwv[16];
  {
    float run = 0.f;
#pragma unroll
    for (int u = 0; u < 16; ++u) {
      run += -EM * sigmoidf_(p_w0 + bf2f(wr_u[u]));
      lwv[u] = run;                       // inclusive prefix within strip
    }
    SS[wv * 64 + jl] = run;
  }
  __syncthreads();
  const float s0 = SS[0 * 64 + jl], s1 = SS[1 * 64 + jl];
  const float s2 = SS[2 * 64 + jl], s3s = SS[3 * 64 + jl];
  const float goff = (wv > 0 ? s0 : 0.f) + (wv > 1 ? s1 : 0.f) + (wv > 2 ? s2 : 0.f);
  const float gl = s0 + s1 + s2 + s3s;
  if (wv == 0) GLs[jl] = gl;

  // ---- pass 2: per-token transforms + factor matrices (independent u) ----
  float s3v[16];
  {
    const float e_gl = __expf(gl);
#pragma unroll
    for (int u = 0; u < 16; ++u) {
      const int t = 16 * wv + u;
      const float pre = goff + (u ? lwv[u - 1] : 0.f);   // g_{t-1}
      const float cur = goff + lwv[u];                   // g_t
      const float kv = bf2f(kv_u[u]), rv = bf2f(rv_u[u]);
      const float vv = vv_u[u];
      const float av = sigmoidf_(p_a0 + bf2f(ar_u[u]));
      const float kkx = kv * p_kk;
      float ssq = kkx * kkx;
#pragma unroll
      for (int m = 1; m < 64; m <<= 1) ssq += __shfl_xor(ssq, m);
      const float scale = __builtin_amdgcn_rsqf(fmaxf(ssq, 1e-24f));
      const float kkn = kkx * scale;
      const float bb = kkn * av;
      const float kmod = kv * (1.0f + (av - 1.0f) * p_ka);
      float s3 = rv * kmod * p_rk;
#pragma unroll
      for (int m = 1; m < 64; m <<= 1) s3 += __shfl_xor(s3, m);
      s3v[u] = s3;
      const float e_prev = __expf(pre);                  // exp(g_{t-1})
      const float e_gu   = __expf(cur);                  // exp(g_t), <= 1
      const float em     = __expf(-cur);                 // exp(-g_t)
      const float egl    = e_gl * em;                    // exp(gl-g_t) <= 1
      AHb[t * RS + jl] = f2bf(-kkn * e_prev);
      BPb[t * RS + jl] = f2bf(bb * em);
      KPb[t * RS + jl] = f2bf(kmod * em);
      BPTb[jl * RS + t] = f2bf(bb * egl);
      KPTb[jl * RS + t] = f2bf(kmod * egl);
      RHb[t * RS + jl] = f2bf(rv * e_gu);
      VSTb[jl * RS + t] = f2bf(vv);
    }
    if (jl == 0) {
      float* sp = s3G + (bh << 10) + (c << 6) + 16 * wv;
#pragma unroll
      for (int k2 = 0; k2 < 4; ++k2)
        *(float4*)(sp + 4 * k2) = make_float4(s3v[4 * k2], s3v[4 * k2 + 1],
                                              s3v[4 * k2 + 2], s3v[4 * k2 + 3]);
    }
  }
  __syncthreads();

  const int fr = lane & 15, q = lane >> 4;
  const int i0 = wv * 16;

  // ---- Gram products via MFMA: LBA, LKA, DBR, DKR(->global) ----
  {
    f32x4 aLB[4], aLK[4], aDB[4], aDK[4];
#pragma unroll
    for (int j = 0; j < 4; ++j) {
      aLB[j] = (f32x4){0.f, 0.f, 0.f, 0.f}; aLK[j] = (f32x4){0.f, 0.f, 0.f, 0.f};
      aDB[j] = (f32x4){0.f, 0.f, 0.f, 0.f}; aDK[j] = (f32x4){0.f, 0.f, 0.f, 0.f};
    }
#pragma unroll
    for (int ks = 0; ks < 2; ++ks) {
      const int ko = ks * 32 + q * 8;
      bf16x8 fA = *(const bf16x8*)(AHb + (i0 + fr) * RS + ko);
      bf16x8 fR = *(const bf16x8*)(RHb + (i0 + fr) * RS + ko);
#pragma unroll
      for (int j = 0; j < 4; ++j) {
        bf16x8 fB = *(const bf16x8*)(BPb + (j * 16 + fr) * RS + ko);
        bf16x8 fK = *(const bf16x8*)(KPb + (j * 16 + fr) * RS + ko);
        aLB[j] = __builtin_amdgcn_mfma_f32_16x16x32_bf16(fA, fB, aLB[j], 0, 0, 0);
        aLK[j] = __builtin_amdgcn_mfma_f32_16x16x32_bf16(fA, fK, aLK[j], 0, 0, 0);
        aDB[j] = __builtin_amdgcn_mfma_f32_16x16x32_bf16(fR, fB, aDB[j], 0, 0, 0);
        aDK[j] = __builtin_amdgcn_mfma_f32_16x16x32_bf16(fR, fK, aDK[j], 0, 0, 0);
      }
    }
    __syncthreads();   // all Gram fragment reads done before overlay stores
#pragma unroll
    for (int j = 0; j < 4; ++j) {
      const int s = j * 16 + fr;
#pragma unroll
      for (int r = 0; r < 4; ++r) {
        const int t = i0 + q * 4 + r;
        LBb[t * LBS + s] = f2bf((s < t) ? aLB[j][r] : 0.f);
        LKb[t * RS + s] = f2bf((s < t) ? aLK[j][r] : 0.f);
        DBb[t * RS + s] = f2bf((s <= t) ? aDB[j][r] : 0.f);
        DkG[(size_t)inst * 4096 + t * 64 + s] = f2bf((s <= t) ? aDK[j][r] : 0.f);
      }
    }
  }
  __syncthreads();

  // ---- W = LKA · V (MFMA, all waves; replaces Y-solve + Qloc) ----
  {
    f32x4 wacc[4];
#pragma unroll
    for (int j = 0; j < 4; ++j) wacc[j] = (f32x4){0.f, 0.f, 0.f, 0.f};
#pragma unroll
    for (int ks = 0; ks < 2; ++ks) {
      const int ko = ks * 32 + q * 8;
      bf16x8 fL = *(const bf16x8*)(LKb + (i0 + fr) * RS + ko);
#pragma unroll
      for (int j = 0; j < 4; ++j) {
        bf16x8 fV = *(const bf16x8*)(VSTb + (j * 16 + fr) * RS + ko);
        wacc[j] = __builtin_amdgcn_mfma_f32_16x16x32_bf16(fL, fV, wacc[j], 0, 0, 0);
      }
    }
#pragma unroll
    for (int j = 0; j < 4; ++j)
#pragma unroll
      for (int r = 0; r < 4; ++r)
        LKb[(i0 + q * 4 + r) * RS + j * 16 + fr] = f2bf(wacc[j][r]);
  }
  __syncthreads();

  // ---- prefetch DKR fragments from global (L2-hot: our own writes) ----
  bf16x8 fDK0, fDK1;
  {
    const unsigned short* dkp = DkG + (size_t)inst * 4096 + (i0 + fr) * 64 + q * 8;
    fDK0 = *(const bf16x8*)(dkp);
    fDK1 = *(const bf16x8*)(dkp + 32);
  }

  // ---- blocked dual triangular solve (barrier-free, intra-wave):
  //      wave0: (I-L)X = Ahat  -> XTb[jc][t];  wave1: (I-L)Q = W -> QTb[jc][t]
  if (wv < 2) {
    const int jc = lane;
    unsigned short* Sb = (wv == 0) ? AHb : LKb;    // RHS (consumed into regs)
    unsigned short* Tb = (wv == 0) ? XTb : QTb;    // col-major solution [jc][t]
    float x[64];
#pragma unroll
    for (int t = 0; t < 64; ++t) x[t] = bf2f(Sb[t * RS + jc]);
    // zero my solution row: bridge MFMAs read 0 for not-yet-solved t
#pragma unroll
    for (int z2 = 0; z2 < 8; ++z2)
      *(bf16x8*)(Tb + jc * RS + z2 * 8) = (bf16x8){0, 0, 0, 0, 0, 0, 0, 0};

    const int jf = jc & 15, tjm = jc >> 4;

#pragma unroll
    for (int I = 0; I < 4; ++I) {
      if (I > 0) {
        // bridge: x[16I+u] += sum_{s<16I} L[16I+u][s] * sol[s][jc]  (MFMA)
        f32x4 cU[4];
#pragma unroll
        for (int tj = 0; tj < 4; ++tj) cU[tj] = (f32x4){0.f, 0.f, 0.f, 0.f};
#pragma unroll
        for (int kw = 0; kw < 2; ++kw) {
          if (kw * 32 < 16 * I) {
            const int ko = kw * 32 + q * 8;
            bf16x8 fL;
            *(ushort4*)&fL = *(const ushort4*)(LBb + (16 * I + fr) * LBS + ko);
            *((ushort4*)&fL + 1) = *(const ushort4*)(LBb + (16 * I + fr) * LBS + ko + 4);
#pragma unroll
            for (int tj = 0; tj < 4; ++tj) {
              bf16x8 fX = *(const bf16x8*)(Tb + (tj * 16 + fr) * RS + ko);
              cU[tj] = __builtin_amdgcn_mfma_f32_16x16x32_bf16(fL, fX, cU[tj], 0, 0, 0);
            }
          }
        }
        // redistribute MFMA C-layout to column-owner lanes
#pragma unroll
        for (int qq = 0; qq < 4; ++qq) {
          const int saddr = (qq * 16 + jf) * 4;
#pragma unroll
          for (int r = 0; r < 4; ++r) {
            int g0 = __builtin_amdgcn_ds_bpermute(saddr, __builtin_bit_cast(int, cU[0][r]));
            int g1 = __builtin_amdgcn_ds_bpermute(saddr, __builtin_bit_cast(int, cU[1][r]));
            int g2 = __builtin_amdgcn_ds_bpermute(saddr, __builtin_bit_cast(int, cU[2][r]));
            int g3 = __builtin_amdgcn_ds_bpermute(saddr, __builtin_bit_cast(int, cU[3][r]));
            int gs = (tjm == 0) ? g0 : (tjm == 1) ? g1 : (tjm == 2) ? g2 : g3;
            x[16 * I + qq * 4 + r] += __builtin_bit_cast(float, gs);
          }
        }
      }
      // diagonal 16x16 unit-lower solve (fp32 chain, bf16 L)
#pragma unroll
      for (int u = 1; u < 16; ++u) {
        const unsigned short* lr = LBb + (16 * I + u) * LBS + 16 * I;
        float acc0 = 0.f, acc1 = 0.f;
#pragma unroll
        for (int s = 0; s + 2 <= u; s += 2) {
          acc0 = fmaf(bf2f(lr[s]), x[16 * I + s], acc0);
          acc1 = fmaf(bf2f(lr[s + 1]), x[16 * I + s + 1], acc1);
        }
        if (u & 1) acc0 = fmaf(bf2f(lr[u - 1]), x[16 * I + u - 1], acc0);
        x[16 * I + u] += acc0 + acc1;
      }
      // store solved block of my column (bf16 pairs)
#pragma unroll
      for (int t2 = 0; t2 < 16; t2 += 2) {
        unsigned int pk = (unsigned int)f2bf(x[16 * I + t2])
                        | ((unsigned int)f2bf(x[16 * I + t2 + 1]) << 16);
        *(unsigned int*)(Tb + jc * RS + 16 * I + t2) = pk;
      }
    }
  }
  __syncthreads();

  // ---- final operators: Mc, Ncc, Pc, Oloc (MFMA) -> global bf16 ----
  {
    f32x4 mA[4], nA[4], pA[4], oA[4];
#pragma unroll
    for (int j = 0; j < 4; ++j) {
      mA[j] = (f32x4){0.f, 0.f, 0.f, 0.f}; nA[j] = (f32x4){0.f, 0.f, 0.f, 0.f};
      pA[j] = (f32x4){0.f, 0.f, 0.f, 0.f}; oA[j] = (f32x4){0.f, 0.f, 0.f, 0.f};
    }
#pragma unroll
    for (int ks = 0; ks < 2; ++ks) {
      const int ko = ks * 32 + q * 8;
      bf16x8 fBT = *(const bf16x8*)(BPTb + (i0 + fr) * RS + ko);
      bf16x8 fKT = *(const bf16x8*)(KPTb + (i0 + fr) * RS + ko);
      bf16x8 fDB = *(const bf16x8*)(DBb + (i0 + fr) * RS + ko);
      bf16x8 fDK = ks ? fDK1 : fDK0;
#pragma unroll
      for (int j = 0; j < 4; ++j) {
        bf16x8 fXT = *(const bf16x8*)(XTb + (j * 16 + fr) * RS + ko);
        bf16x8 fQT = *(const bf16x8*)(QTb + (j * 16 + fr) * RS + ko);
        bf16x8 fVT = *(const bf16x8*)(VSTb + (j * 16 + fr) * RS + ko);
        mA[j] = __builtin_amdgcn_mfma_f32_16x16x32_bf16(fBT, fXT, mA[j], 0, 0, 0);
        nA[j] = __builtin_amdgcn_mfma_f32_16x16x32_bf16(fBT, fQT, nA[j], 0, 0, 0);
        nA[j] = __builtin_amdgcn_mfma_f32_16x16x32_bf16(fKT, fVT, nA[j], 0, 0, 0);
        pA[j] = __builtin_amdgcn_mfma_f32_16x16x32_bf16(fDB, fXT, pA[j], 0, 0, 0);
        oA[j] = __builtin_amdgcn_mfma_f32_16x16x32_bf16(fDB, fQT, oA[j], 0, 0, 0);
        oA[j] = __builtin_amdgcn_mfma_f32_16x16x32_bf16(fDK, fVT, oA[j], 0, 0, 0);
      }
    }
    const size_t ob = (size_t)inst * 4096;
    float eg[4];
#pragma unroll
    for (int r = 0; r < 4; ++r) eg[r] = __expf(GLs[i0 + q * 4 + r]);
#pragma unroll
    for (int j = 0; j < 4; ++j) {
      const int col = j * 16 + fr;
#pragma unroll
      for (int r = 0; r < 4; ++r) {
        const int row = i0 + q * 4 + r;
        const size_t oi = ob + (size_t)row * 64 + col;
        McG[oi] = f2bf(mA[j][r] + (row == col ? eg[r] : 0.f));
        NcG[oi] = f2bf(nA[j][r]);
        PcG[oi] = f2bf(pA[j][r] + bf2f(RHb[row * RS + col]));
        OlG[oi] = f2bf(oA[j][r]);
      }
    }
  }
}

// ---------------------------------------------------------------------------
// Phase 2 (v7, MFMA): sequential chunk-state propagation per (b,h):
// ST' = Mc ST + Ncc. State held as ST^T in LDS as TWO bf16 planes
// (hi = bf16(ST), lo = bf16(ST - hi)) so Mc·ST = Mc·H + Mc·L with fp32 MFMA
// accumulation (~fp32-accurate recurrence). Replaces the 64-step VALU loop
// (was ~45us at 1 wave/SIMD on 64 CUs). Sch layout identical to before:
// Sch[c] = bf16(state entering chunk c), row-major.
// ---------------------------------------------------------------------------
__global__ __launch_bounds__(256) void chunk_scan_kernel(
    const unsigned short* __restrict__ McG, const unsigned short* __restrict__ NcG,
    unsigned short* __restrict__ Sch)
{
  __shared__ __align__(16) unsigned short STh[64 * RS];  // ST^T hi: [col][row]
  __shared__ __align__(16) unsigned short STl[64 * RS];  // ST^T lo
  const int bh = blockIdx.x;
  const int tid = threadIdx.x;
  const int wv = tid >> 6, lane = tid & 63;
  const int fr = lane & 15, q = lane >> 4;

  f32x4 acc[4];   // state rows [16wv,16wv+16) x cols [16j,16j+16), C-layout

  // ---- c = 0: Sch[0] = 0; acc = Nc[0]; STT not read this chunk ----
  {
    const size_t ob = ((size_t)bh << 4) << 12;
#pragma unroll
    for (int j = 0; j < 4; ++j) {
      const int col = j * 16 + fr;
#pragma unroll
      for (int r = 0; r < 4; ++r) {
        const int row = wv * 16 + q * 4 + r;
        Sch[ob + (size_t)row * 64 + col] = 0;
        acc[j][r] = bf2f(NcG[ob + (size_t)row * 64 + col]);
      }
    }
  }

  for (int c = 1; c < 16; ++c) {
    const size_t ob = ((((size_t)bh << 4) + (size_t)c) << 12);
    // barrier A: prior iteration's B-reads of STT complete before rewrite
    __syncthreads();
    // write prev state (acc) into STT hi/lo; also store Sch[c] = bf16(state)
#pragma unroll
    for (int j = 0; j < 4; ++j) {
      const int col = j * 16 + fr;
#pragma unroll
      for (int r = 0; r < 4; ++r) {
        const int row = wv * 16 + q * 4 + r;
        const float v = acc[j][r];
        const unsigned short hi = f2bf(v);
        STh[col * RS + row] = hi;
        STl[col * RS + row] = f2bf(v - bf2f(hi));
        Sch[ob + (size_t)row * 64 + col] = hi;
      }
    }
    __syncthreads();
    // A-frags: Mc rows (16wv+fr), k-contig (L2-hot global, b128)
    const bf16x8 fA0 = *(const bf16x8*)(McG + ob + (size_t)(wv * 16 + fr) * 64 + q * 8);
    const bf16x8 fA1 = *(const bf16x8*)(McG + ob + (size_t)(wv * 16 + fr) * 64 + 32 + q * 8);
#pragma unroll
    for (int j = 0; j < 4; ++j) {
      const int col = j * 16 + fr;
#pragma unroll
      for (int r = 0; r < 4; ++r)
        acc[j][r] = bf2f(NcG[ob + (size_t)(wv * 16 + q * 4 + r) * 64 + col]);
      const bf16x8 h0 = *(const bf16x8*)(STh + (j * 16 + fr) * RS + q * 8);
      const bf16x8 h1 = *(const bf16x8*)(STh + (j * 16 + fr) * RS + 32 + q * 8);
      const bf16x8 l0 = *(const bf16x8*)(STl + (j * 16 + fr) * RS + q * 8);
      const bf16x8 l1 = *(const bf16x8*)(STl + (j * 16 + fr) * RS + 32 + q * 8);
      acc[j] = __builtin_amdgcn_mfma_f32_16x16x32_bf16(fA0, h0, acc[j], 0, 0, 0);
      acc[j] = __builtin_amdgcn_mfma_f32_16x16x32_bf16(fA1, h1, acc[j], 0, 0, 0);
      acc[j] = __builtin_amdgcn_mfma_f32_16x16x32_bf16(fA0, l0, acc[j], 0, 0, 0);
      acc[j] = __builtin_amdgcn_mfma_f32_16x16x32_bf16(fA1, l1, acc[j], 0, 0, 0);
    }
  }
  // final state (after chunk 15) is not needed downstream — done.
}

// ---------------------------------------------------------------------------
// Phase 3 + GroupNorm fused: Out = Pc ST + Oloc; per-row norm; + s3*v; *g.
// ---------------------------------------------------------------------------
__global__ __launch_bounds__(256) void chunk_outgn_kernel(
    const unsigned short* __restrict__ PcG, const unsigned short* __restrict__ OlG,
    const unsigned short* __restrict__ Sch, const float* __restrict__ s3G,
    const float* __restrict__ v_btc, const unsigned short* __restrict__ g_f,
    const float* __restrict__ gamma, const float* __restrict__ beta,
    unsigned short* __restrict__ yg)
{
  __shared__ float ST[64 * PAD];
  __shared__ float PB[64 * PAD];
  const int inst = blockIdx.x;
  const int bh = inst >> 4, c = inst & 15;
  const int b = bh >> 4, h = bh & 15;
  const int tid = threadIdx.x;
  const int tt = tid >> 4, jt = tid & 15;
  const size_t ob = (size_t)inst << 12;

#pragma unroll
  for (int q = 0; q < 4; ++q) {
    int idx = q * 1024 + tid * 4;
    int row = idx >> 6, col = idx & 63;
    ushort4 sv = *(const ushort4*)(Sch + ob + idx);
    ST[row * PAD + col] = bf2f(sv.x);     ST[row * PAD + col + 1] = bf2f(sv.y);
    ST[row * PAD + col + 2] = bf2f(sv.z); ST[row * PAD + col + 3] = bf2f(sv.w);
    ushort4 pv = *(const ushort4*)(PcG + ob + idx);
    PB[row * PAD + col] = bf2f(pv.x);     PB[row * PAD + col + 1] = bf2f(pv.y);
    PB[row * PAD + col + 2] = bf2f(pv.z); PB[row * PAD + col + 3] = bf2f(pv.w);
  }
  __syncthreads();

  float acc[4][4];
#pragma unroll
  for (int u = 0; u < 4; ++u) {
    ushort4 o4 = *(const ushort4*)(OlG + ob + (size_t)(4 * tt + u) * 64 + 4 * jt);
    acc[u][0] = bf2f(o4.x); acc[u][1] = bf2f(o4.y);
    acc[u][2] = bf2f(o4.z); acc[u][3] = bf2f(o4.w);
  }
#pragma unroll 4
  for (int pp = 0; pp < 64; ++pp) {
    float pv[4], sv[4];
#pragma unroll
    for (int u = 0; u < 4; ++u) pv[u] = PB[(4 * tt + u) * PAD + pp];
#pragma unroll
    for (int v = 0; v < 4; ++v) sv[v] = ST[pp * PAD + 4 * jt + v];
#pragma unroll
    for (int u = 0; u < 4; ++u)
#pragma unroll
      for (int v = 0; v < 4; ++v) acc[u][v] = fmaf(pv[u], sv[v], acc[u][v]);
  }

  const int colb = h * 64 + 4 * jt;
  float4 ga4 = *(const float4*)(gamma + colb);
  float4 be4 = *(const float4*)(beta + colb);

#pragma unroll
  for (int u = 0; u < 4; ++u) {
    float sum1 = acc[u][0] + acc[u][1] + acc[u][2] + acc[u][3];
    float sum2 = acc[u][0] * acc[u][0] + acc[u][1] * acc[u][1]
               + acc[u][2] * acc[u][2] + acc[u][3] * acc[u][3];
#pragma unroll
    for (int m = 1; m < 16; m <<= 1) {
      sum1 += __shfl_xor(sum1, m);
      sum2 += __shfl_xor(sum2, m);
    }
    const float mean = sum1 * (1.0f / 64.0f);
    const float var = sum2 * (1.0f / 64.0f) - mean * mean;
    const float rstd = __builtin_amdgcn_rsqf(var + 0.00064f);
    const int tok = c * 64 + 4 * tt + u;
    const float s3 = s3G[(bh << 10) + tok];
    const size_t gaddr = ((size_t)(b * 1024 + tok) * 1024) + colb;
    float4 v4 = *(const float4*)(v_btc + gaddr);
    ushort4 g4b = *(const ushort4*)(g_f + gaddr);
    ushort4 ov;
    ov.x = f2bf(((acc[u][0] - mean) * rstd * ga4.x + be4.x + s3 * v4.x) * bf2f(g4b.x));
    ov.y = f2bf(((acc[u][1] - mean) * rstd * ga4.y + be4.y + s3 * v4.y) * bf2f(g4b.y));
    ov.z = f2bf(((acc[u][2] - mean) * rstd * ga4.z + be4.z + s3 * v4.z) * bf2f(g4b.z));
    ov.w = f2bf(((acc[u][3] - mean) * rstd * ga4.w + be4.w + s3 * v4.w) * bf2f(g4b.w));
    *(ushort4*)(yg + gaddr) = ov;
  }
}

// ---------------------------------------------------------------------------
extern "C" void kernel_launch(void* const* d_in, const int* in_sizes, int n_in,
                              void* d_out, int out_size, void* d_ws, size_t ws_size,
                              hipStream_t stream)
{
  (void)in_sizes; (void)n_in; (void)out_size;
  const float* x    = (const float*)d_in[0];
  const float* x_r  = (const float*)d_in[1];
  const float* x_w  = (const float*)d_in[2];
  const float* x_k  = (const float*)d_in[3];
  const float* x_v  = (const float*)d_in[4];
  const float* x_a  = (const float*)d_in[5];
  const float* x_g  = (const float*)d_in[6];
  const float* w0   = (const float*)d_in[7];
  const float* w1   = (const float*)d_in[8];
  const float* w2   = (const float*)d_in[9];
  const float* a0   = (const float*)d_in[10];
  const float* a1   = (const float*)d_in[11];
  const float* a2   = (const float*)d_in[12];
  const float* g1   = (const float*)d_in[16];
  const float* g2   = (const float*)d_in[17];
  const float* k_k  = (const float*)d_in[18];
  const float* k_a  = (const float*)d_in[19];
  const float* r_k  = (const float*)d_in[20];
  const float* Wr   = (const float*)d_in[21];
  const float* Wk   = (const float*)d_in[22];
  const float* Wv   = (const float*)d_in[23];
  const float* Wo   = (const float*)d_in[24];
  const float* ln_g = (const float*)d_in[25];
  const float* ln_b = (const float*)d_in[26];

  float* outp = (float*)d_out;
  float* vfirst = outp + (size_t)BB * TT * CCH;

  char* ws = (char*)d_ws;
  size_t off = 0;
  auto alloc = [&](size_t bytes) -> char* {
    char* p = ws + off;
    off += (bytes + 255) & ~(size_t)255;
    return p;
  };

  unsigned short* WrT = (unsigned short*)alloc(2097152);
  unsigned short* WkT = (unsigned short*)alloc(2097152);
  unsigned short* WvT = (unsigned short*)alloc(2097152);
  unsigned short* WoT = (unsigned short*)alloc(2097152);
  unsigned short* w1T = (unsigned short*)alloc(131072);
  unsigned short* w2T = (unsigned short*)alloc(131072);
  unsigned short* a1T = (unsigned short*)alloc(131072);
  unsigned short* a2T = (unsigned short*)alloc(131072);
  unsigned short* g1T = (unsigned short*)alloc(262144);
  unsigned short* g2T = (unsigned short*)alloc(262144);
  unsigned short* xrB = (unsigned short*)alloc(8388608);
  unsigned short* xwB = (unsigned short*)alloc(8388608);
  unsigned short* xkB = (unsigned short*)alloc(8388608);
  unsigned short* xvB = (unsigned short*)alloc(8388608);
  unsigned short* xaB = (unsigned short*)alloc(8388608);
  unsigned short* xgB = (unsigned short*)alloc(8388608);
  unsigned short* r_btc = (unsigned short*)alloc(8388608);
  unsigned short* k_btc = (unsigned short*)alloc(8388608);
  unsigned short* wraw  = (unsigned short*)alloc(8388608);
  unsigned short* araw  = (unsigned short*)alloc(8388608);
  unsigned short* gfB = (unsigned short*)alloc(8388608);
  unsigned short* OlG = (unsigned short*)alloc(8388608);
  unsigned short* DkG = (unsigned short*)alloc(8388608);
  float* s3G   = (float*)alloc(262144);
  unsigned short* hwB = (unsigned short*)alloc(524288);
  unsigned short* haB = (unsigned short*)alloc(524288);
  unsigned short* hgB = (unsigned short*)alloc(1048576);
  unsigned short* ygB = (unsigned short*)alloc(8388608);

  // overlays (owners dead before the writer runs)
  unsigned short* McG = xrB;          // over xrB (dead after gemm_stage1)
  unsigned short* NcG = xkB;          // over xkB
  unsigned short* PcG = xaB;          // over xaB
  unsigned short* Sch = k_btc;        // k_btc dead after chunk_ops

  if (off > ws_size) return;

  dim3 blk(256);

  // transposes + mix in one launch
  prep_kernel<<<5248, blk, 0, stream>>>(
      x, x_r, x_w, x_k, x_v, x_a, x_g,
      xrB, xwB, xkB, xvB, xaB, xgB,
      Wr, Wk, Wv, Wo, WrT, WkT, WvT, WoT,
      w1, w2, a1, a2, g1, g2, w1T, w2T, a1T, a2T, g1T, g2T);

  // r/k/v GEMMs + lora1 in one launch; v straight into vfirst (output 1)
  gemm_stage1_kernel<<<896, blk, 0, stream>>>(
      xrB, xkB, xvB, WrT, WkT, WvT, r_btc, k_btc, vfirst,
      xwB, xaB, xgB, w1T, a1T, g1T, hwB, haB, hgB);

  // LoRA stage 2 (w/a/g) in one launch
  lora2_kernel<<<dim3(32, 8, 3), blk, 0, stream>>>(
      hwB, haB, hgB, w2T, a2T, g2T, wraw, araw, gfB);

  // chunked-DPLR scan phase 1 (postproc fused, 2 blocks/CU)
  constexpr int CHUNK_LDS = 7 * 64 * RS * 2 + 64 * LBS * 2 + 64 * 4 + 4 * 64 * 4;
  hipFuncSetAttribute((const void*)chunk_ops_kernel,
                      hipFuncAttributeMaxDynamicSharedMemorySize, CHUNK_LDS);
  chunk_ops_kernel<<<1024, blk, CHUNK_LDS, stream>>>(
      r_btc, k_btc, vfirst, wraw, araw, w0, a0, k_k, k_a, r_k,
      McG, NcG, PcG, OlG, DkG, s3G);

  chunk_scan_kernel<<<64, blk, 0, stream>>>(McG, NcG, Sch);

  chunk_outgn_kernel<<<1024, blk, 0, stream>>>(PcG, OlG, Sch, s3G, vfirst, gfB,
                                               ln_g, ln_b, ygB);

  gemm_out_kernel<<<dim3(32, 8), blk, 0, stream>>>(ygB, WoT, outp);
}

// Round 10
// 312.101 us; speedup vs baseline: 1.1873x; 1.0176x over previous
//
#include <hip/hip_runtime.h>
#include <hip/hip_bf16.h>
#include <math.h>

// Problem constants
#define BB 4
#define TT 1024
#define CCH 1024
#define HH 16
#define NNd 64
#define RS 72       // bf16 LDS row stride in shorts (144B = 9x16B, frag-aligned)
#define LBS 68      // bf16 L-matrix row stride in shorts (136B, 8B-aligned u4)

typedef short bf16x8 __attribute__((ext_vector_type(8)));
typedef float f32x4 __attribute__((ext_vector_type(4)));

__device__ __forceinline__ unsigned short f2bf(float f) {
  __hip_bfloat16 h = __float2bfloat16(f);
  return __builtin_bit_cast(unsigned short, h);
}
__device__ __forceinline__ float bf2f(unsigned short u) {
  unsigned int x = (unsigned int)u << 16;
  return __builtin_bit_cast(float, x);
}
// Native transcendentals: outputs all round through bf16 downstream, so
// v_exp/v_rcp/v_rsq (~1 ulp) precision is far below bf16 quantization.
__device__ __forceinline__ float sigmoidf_(float x) {
  return __builtin_amdgcn_rcpf(1.0f + __expf(-x));
}
__device__ __forceinline__ float ftanh_(float x) {
  // tanh(x) = 1 - 2/(e^{2x}+1); saturates correctly at +/-inf.
  return 1.0f - 2.0f * __builtin_amdgcn_rcpf(__expf(2.0f * x) + 1.0f);
}

// async global->LDS, 16B per lane; LDS dest must be wave-uniform base + 16*lane
__device__ __forceinline__ void gl2lds16(const unsigned short* g, unsigned short* l) {
  __builtin_amdgcn_global_load_lds(
      (const __attribute__((address_space(1))) unsigned int*)g,
      (__attribute__((address_space(3))) unsigned int*)l, 16, 0, 0);
}

// ---------------------------------------------------------------------------
// Transpose tile helper
// ---------------------------------------------------------------------------
__device__ __forceinline__ void transpose_tile(
    const float* __restrict__ in, unsigned short* __restrict__ out,
    int R, int Cc, int r0, int c0, unsigned short (*tile)[68], int t)
{
  const int rr = t >> 4;
  const int cc = (t & 15) * 4;
#pragma unroll
  for (int p = 0; p < 4; ++p) {
    int row = p * 16 + rr;
    float4 v = *(const float4*)(in + (size_t)(r0 + row) * Cc + c0 + cc);
    tile[row][cc]     = f2bf(v.x);
    tile[row][cc + 1] = f2bf(v.y);
    tile[row][cc + 2] = f2bf(v.z);
    tile[row][cc + 3] = f2bf(v.w);
  }
  __syncthreads();
#pragma unroll
  for (int p = 0; p < 4; ++p) {
    int row = p * 16 + rr;
    ushort4 o;
    o.x = tile[cc][row];
    o.y = tile[cc + 1][row];
    o.z = tile[cc + 2][row];
    o.w = tile[cc + 3][row];
    *(ushort4*)(out + (size_t)(c0 + row) * R + r0 + cc) = o;
  }
}

// ---------------------------------------------------------------------------
// prep_kernel: mix (blocks 0..4095) + big4 transposes (4096..5119)
//            + lora transposes (5120..5247), one launch.
// ---------------------------------------------------------------------------
__global__ __launch_bounds__(256) void prep_kernel(
    const float* __restrict__ x,
    const float* __restrict__ cr, const float* __restrict__ cw,
    const float* __restrict__ ck, const float* __restrict__ cv,
    const float* __restrict__ ca, const float* __restrict__ cg,
    unsigned short* __restrict__ xr, unsigned short* __restrict__ xw,
    unsigned short* __restrict__ xk, unsigned short* __restrict__ xv,
    unsigned short* __restrict__ xa, unsigned short* __restrict__ xg,
    const float* __restrict__ W0, const float* __restrict__ W1,
    const float* __restrict__ W2, const float* __restrict__ W3,
    unsigned short* __restrict__ T0, unsigned short* __restrict__ T1,
    unsigned short* __restrict__ T2, unsigned short* __restrict__ T3,
    const float* __restrict__ w1, const float* __restrict__ w2,
    const float* __restrict__ a1, const float* __restrict__ a2,
    const float* __restrict__ g1, const float* __restrict__ g2,
    unsigned short* __restrict__ w1T, unsigned short* __restrict__ w2T,
    unsigned short* __restrict__ a1T, unsigned short* __restrict__ a2T,
    unsigned short* __restrict__ g1T, unsigned short* __restrict__ g2T)
{
  __shared__ unsigned short tile[64][68];
  const int blk = blockIdx.x;
  const int tid = threadIdx.x;
  if (blk < 4096) {
    // ---- token-shift mix ----
    const size_t idx = ((size_t)blk * 256 + tid) * 4;
    const int c = (int)(idx & 1023);
    const int t = (int)((idx >> 10) & 1023);
    float4 xc = *(const float4*)(x + idx);
    float4 xp = make_float4(0.f, 0.f, 0.f, 0.f);
    if (t > 0) xp = *(const float4*)(x + idx - 1024);
    float4 dx = make_float4(xp.x - xc.x, xp.y - xc.y, xp.z - xc.z, xp.w - xc.w);
    auto st = [&](unsigned short* dst, const float* coef) {
      float4 w = *(const float4*)(coef + c);
      ushort4 o;
      o.x = f2bf(fmaf(dx.x, w.x, xc.x));
      o.y = f2bf(fmaf(dx.y, w.y, xc.y));
      o.z = f2bf(fmaf(dx.z, w.z, xc.z));
      o.w = f2bf(fmaf(dx.w, w.w, xc.w));
      *(ushort4*)(dst + idx) = o;
    };
    st(xr, cr); st(xw, cw); st(xk, ck); st(xv, cv); st(xa, ca); st(xg, cg);
  } else if (blk < 5120) {
    const int j = blk - 4096;
    const int z = j >> 8, rem = j & 255;
    const int ty = rem >> 4, tx = rem & 15;
    const float* src = (z == 0) ? W0 : (z == 1) ? W1 : (z == 2) ? W2 : W3;
    unsigned short* dst = (z == 0) ? T0 : (z == 1) ? T1 : (z == 2) ? T2 : T3;
    transpose_tile(src, dst, 1024, 1024, tx * 64, ty * 64, tile, tid);
  } else {
    const int i = blk - 5120;
    const float* src; unsigned short* dst; int R, C, rt, ct;
    if (i < 16)      { src = w1; dst = w1T; R = 1024; C = 64;   rt = i;      ct = 0; }
    else if (i < 32) { src = w2; dst = w2T; R = 64;   C = 1024; rt = 0;      ct = i - 16; }
    else if (i < 48) { src = a1; dst = a1T; R = 1024; C = 64;   rt = i - 32; ct = 0; }
    else if (i < 64) { src = a2; dst = a2T; R = 64;   C = 1024; rt = 0;      ct = i - 48; }
    else if (i < 96) { int k = i - 64; src = g1; dst = g1T; R = 1024; C = 128; rt = k >> 1; ct = k & 1; }
    else             { int k = i - 96; src = g2; dst = g2T; R = 128; C = 1024; rt = k & 1;  ct = k >> 1; }
    transpose_tile(src, dst, R, C, rt * 64, ct * 64, tile, tid);
  }
}

// ---------------------------------------------------------------------------
// gemm_stage1: blocks 0..767 = r/k/v big GEMMs (z=blk/256), 768..895 = lora1.
// r,k outputs bf16 (chunk_ops-only consumers); v output fp32 (vfirst).
// ---------------------------------------------------------------------------
__global__ __launch_bounds__(256) void gemm_stage1_kernel(
    const unsigned short* __restrict__ xrB, const unsigned short* __restrict__ xkB,
    const unsigned short* __restrict__ xvB,
    const unsigned short* __restrict__ WrT, const unsigned short* __restrict__ WkT,
    const unsigned short* __restrict__ WvT,
    unsigned short* __restrict__ r_btc, unsigned short* __restrict__ k_btc,
    float* __restrict__ v_btc,
    const unsigned short* __restrict__ xwB, const unsigned short* __restrict__ xaB,
    const unsigned short* __restrict__ xgB,
    const unsigned short* __restrict__ w1T, const unsigned short* __restrict__ a1T,
    const unsigned short* __restrict__ g1T,
    unsigned short* __restrict__ hwB, unsigned short* __restrict__ haB,
    unsigned short* __restrict__ hgB)
{
  constexpr int K = 1024, SK = 32;
  __shared__ __align__(16) unsigned short As[128 * SK];
  __shared__ __align__(16) unsigned short Bs[128 * SK];
  const int blk = blockIdx.x;
  const int tid = threadIdx.x;
  const int wv = tid >> 6, lane = tid & 63;
  const int fr = lane & 15, q = lane >> 4;
  const int arow = tid >> 2;
  const int akc = (tid & 3) * 8;

  if (blk < 768) {
    // ---- big3 GEMM: z selects r/k/v ----
    const int z = blk >> 8, rem = blk & 255;
    const int m0 = (rem & 31) * 128;
    const int n0 = (rem >> 5) * 128;
    const unsigned short* A = (z == 0) ? xrB : (z == 1) ? xkB : xvB;
    const unsigned short* BT = (z == 0) ? WrT : (z == 1) ? WkT : WvT;
    const int wave_m = wv >> 1, wave_n = wv & 1;

    f32x4 acc[4][4];
#pragma unroll
    for (int i = 0; i < 4; i++)
#pragma unroll
      for (int j = 0; j < 4; j++) acc[i][j] = (f32x4){0.f, 0.f, 0.f, 0.f};

    for (int k0 = 0; k0 < K; k0 += 32) {
#pragma unroll
      for (int i = 0; i < 2; ++i)
        gl2lds16(A + (size_t)(m0 + arow + i * 64) * K + k0 + akc, As + i * 2048 + wv * 512);
#pragma unroll
      for (int i = 0; i < 2; ++i)
        gl2lds16(BT + (size_t)(n0 + arow + i * 64) * K + k0 + akc, Bs + i * 2048 + wv * 512);
      __syncthreads();
      bf16x8 af[4], bfv[4];
#pragma unroll
      for (int i = 0; i < 4; i++)
        af[i] = *(const bf16x8*)(&As[(wave_m * 64 + i * 16 + fr) * SK + q * 8]);
#pragma unroll
      for (int j = 0; j < 4; j++)
        bfv[j] = *(const bf16x8*)(&Bs[(wave_n * 64 + j * 16 + fr) * SK + q * 8]);
#pragma unroll
      for (int i = 0; i < 4; i++)
#pragma unroll
        for (int j = 0; j < 4; j++)
          acc[i][j] = __builtin_amdgcn_mfma_f32_16x16x32_bf16(af[i], bfv[j], acc[i][j], 0, 0, 0);
      __syncthreads();
    }
#pragma unroll
    for (int i = 0; i < 4; i++)
#pragma unroll
      for (int j = 0; j < 4; j++) {
        const int mb = m0 + wave_m * 64 + i * 16 + q * 4;
        const int n = n0 + wave_n * 64 + j * 16 + fr;
#pragma unroll
        for (int r = 0; r < 4; r++) {
          if (z == 0)      r_btc[(size_t)(mb + r) * 1024 + n] = f2bf(acc[i][j][r]);
          else if (z == 1) k_btc[(size_t)(mb + r) * 1024 + n] = f2bf(acc[i][j][r]);
          else             v_btc[(size_t)(mb + r) * 1024 + n] = acc[i][j][r];
        }
      }
  } else {
    // ---- lora1: y=0 hw=tanh, y=1 ha, y=2/3 hg sigmoid halves ----
    const int j2 = blk - 768;
    const int y = j2 >> 5;
    const int m0 = (j2 & 31) * 128;
    const unsigned short* A  = (y == 0) ? xwB : (y == 1) ? xaB : xgB;
    const unsigned short* BT = (y == 0) ? w1T : (y == 1) ? a1T : (g1T + (size_t)(y - 2) * 64 * K);
    unsigned short* outb = (y == 0) ? hwB : (y == 1) ? haB : hgB;
    const int Nout = (y < 2) ? 64 : 128;
    const int ncol0 = (y < 2) ? 0 : (y - 2) * 64;

    f32x4 acc[2][4];
#pragma unroll
    for (int i = 0; i < 2; i++)
#pragma unroll
      for (int j = 0; j < 4; j++) acc[i][j] = (f32x4){0.f, 0.f, 0.f, 0.f};

    for (int k0 = 0; k0 < K; k0 += 32) {
#pragma unroll
      for (int i = 0; i < 2; ++i)
        gl2lds16(A + (size_t)(m0 + arow + i * 64) * K + k0 + akc, As + i * 2048 + wv * 512);
      gl2lds16(BT + (size_t)arow * K + k0 + akc, Bs + wv * 512);
      __syncthreads();
      bf16x8 af[2], bfv[4];
#pragma unroll
      for (int i = 0; i < 2; i++)
        af[i] = *(const bf16x8*)(&As[(wv * 32 + i * 16 + fr) * SK + q * 8]);
#pragma unroll
      for (int j = 0; j < 4; j++)
        bfv[j] = *(const bf16x8*)(&Bs[(j * 16 + fr) * SK + q * 8]);
#pragma unroll
      for (int i = 0; i < 2; i++)
#pragma unroll
        for (int j = 0; j < 4; j++)
          acc[i][j] = __builtin_amdgcn_mfma_f32_16x16x32_bf16(af[i], bfv[j], acc[i][j], 0, 0, 0);
      __syncthreads();
    }
#pragma unroll
    for (int i = 0; i < 2; i++)
#pragma unroll
      for (int j = 0; j < 4; j++) {
        const int mb = m0 + wv * 32 + i * 16 + q * 4;
        const int n = ncol0 + j * 16 + fr;
#pragma unroll
        for (int r = 0; r < 4; r++) {
          float val = acc[i][j][r];
          if (y == 0) val = ftanh_(val);
          else if (y >= 2) val = sigmoidf_(val);
          outb[(size_t)(mb + r) * Nout + n] = f2bf(val);
        }
      }
  }
}

// z-batched LoRA-2 GEMMs -> all bf16 outputs (wraw, araw, g).
__global__ __launch_bounds__(256) void lora2_kernel(
    const unsigned short* __restrict__ hwB, const unsigned short* __restrict__ haB,
    const unsigned short* __restrict__ hgB,
    const unsigned short* __restrict__ w2T, const unsigned short* __restrict__ a2T,
    const unsigned short* __restrict__ g2T,
    unsigned short* __restrict__ wraw, unsigned short* __restrict__ araw,
    unsigned short* __restrict__ gfB)
{
  constexpr int N = 1024, SK = 32;
  __shared__ __align__(16) unsigned short As[128 * SK];
  __shared__ __align__(16) unsigned short Bs[128 * SK];
  const int z = blockIdx.z;
  const unsigned short* A = (z == 0) ? hwB : (z == 1) ? haB : hgB;
  const unsigned short* BT = (z == 0) ? w2T : (z == 1) ? a2T : g2T;
  unsigned short* out = (z == 0) ? wraw : (z == 1) ? araw : gfB;
  const int K = (z == 2) ? 128 : 64;

  const int tid = threadIdx.x;
  const int wv = tid >> 6, lane = tid & 63;
  const int fr = lane & 15, q = lane >> 4;
  const int wave_m = wv >> 1, wave_n = wv & 1;
  const int m0 = blockIdx.x * 128;
  const int n0 = blockIdx.y * 128;

  f32x4 acc[4][4];
#pragma unroll
  for (int i = 0; i < 4; i++)
#pragma unroll
    for (int j = 0; j < 4; j++) acc[i][j] = (f32x4){0.f, 0.f, 0.f, 0.f};

  const int arow = tid >> 2;
  const int akc = (tid & 3) * 8;

  for (int k0 = 0; k0 < K; k0 += 32) {
#pragma unroll
    for (int i = 0; i < 2; ++i)
      gl2lds16(A + (size_t)(m0 + arow + i * 64) * K + k0 + akc, As + i * 2048 + wv * 512);
#pragma unroll
    for (int i = 0; i < 2; ++i)
      gl2lds16(BT + (size_t)(n0 + arow + i * 64) * K + k0 + akc, Bs + i * 2048 + wv * 512);
    __syncthreads();
    bf16x8 af[4], bfv[4];
#pragma unroll
    for (int i = 0; i < 4; i++)
      af[i] = *(const bf16x8*)(&As[(wave_m * 64 + i * 16 + fr) * SK + q * 8]);
#pragma unroll
    for (int j = 0; j < 4; j++)
      bfv[j] = *(const bf16x8*)(&Bs[(wave_n * 64 + j * 16 + fr) * SK + q * 8]);
#pragma unroll
    for (int i = 0; i < 4; i++)
#pragma unroll
      for (int j = 0; j < 4; j++)
        acc[i][j] = __builtin_amdgcn_mfma_f32_16x16x32_bf16(af[i], bfv[j], acc[i][j], 0, 0, 0);
    __syncthreads();
  }
#pragma unroll
  for (int i = 0; i < 4; i++)
#pragma unroll
    for (int j = 0; j < 4; j++) {
      const int mb = m0 + wave_m * 64 + i * 16 + q * 4;
      const int n = n0 + wave_n * 64 + j * 16 + fr;
#pragma unroll
      for (int r = 0; r < 4; r++)
        out[(size_t)(mb + r) * N + n] = f2bf(acc[i][j][r]);
    }
}

// Final projection GEMM (yg @ WoT -> out fp32)
__global__ __launch_bounds__(256) void gemm_out_kernel(
    const unsigned short* __restrict__ A,
    const unsigned short* __restrict__ BT,
    float* __restrict__ out)
{
  constexpr int K = 1024, N = 1024, SK = 32;
  __shared__ __align__(16) unsigned short As[128 * SK];
  __shared__ __align__(16) unsigned short Bs[128 * SK];
  const int tid = threadIdx.x;
  const int wv = tid >> 6, lane = tid & 63;
  const int fr = lane & 15, q = lane >> 4;
  const int wave_m = wv >> 1, wave_n = wv & 1;
  const int m0 = blockIdx.x * 128;
  const int n0 = blockIdx.y * 128;

  f32x4 acc[4][4];
#pragma unroll
  for (int i = 0; i < 4; i++)
#pragma unroll
    for (int j = 0; j < 4; j++) acc[i][j] = (f32x4){0.f, 0.f, 0.f, 0.f};

  const int arow = tid >> 2;
  const int akc = (tid & 3) * 8;

  for (int k0 = 0; k0 < K; k0 += 32) {
#pragma unroll
    for (int i = 0; i < 2; ++i)
      gl2lds16(A + (size_t)(m0 + arow + i * 64) * K + k0 + akc, As + i * 2048 + wv * 512);
#pragma unroll
    for (int i = 0; i < 2; ++i)
      gl2lds16(BT + (size_t)(n0 + arow + i * 64) * K + k0 + akc, Bs + i * 2048 + wv * 512);
    __syncthreads();
    bf16x8 af[4], bfv[4];
#pragma unroll
    for (int i = 0; i < 4; i++)
      af[i] = *(const bf16x8*)(&As[(wave_m * 64 + i * 16 + fr) * SK + q * 8]);
#pragma unroll
    for (int j = 0; j < 4; j++)
      bfv[j] = *(const bf16x8*)(&Bs[(wave_n * 64 + j * 16 + fr) * SK + q * 8]);
#pragma unroll
    for (int i = 0; i < 4; i++)
#pragma unroll
      for (int j = 0; j < 4; j++)
        acc[i][j] = __builtin_amdgcn_mfma_f32_16x16x32_bf16(af[i], bfv[j], acc[i][j], 0, 0, 0);
    __syncthreads();
  }
#pragma unroll
  for (int i = 0; i < 4; i++)
#pragma unroll
    for (int j = 0; j < 4; j++) {
      const int mb = m0 + wave_m * 64 + i * 16 + q * 4;
      const int n = n0 + wave_n * 64 + j * 16 + fr;
#pragma unroll
      for (int r = 0; r < 4; r++)
        out[(size_t)(mb + r) * N + n] = acc[i][j][r];
    }
}

// ---------------------------------------------------------------------------
// Phase 1 (MFMA): per-(bh,chunk) chunked-DPLR operators, postproc FUSED.
// v3: Y-solve eliminated via Qloc = (I-L)^-1 (LKA·V): W = LKA·V by MFMA, then
// a single dual-RHS blocked triangular solve (4x16 blocks). Cross-block terms
// via MFMA bridge reading XTb/QTb (col-major, K-contiguous); only 16x16
// diagonal recurrences stay on fp32 VALU. Solve is barrier-free (intra-wave).
// ---------------------------------------------------------------------------
__global__ __launch_bounds__(256, 2) void chunk_ops_kernel(
    const unsigned short* __restrict__ r_btc, const unsigned short* __restrict__ k_btc,
    const float* __restrict__ v_btc, const unsigned short* __restrict__ wraw,
    const unsigned short* __restrict__ araw,
    const float* __restrict__ w0, const float* __restrict__ a0,
    const float* __restrict__ k_k, const float* __restrict__ k_a,
    const float* __restrict__ r_k,
    unsigned short* __restrict__ McG, unsigned short* __restrict__ NcG,
    unsigned short* __restrict__ PcG, unsigned short* __restrict__ OlG,
    unsigned short* __restrict__ DkG, float* __restrict__ s3G)
{
  extern __shared__ char smraw[];
  unsigned short* AHb  = (unsigned short*)smraw;   // S1: Ahat -> XTb
  unsigned short* RHb  = AHb + 64 * RS;            // S2: Rhat (bf16, thru E)
  unsigned short* BPb  = RHb + 64 * RS;            // S3: Bp -> LKA -> W -> QTb
  unsigned short* KPb  = BPb + 64 * RS;            // S4: Kp -> DBR
  unsigned short* BPTb = KPb + 64 * RS;            // S5: Btil^T [i][t]
  unsigned short* KPTb = BPTb + 64 * RS;           // S6: Ktil^T [i][t]
  unsigned short* VSTb = KPTb + 64 * RS;           // S7: V^T [n][t]
  unsigned short* LBb  = VSTb + 64 * RS;           // S8: LBA bf16 (s68)
  float* GLs = (float*)(LBb + 64 * LBS);           // [64] total log-decay
  float* SS  = GLs + 64;                           // [4][64] strip sums
  unsigned short* XTb = AHb;                       // overlay after solve
  unsigned short* LKb = BPb;                       // overlay after Gram (LKA, then W)
  unsigned short* QTb = BPb;                       // overlay after Q-solve
  unsigned short* DBb = KPb;                       // overlay after Gram

  const int inst = blockIdx.x;
  const int bh = inst >> 4, c = inst & 15;
  const int b = bh >> 4, h = bh & 15;
  const int tid = threadIdx.x;
  const int lane = tid & 63;
  const int wv = tid >> 6;
  const int jl = lane;
  const int ch = h * 64 + jl;
  const size_t base = ((size_t)(b * 1024 + c * 64) * 1024) + ch;

  const float p_w0 = w0[ch], p_a0 = a0[ch];
  const float p_kk = k_k[ch], p_ka = k_a[ch], p_rk = r_k[ch];
  const float EM = 0.60653065971263342f;  // e^{-0.5}

  // ---- prefetch ALL per-token global inputs into registers (80 loads) ----
  unsigned short wr_u[16], kv_u[16], rv_u[16], ar_u[16];
  float vv_u[16];
#pragma unroll
  for (int u = 0; u < 16; ++u) {
    const size_t gi = base + (size_t)(16 * wv + u) * 1024;
    wr_u[u] = wraw[gi];
    kv_u[u] = k_btc[gi];
    rv_u[u] = r_btc[gi];
    ar_u[u] = araw[gi];
    vv_u[u] = v_btc[gi];
  }

  // ---- pass 1: inclusive log-decay prefix for my 16 rows + strip sum ----
  float lwv[16];
  {
    float run = 0.f;
#pragma unroll
    for (int u = 0; u < 16; ++u) {
      run += -EM * sigmoidf_(p_w0 + bf2f(wr_u[u]));
      lwv[u] = run;                       // inclusive prefix within strip
    }
    SS[wv * 64 + jl] = run;
  }
  __syncthreads();
  const float s0 = SS[0 * 64 + jl], s1 = SS[1 * 64 + jl];
  const float s2 = SS[2 * 64 + jl], s3s = SS[3 * 64 + jl];
  const float goff = (wv > 0 ? s0 : 0.f) + (wv > 1 ? s1 : 0.f) + (wv > 2 ? s2 : 0.f);
  const float gl = s0 + s1 + s2 + s3s;
  if (wv == 0) GLs[jl] = gl;

  // ---- pass 2: per-token transforms + factor matrices (independent u) ----
  float s3v[16];
  {
    const float e_gl = __expf(gl);
#pragma unroll
    for (int u = 0; u < 16; ++u) {
      const int t = 16 * wv + u;
      const float pre = goff + (u ? lwv[u - 1] : 0.f);   // g_{t-1}
      const float cur = goff + lwv[u];                   // g_t
      const float kv = bf2f(kv_u[u]), rv = bf2f(rv_u[u]);
      const float vv = vv_u[u];
      const float av = sigmoidf_(p_a0 + bf2f(ar_u[u]));
      const float kkx = kv * p_kk;
      float ssq = kkx * kkx;
#pragma unroll
      for (int m = 1; m < 64; m <<= 1) ssq += __shfl_xor(ssq, m);
      const float scale = __builtin_amdgcn_rsqf(fmaxf(ssq, 1e-24f));
      const float kkn = kkx * scale;
      const float bb = kkn * av;
      const float kmod = kv * (1.0f + (av - 1.0f) * p_ka);
      float s3 = rv * kmod * p_rk;
#pragma unroll
      for (int m = 1; m < 64; m <<= 1) s3 += __shfl_xor(s3, m);
      s3v[u] = s3;
      const float e_prev = __expf(pre);                  // exp(g_{t-1})
      const float e_gu   = __expf(cur);                  // exp(g_t), <= 1
      const float em     = __expf(-cur);                 // exp(-g_t)
      const float egl    = e_gl * em;                    // exp(gl-g_t) <= 1
      AHb[t * RS + jl] = f2bf(-kkn * e_prev);
      BPb[t * RS + jl] = f2bf(bb * em);
      KPb[t * RS + jl] = f2bf(kmod * em);
      BPTb[jl * RS + t] = f2bf(bb * egl);
      KPTb[jl * RS + t] = f2bf(kmod * egl);
      RHb[t * RS + jl] = f2bf(rv * e_gu);
      VSTb[jl * RS + t] = f2bf(vv);
    }
    if (jl == 0) {
      float* sp = s3G + (bh << 10) + (c << 6) + 16 * wv;
#pragma unroll
      for (int k2 = 0; k2 < 4; ++k2)
        *(float4*)(sp + 4 * k2) = make_float4(s3v[4 * k2], s3v[4 * k2 + 1],
                                              s3v[4 * k2 + 2], s3v[4 * k2 + 3]);
    }
  }
  __syncthreads();

  const int fr = lane & 15, q = lane >> 4;
  const int i0 = wv * 16;

  // ---- Gram products via MFMA: LBA, LKA, DBR, DKR(->global) ----
  {
    f32x4 aLB[4], aLK[4], aDB[4], aDK[4];
#pragma unroll
    for (int j = 0; j < 4; ++j) {
      aLB[j] = (f32x4){0.f, 0.f, 0.f, 0.f}; aLK[j] = (f32x4){0.f, 0.f, 0.f, 0.f};
      aDB[j] = (f32x4){0.f, 0.f, 0.f, 0.f}; aDK[j] = (f32x4){0.f, 0.f, 0.f, 0.f};
    }
#pragma unroll
    for (int ks = 0; ks < 2; ++ks) {
      const int ko = ks * 32 + q * 8;
      bf16x8 fA = *(const bf16x8*)(AHb + (i0 + fr) * RS + ko);
      bf16x8 fR = *(const bf16x8*)(RHb + (i0 + fr) * RS + ko);
#pragma unroll
      for (int j = 0; j < 4; ++j) {
        bf16x8 fB = *(const bf16x8*)(BPb + (j * 16 + fr) * RS + ko);
        bf16x8 fK = *(const bf16x8*)(KPb + (j * 16 + fr) * RS + ko);
        aLB[j] = __builtin_amdgcn_mfma_f32_16x16x32_bf16(fA, fB, aLB[j], 0, 0, 0);
        aLK[j] = __builtin_amdgcn_mfma_f32_16x16x32_bf16(fA, fK, aLK[j], 0, 0, 0);
        aDB[j] = __builtin_amdgcn_mfma_f32_16x16x32_bf16(fR, fB, aDB[j], 0, 0, 0);
        aDK[j] = __builtin_amdgcn_mfma_f32_16x16x32_bf16(fR, fK, aDK[j], 0, 0, 0);
      }
    }
    __syncthreads();   // all Gram fragment reads done before overlay stores
#pragma unroll
    for (int j = 0; j < 4; ++j) {
      const int s = j * 16 + fr;
#pragma unroll
      for (int r = 0; r < 4; ++r) {
        const int t = i0 + q * 4 + r;
        LBb[t * LBS + s] = f2bf((s < t) ? aLB[j][r] : 0.f);
        LKb[t * RS + s] = f2bf((s < t) ? aLK[j][r] : 0.f);
        DBb[t * RS + s] = f2bf((s <= t) ? aDB[j][r] : 0.f);
        DkG[(size_t)inst * 4096 + t * 64 + s] = f2bf((s <= t) ? aDK[j][r] : 0.f);
      }
    }
  }
  __syncthreads();

  // ---- W = LKA · V (MFMA, all waves; replaces Y-solve + Qloc) ----
  {
    f32x4 wacc[4];
#pragma unroll
    for (int j = 0; j < 4; ++j) wacc[j] = (f32x4){0.f, 0.f, 0.f, 0.f};
#pragma unroll
    for (int ks = 0; ks < 2; ++ks) {
      const int ko = ks * 32 + q * 8;
      bf16x8 fL = *(const bf16x8*)(LKb + (i0 + fr) * RS + ko);
#pragma unroll
      for (int j = 0; j < 4; ++j) {
        bf16x8 fV = *(const bf16x8*)(VSTb + (j * 16 + fr) * RS + ko);
        wacc[j] = __builtin_amdgcn_mfma_f32_16x16x32_bf16(fL, fV, wacc[j], 0, 0, 0);
      }
    }
#pragma unroll
    for (int j = 0; j < 4; ++j)
#pragma unroll
      for (int r = 0; r < 4; ++r)
        LKb[(i0 + q * 4 + r) * RS + j * 16 + fr] = f2bf(wacc[j][r]);
  }
  __syncthreads();

  // ---- prefetch DKR fragments from global (L2-hot: our own writes) ----
  bf16x8 fDK0, fDK1;
  {
    const unsigned short* dkp = DkG + (size_t)inst * 4096 + (i0 + fr) * 64 + q * 8;
    fDK0 = *(const bf16x8*)(dkp);
    fDK1 = *(const bf16x8*)(dkp + 32);
  }

  // ---- blocked dual triangular solve (barrier-free, intra-wave):
  //      wave0: (I-L)X = Ahat  -> XTb[jc][t];  wave1: (I-L)Q = W -> QTb[jc][t]
  if (wv < 2) {
    const int jc = lane;
    unsigned short* Sb = (wv == 0) ? AHb : LKb;    // RHS (consumed into regs)
    unsigned short* Tb = (wv == 0) ? XTb : QTb;    // col-major solution [jc][t]
    float x[64];
#pragma unroll
    for (int t = 0; t < 64; ++t) x[t] = bf2f(Sb[t * RS + jc]);
    // zero my solution row: bridge MFMAs read 0 for not-yet-solved t
#pragma unroll
    for (int z2 = 0; z2 < 8; ++z2)
      *(bf16x8*)(Tb + jc * RS + z2 * 8) = (bf16x8){0, 0, 0, 0, 0, 0, 0, 0};

    const int jf = jc & 15, tjm = jc >> 4;

#pragma unroll
    for (int I = 0; I < 4; ++I) {
      if (I > 0) {
        // bridge: x[16I+u] += sum_{s<16I} L[16I+u][s] * sol[s][jc]  (MFMA)
        f32x4 cU[4];
#pragma unroll
        for (int tj = 0; tj < 4; ++tj) cU[tj] = (f32x4){0.f, 0.f, 0.f, 0.f};
#pragma unroll
        for (int kw = 0; kw < 2; ++kw) {
          if (kw * 32 < 16 * I) {
            const int ko = kw * 32 + q * 8;
            bf16x8 fL;
            *(ushort4*)&fL = *(const ushort4*)(LBb + (16 * I + fr) * LBS + ko);
            *((ushort4*)&fL + 1) = *(const ushort4*)(LBb + (16 * I + fr) * LBS + ko + 4);
#pragma unroll
            for (int tj = 0; tj < 4; ++tj) {
              bf16x8 fX = *(const bf16x8*)(Tb + (tj * 16 + fr) * RS + ko);
              cU[tj] = __builtin_amdgcn_mfma_f32_16x16x32_bf16(fL, fX, cU[tj], 0, 0, 0);
            }
          }
        }
        // redistribute MFMA C-layout to column-owner lanes
#pragma unroll
        for (int qq = 0; qq < 4; ++qq) {
          const int saddr = (qq * 16 + jf) * 4;
#pragma unroll
          for (int r = 0; r < 4; ++r) {
            int g0 = __builtin_amdgcn_ds_bpermute(saddr, __builtin_bit_cast(int, cU[0][r]));
            int g1 = __builtin_amdgcn_ds_bpermute(saddr, __builtin_bit_cast(int, cU[1][r]));
            int g2 = __builtin_amdgcn_ds_bpermute(saddr, __builtin_bit_cast(int, cU[2][r]));
            int g3 = __builtin_amdgcn_ds_bpermute(saddr, __builtin_bit_cast(int, cU[3][r]));
            int gs = (tjm == 0) ? g0 : (tjm == 1) ? g1 : (tjm == 2) ? g2 : g3;
            x[16 * I + qq * 4 + r] += __builtin_bit_cast(float, gs);
          }
        }
      }
      // diagonal 16x16 unit-lower solve (fp32 chain, bf16 L)
#pragma unroll
      for (int u = 1; u < 16; ++u) {
        const unsigned short* lr = LBb + (16 * I + u) * LBS + 16 * I;
        float acc0 = 0.f, acc1 = 0.f;
#pragma unroll
        for (int s = 0; s + 2 <= u; s += 2) {
          acc0 = fmaf(bf2f(lr[s]), x[16 * I + s], acc0);
          acc1 = fmaf(bf2f(lr[s + 1]), x[16 * I + s + 1], acc1);
        }
        if (u & 1) acc0 = fmaf(bf2f(lr[u - 1]), x[16 * I + u - 1], acc0);
        x[16 * I + u] += acc0 + acc1;
      }
      // store solved block of my column (bf16 pairs)
#pragma unroll
      for (int t2 = 0; t2 < 16; t2 += 2) {
        unsigned int pk = (unsigned int)f2bf(x[16 * I + t2])
                        | ((unsigned int)f2bf(x[16 * I + t2 + 1]) << 16);
        *(unsigned int*)(Tb + jc * RS + 16 * I + t2) = pk;
      }
    }
  }
  __syncthreads();

  // ---- final operators: Mc, Ncc, Pc, Oloc (MFMA) -> global bf16 ----
  {
    f32x4 mA[4], nA[4], pA[4], oA[4];
#pragma unroll
    for (int j = 0; j < 4; ++j) {
      mA[j] = (f32x4){0.f, 0.f, 0.f, 0.f}; nA[j] = (f32x4){0.f, 0.f, 0.f, 0.f};
      pA[j] = (f32x4){0.f, 0.f, 0.f, 0.f}; oA[j] = (f32x4){0.f, 0.f, 0.f, 0.f};
    }
#pragma unroll
    for (int ks = 0; ks < 2; ++ks) {
      const int ko = ks * 32 + q * 8;
      bf16x8 fBT = *(const bf16x8*)(BPTb + (i0 + fr) * RS + ko);
      bf16x8 fKT = *(const bf16x8*)(KPTb + (i0 + fr) * RS + ko);
      bf16x8 fDB = *(const bf16x8*)(DBb + (i0 + fr) * RS + ko);
      bf16x8 fDK = ks ? fDK1 : fDK0;
#pragma unroll
      for (int j = 0; j < 4; ++j) {
        bf16x8 fXT = *(const bf16x8*)(XTb + (j * 16 + fr) * RS + ko);
        bf16x8 fQT = *(const bf16x8*)(QTb + (j * 16 + fr) * RS + ko);
        bf16x8 fVT = *(const bf16x8*)(VSTb + (j * 16 + fr) * RS + ko);
        mA[j] = __builtin_amdgcn_mfma_f32_16x16x32_bf16(fBT, fXT, mA[j], 0, 0, 0);
        nA[j] = __builtin_amdgcn_mfma_f32_16x16x32_bf16(fBT, fQT, nA[j], 0, 0, 0);
        nA[j] = __builtin_amdgcn_mfma_f32_16x16x32_bf16(fKT, fVT, nA[j], 0, 0, 0);
        pA[j] = __builtin_amdgcn_mfma_f32_16x16x32_bf16(fDB, fXT, pA[j], 0, 0, 0);
        oA[j] = __builtin_amdgcn_mfma_f32_16x16x32_bf16(fDB, fQT, oA[j], 0, 0, 0);
        oA[j] = __builtin_amdgcn_mfma_f32_16x16x32_bf16(fDK, fVT, oA[j], 0, 0, 0);
      }
    }
    const size_t ob = (size_t)inst * 4096;
    float eg[4];
#pragma unroll
    for (int r = 0; r < 4; ++r) eg[r] = __expf(GLs[i0 + q * 4 + r]);
#pragma unroll
    for (int j = 0; j < 4; ++j) {
      const int col = j * 16 + fr;
#pragma unroll
      for (int r = 0; r < 4; ++r) {
        const int row = i0 + q * 4 + r;
        const size_t oi = ob + (size_t)row * 64 + col;
        McG[oi] = f2bf(mA[j][r] + (row == col ? eg[r] : 0.f));
        NcG[oi] = f2bf(nA[j][r]);
        PcG[oi] = f2bf(pA[j][r] + bf2f(RHb[row * RS + col]));
        OlG[oi] = f2bf(oA[j][r]);
      }
    }
  }
}

// ---------------------------------------------------------------------------
// Phase 2 (v8, MFMA): sequential chunk-state propagation per (b,h):
// ST' = Mc ST + Ncc, state as ST^T bf16 hi/lo planes in LDS (fp32-class
// recurrence). v8: Sch is now written TRANSPOSED (SchT[ch][p], packed
// ushort4) so chunk_outgn can read k-contiguous B-fragments directly.
// ---------------------------------------------------------------------------
__global__ __launch_bounds__(256) void chunk_scan_kernel(
    const unsigned short* __restrict__ McG, const unsigned short* __restrict__ NcG,
    unsigned short* __restrict__ SchT)
{
  __shared__ __align__(16) unsigned short STh[64 * RS];  // ST^T hi: [col][row]
  __shared__ __align__(16) unsigned short STl[64 * RS];  // ST^T lo
  const int bh = blockIdx.x;
  const int tid = threadIdx.x;
  const int wv = tid >> 6, lane = tid & 63;
  const int fr = lane & 15, q = lane >> 4;

  f32x4 acc[4];   // state rows [16wv,16wv+16) x cols [16j,16j+16), C-layout

  // ---- c = 0: SchT[0] = 0; acc = Nc[0]; STT not read this chunk ----
  {
    const size_t ob = ((size_t)bh << 4) << 12;
#pragma unroll
    for (int j = 0; j < 4; ++j) {
      const int col = j * 16 + fr;
      *(ushort4*)(SchT + ob + (size_t)col * 64 + wv * 16 + q * 4) =
          make_ushort4(0, 0, 0, 0);
#pragma unroll
      for (int r = 0; r < 4; ++r) {
        const int row = wv * 16 + q * 4 + r;
        acc[j][r] = bf2f(NcG[ob + (size_t)row * 64 + col]);
      }
    }
  }

  for (int c = 1; c < 16; ++c) {
    const size_t ob = ((((size_t)bh << 4) + (size_t)c) << 12);
    // barrier A: prior iteration's B-reads of STT complete before rewrite
    __syncthreads();
    // write prev state (acc) into STT hi/lo; also SchT[c] = bf16(state)^T
#pragma unroll
    for (int j = 0; j < 4; ++j) {
      const int col = j * 16 + fr;
      ushort4 hs, ls;
#pragma unroll
      for (int r = 0; r < 4; ++r) {
        const float v = acc[j][r];
        const unsigned short hi = f2bf(v);
        const unsigned short lo = f2bf(v - bf2f(hi));
        if (r == 0) { hs.x = hi; ls.x = lo; }
        else if (r == 1) { hs.y = hi; ls.y = lo; }
        else if (r == 2) { hs.z = hi; ls.z = lo; }
        else { hs.w = hi; ls.w = lo; }
      }
      *(ushort4*)(STh + col * RS + wv * 16 + q * 4) = hs;
      *(ushort4*)(STl + col * RS + wv * 16 + q * 4) = ls;
      *(ushort4*)(SchT + ob + (size_t)col * 64 + wv * 16 + q * 4) = hs;
    }
    __syncthreads();
    // A-frags: Mc rows (16wv+fr), k-contig (L2-hot global, b128)
    const bf16x8 fA0 = *(const bf16x8*)(McG + ob + (size_t)(wv * 16 + fr) * 64 + q * 8);
    const bf16x8 fA1 = *(const bf16x8*)(McG + ob + (size_t)(wv * 16 + fr) * 64 + 32 + q * 8);
#pragma unroll
    for (int j = 0; j < 4; ++j) {
      const int col = j * 16 + fr;
#pragma unroll
      for (int r = 0; r < 4; ++r)
        acc[j][r] = bf2f(NcG[ob + (size_t)(wv * 16 + q * 4 + r) * 64 + col]);
      const bf16x8 h0 = *(const bf16x8*)(STh + (j * 16 + fr) * RS + q * 8);
      const bf16x8 h1 = *(const bf16x8*)(STh + (j * 16 + fr) * RS + 32 + q * 8);
      const bf16x8 l0 = *(const bf16x8*)(STl + (j * 16 + fr) * RS + q * 8);
      const bf16x8 l1 = *(const bf16x8*)(STl + (j * 16 + fr) * RS + 32 + q * 8);
      acc[j] = __builtin_amdgcn_mfma_f32_16x16x32_bf16(fA0, h0, acc[j], 0, 0, 0);
      acc[j] = __builtin_amdgcn_mfma_f32_16x16x32_bf16(fA1, h1, acc[j], 0, 0, 0);
      acc[j] = __builtin_amdgcn_mfma_f32_16x16x32_bf16(fA0, l0, acc[j], 0, 0, 0);
      acc[j] = __builtin_amdgcn_mfma_f32_16x16x32_bf16(fA1, l1, acc[j], 0, 0, 0);
    }
  }
  // final state (after chunk 15) is not needed downstream — done.
}

// ---------------------------------------------------------------------------
// Phase 3 + GroupNorm fused (v8, MFMA, barrier-free): Out = Pc ST + Oloc via
// 8 MFMAs/wave reading Pc (A, row-contig) and SchT (B, k-contig) straight
// from L2-hot global — no LDS staging, no barriers, no 64-iter VALU loop.
// GN row-reduce via 16-lane butterfly in the C-layout (same math as before).
// ---------------------------------------------------------------------------
__global__ __launch_bounds__(256) void chunk_outgn_kernel(
    const unsigned short* __restrict__ PcG, const unsigned short* __restrict__ OlG,
    const unsigned short* __restrict__ SchT, const float* __restrict__ s3G,
    const float* __restrict__ v_btc, const unsigned short* __restrict__ g_f,
    const float* __restrict__ gamma, const float* __restrict__ beta,
    unsigned short* __restrict__ yg)
{
  const int inst = blockIdx.x;
  const int bh = inst >> 4, c = inst & 15;
  const int b = bh >> 4, h = bh & 15;
  const int tid = threadIdx.x;
  const int wv = tid >> 6, lane = tid & 63;
  const int fr = lane & 15, q = lane >> 4;
  const int i0 = wv * 16;
  const size_t ob = (size_t)inst << 12;

  f32x4 acc[4];
#pragma unroll
  for (int j = 0; j < 4; ++j) {
    const int col = j * 16 + fr;
#pragma unroll
    for (int r = 0; r < 4; ++r)
      acc[j][r] = bf2f(OlG[ob + (size_t)(i0 + q * 4 + r) * 64 + col]);
  }
  const bf16x8 fA0 = *(const bf16x8*)(PcG + ob + (size_t)(i0 + fr) * 64 + q * 8);
  const bf16x8 fA1 = *(const bf16x8*)(PcG + ob + (size_t)(i0 + fr) * 64 + 32 + q * 8);
#pragma unroll
  for (int j = 0; j < 4; ++j) {
    const bf16x8 fB0 = *(const bf16x8*)(SchT + ob + (size_t)(j * 16 + fr) * 64 + q * 8);
    const bf16x8 fB1 = *(const bf16x8*)(SchT + ob + (size_t)(j * 16 + fr) * 64 + 32 + q * 8);
    acc[j] = __builtin_amdgcn_mfma_f32_16x16x32_bf16(fA0, fB0, acc[j], 0, 0, 0);
    acc[j] = __builtin_amdgcn_mfma_f32_16x16x32_bf16(fA1, fB1, acc[j], 0, 0, 0);
  }

  const int colb = h * 64;
  float ga[4], be[4];
#pragma unroll
  for (int j = 0; j < 4; ++j) {
    ga[j] = gamma[colb + j * 16 + fr];
    be[j] = beta[colb + j * 16 + fr];
  }

#pragma unroll
  for (int r = 0; r < 4; ++r) {
    float s1 = (acc[0][r] + acc[1][r]) + (acc[2][r] + acc[3][r]);
    float s2 = (acc[0][r] * acc[0][r] + acc[1][r] * acc[1][r])
             + (acc[2][r] * acc[2][r] + acc[3][r] * acc[3][r]);
#pragma unroll
    for (int m = 1; m < 16; m <<= 1) {
      s1 += __shfl_xor(s1, m);
      s2 += __shfl_xor(s2, m);
    }
    const float mean = s1 * (1.0f / 64.0f);
    const float var = s2 * (1.0f / 64.0f) - mean * mean;
    const float rstd = __builtin_amdgcn_rsqf(var + 0.00064f);
    const int row = i0 + q * 4 + r;
    const int tok = c * 64 + row;
    const float s3 = s3G[(bh << 10) + tok];
    const size_t gaddr = ((size_t)(b * 1024 + tok) * 1024) + colb;
#pragma unroll
    for (int j = 0; j < 4; ++j) {
      const int col = j * 16 + fr;
      const float vv = v_btc[gaddr + col];
      const float gg = bf2f(g_f[gaddr + col]);
      yg[gaddr + col] =
          f2bf(((acc[j][r] - mean) * rstd * ga[j] + be[j] + s3 * vv) * gg);
    }
  }
}

// ---------------------------------------------------------------------------
extern "C" void kernel_launch(void* const* d_in, const int* in_sizes, int n_in,
                              void* d_out, int out_size, void* d_ws, size_t ws_size,
                              hipStream_t stream)
{
  (void)in_sizes; (void)n_in; (void)out_size;
  const float* x    = (const float*)d_in[0];
  const float* x_r  = (const float*)d_in[1];
  const float* x_w  = (const float*)d_in[2];
  const float* x_k  = (const float*)d_in[3];
  const float* x_v  = (const float*)d_in[4];
  const float* x_a  = (const float*)d_in[5];
  const float* x_g  = (const float*)d_in[6];
  const float* w0   = (const float*)d_in[7];
  const float* w1   = (const float*)d_in[8];
  const float* w2   = (const float*)d_in[9];
  const float* a0   = (const float*)d_in[10];
  const float* a1   = (const float*)d_in[11];
  const float* a2   = (const float*)d_in[12];
  const float* g1   = (const float*)d_in[16];
  const float* g2   = (const float*)d_in[17];
  const float* k_k  = (const float*)d_in[18];
  const float* k_a  = (const float*)d_in[19];
  const float* r_k  = (const float*)d_in[20];
  const float* Wr   = (const float*)d_in[21];
  const float* Wk   = (const float*)d_in[22];
  const float* Wv   = (const float*)d_in[23];
  const float* Wo   = (const float*)d_in[24];
  const float* ln_g = (const float*)d_in[25];
  const float* ln_b = (const float*)d_in[26];

  float* outp = (float*)d_out;
  float* vfirst = outp + (size_t)BB * TT * CCH;

  char* ws = (char*)d_ws;
  size_t off = 0;
  auto alloc = [&](size_t bytes) -> char* {
    char* p = ws + off;
    off += (bytes + 255) & ~(size_t)255;
    return p;
  };

  unsigned short* WrT = (unsigned short*)alloc(2097152);
  unsigned short* WkT = (unsigned short*)alloc(2097152);
  unsigned short* WvT = (unsigned short*)alloc(2097152);
  unsigned short* WoT = (unsigned short*)alloc(2097152);
  unsigned short* w1T = (unsigned short*)alloc(131072);
  unsigned short* w2T = (unsigned short*)alloc(131072);
  unsigned short* a1T = (unsigned short*)alloc(131072);
  unsigned short* a2T = (unsigned short*)alloc(131072);
  unsigned short* g1T = (unsigned short*)alloc(262144);
  unsigned short* g2T = (unsigned short*)alloc(262144);
  unsigned short* xrB = (unsigned short*)alloc(8388608);
  unsigned short* xwB = (unsigned short*)alloc(8388608);
  unsigned short* xkB = (unsigned short*)alloc(8388608);
  unsigned short* xvB = (unsigned short*)alloc(8388608);
  unsigned short* xaB = (unsigned short*)alloc(8388608);
  unsigned short* xgB = (unsigned short*)alloc(8388608);
  unsigned short* r_btc = (unsigned short*)alloc(8388608);
  unsigned short* k_btc = (unsigned short*)alloc(8388608);
  unsigned short* wraw  = (unsigned short*)alloc(8388608);
  unsigned short* araw  = (unsigned short*)alloc(8388608);
  unsigned short* gfB = (unsigned short*)alloc(8388608);
  unsigned short* OlG = (unsigned short*)alloc(8388608);
  unsigned short* DkG = (unsigned short*)alloc(8388608);
  float* s3G   = (float*)alloc(262144);
  unsigned short* hwB = (unsigned short*)alloc(524288);
  unsigned short* haB = (unsigned short*)alloc(524288);
  unsigned short* hgB = (unsigned short*)alloc(1048576);
  unsigned short* ygB = (unsigned short*)alloc(8388608);

  // overlays (owners dead before the writer runs)
  unsigned short* McG = xrB;          // over xrB (dead after gemm_stage1)
  unsigned short* NcG = xkB;          // over xkB
  unsigned short* PcG = xaB;          // over xaB
  unsigned short* Sch = k_btc;        // k_btc dead after chunk_ops (SchT layout)

  if (off > ws_size) return;

  dim3 blk(256);

  // transposes + mix in one launch
  prep_kernel<<<5248, blk, 0, stream>>>(
      x, x_r, x_w, x_k, x_v, x_a, x_g,
      xrB, xwB, xkB, xvB, xaB, xgB,
      Wr, Wk, Wv, Wo, WrT, WkT, WvT, WoT,
      w1, w2, a1, a2, g1, g2, w1T, w2T, a1T, a2T, g1T, g2T);

  // r/k/v GEMMs + lora1 in one launch; v straight into vfirst (output 1)
  gemm_stage1_kernel<<<896, blk, 0, stream>>>(
      xrB, xkB, xvB, WrT, WkT, WvT, r_btc, k_btc, vfirst,
      xwB, xaB, xgB, w1T, a1T, g1T, hwB, haB, hgB);

  // LoRA stage 2 (w/a/g) in one launch
  lora2_kernel<<<dim3(32, 8, 3), blk, 0, stream>>>(
      hwB, haB, hgB, w2T, a2T, g2T, wraw, araw, gfB);

  // chunked-DPLR scan phase 1 (postproc fused, 2 blocks/CU)
  constexpr int CHUNK_LDS = 7 * 64 * RS * 2 + 64 * LBS * 2 + 64 * 4 + 4 * 64 * 4;
  hipFuncSetAttribute((const void*)chunk_ops_kernel,
                      hipFuncAttributeMaxDynamicSharedMemorySize, CHUNK_LDS);
  chunk_ops_kernel<<<1024, blk, CHUNK_LDS, stream>>>(
      r_btc, k_btc, vfirst, wraw, araw, w0, a0, k_k, k_a, r_k,
      McG, NcG, PcG, OlG, DkG, s3G);

  chunk_scan_kernel<<<64, blk, 0, stream>>>(McG, NcG, Sch);

  chunk_outgn_kernel<<<1024, blk, 0, stream>>>(PcG, OlG, Sch, s3G, vfirst, gfB,
                                               ln_g, ln_b, ygB);

  gemm_out_kernel<<<dim3(32, 8), blk, 0, stream>>>(ygB, WoT, outp);
}

// Round 12
// 303.297 us; speedup vs baseline: 1.2217x; 1.0290x over previous
//
#include <hip/hip_runtime.h>
#include <hip/hip_bf16.h>
#include <math.h>

// Problem constants
#define BB 4
#define TT 1024
#define CCH 1024
#define HH 16
#define NNd 64
#define RS 72       // bf16 LDS row stride in shorts (144B = 9x16B, frag-aligned)
#define LBS 68      // bf16 L-matrix row stride in shorts (136B, 8B-aligned u4)

typedef short bf16x8 __attribute__((ext_vector_type(8)));
typedef float f32x4 __attribute__((ext_vector_type(4)));

__device__ __forceinline__ unsigned short f2bf(float f) {
  __hip_bfloat16 h = __float2bfloat16(f);
  return __builtin_bit_cast(unsigned short, h);
}
__device__ __forceinline__ float bf2f(unsigned short u) {
  unsigned int x = (unsigned int)u << 16;
  return __builtin_bit_cast(float, x);
}
// Native transcendentals: outputs all round through bf16 downstream, so
// v_exp/v_rcp/v_rsq (~1 ulp) precision is far below bf16 quantization.
__device__ __forceinline__ float sigmoidf_(float x) {
  return __builtin_amdgcn_rcpf(1.0f + __expf(-x));
}
__device__ __forceinline__ float ftanh_(float x) {
  // tanh(x) = 1 - 2/(e^{2x}+1); saturates correctly at +/-inf.
  return 1.0f - 2.0f * __builtin_amdgcn_rcpf(__expf(2.0f * x) + 1.0f);
}

// async global->LDS, 16B per lane; LDS dest must be wave-uniform base + 16*lane
__device__ __forceinline__ void gl2lds16(const unsigned short* g, unsigned short* l) {
  __builtin_amdgcn_global_load_lds(
      (const __attribute__((address_space(1))) unsigned int*)g,
      (__attribute__((address_space(3))) unsigned int*)l, 16, 0, 0);
}

// ---------------------------------------------------------------------------
// Transpose tile helper
// ---------------------------------------------------------------------------
__device__ __forceinline__ void transpose_tile(
    const float* __restrict__ in, unsigned short* __restrict__ out,
    int R, int Cc, int r0, int c0, unsigned short (*tile)[68], int t)
{
  const int rr = t >> 4;
  const int cc = (t & 15) * 4;
#pragma unroll
  for (int p = 0; p < 4; ++p) {
    int row = p * 16 + rr;
    float4 v = *(const float4*)(in + (size_t)(r0 + row) * Cc + c0 + cc);
    tile[row][cc]     = f2bf(v.x);
    tile[row][cc + 1] = f2bf(v.y);
    tile[row][cc + 2] = f2bf(v.z);
    tile[row][cc + 3] = f2bf(v.w);
  }
  __syncthreads();
#pragma unroll
  for (int p = 0; p < 4; ++p) {
    int row = p * 16 + rr;
    ushort4 o;
    o.x = tile[cc][row];
    o.y = tile[cc + 1][row];
    o.z = tile[cc + 2][row];
    o.w = tile[cc + 3][row];
    *(ushort4*)(out + (size_t)(c0 + row) * R + r0 + cc) = o;
  }
}

// ---------------------------------------------------------------------------
// prep_kernel: mix (blocks 0..4095) + big4 transposes (4096..5119)
//            + lora transposes (5120..5247), one launch.
// ---------------------------------------------------------------------------
__global__ __launch_bounds__(256) void prep_kernel(
    const float* __restrict__ x,
    const float* __restrict__ cr, const float* __restrict__ cw,
    const float* __restrict__ ck, const float* __restrict__ cv,
    const float* __restrict__ ca, const float* __restrict__ cg,
    unsigned short* __restrict__ xr, unsigned short* __restrict__ xw,
    unsigned short* __restrict__ xk, unsigned short* __restrict__ xv,
    unsigned short* __restrict__ xa, unsigned short* __restrict__ xg,
    const float* __restrict__ W0, const float* __restrict__ W1,
    const float* __restrict__ W2, const float* __restrict__ W3,
    unsigned short* __restrict__ T0, unsigned short* __restrict__ T1,
    unsigned short* __restrict__ T2, unsigned short* __restrict__ T3,
    const float* __restrict__ w1, const float* __restrict__ w2,
    const float* __restrict__ a1, const float* __restrict__ a2,
    const float* __restrict__ g1, const float* __restrict__ g2,
    unsigned short* __restrict__ w1T, unsigned short* __restrict__ w2T,
    unsigned short* __restrict__ a1T, unsigned short* __restrict__ a2T,
    unsigned short* __restrict__ g1T, unsigned short* __restrict__ g2T)
{
  __shared__ unsigned short tile[64][68];
  const int blk = blockIdx.x;
  const int tid = threadIdx.x;
  if (blk < 4096) {
    // ---- token-shift mix ----
    const size_t idx = ((size_t)blk * 256 + tid) * 4;
    const int c = (int)(idx & 1023);
    const int t = (int)((idx >> 10) & 1023);
    float4 xc = *(const float4*)(x + idx);
    float4 xp = make_float4(0.f, 0.f, 0.f, 0.f);
    if (t > 0) xp = *(const float4*)(x + idx - 1024);
    float4 dx = make_float4(xp.x - xc.x, xp.y - xc.y, xp.z - xc.z, xp.w - xc.w);
    auto st = [&](unsigned short* dst, const float* coef) {
      float4 w = *(const float4*)(coef + c);
      ushort4 o;
      o.x = f2bf(fmaf(dx.x, w.x, xc.x));
      o.y = f2bf(fmaf(dx.y, w.y, xc.y));
      o.z = f2bf(fmaf(dx.z, w.z, xc.z));
      o.w = f2bf(fmaf(dx.w, w.w, xc.w));
      *(ushort4*)(dst + idx) = o;
    };
    st(xr, cr); st(xw, cw); st(xk, ck); st(xv, cv); st(xa, ca); st(xg, cg);
  } else if (blk < 5120) {
    const int j = blk - 4096;
    const int z = j >> 8, rem = j & 255;
    const int ty = rem >> 4, tx = rem & 15;
    const float* src = (z == 0) ? W0 : (z == 1) ? W1 : (z == 2) ? W2 : W3;
    unsigned short* dst = (z == 0) ? T0 : (z == 1) ? T1 : (z == 2) ? T2 : T3;
    transpose_tile(src, dst, 1024, 1024, tx * 64, ty * 64, tile, tid);
  } else {
    const int i = blk - 5120;
    const float* src; unsigned short* dst; int R, C, rt, ct;
    if (i < 16)      { src = w1; dst = w1T; R = 1024; C = 64;   rt = i;      ct = 0; }
    else if (i < 32) { src = w2; dst = w2T; R = 64;   C = 1024; rt = 0;      ct = i - 16; }
    else if (i < 48) { src = a1; dst = a1T; R = 1024; C = 64;   rt = i - 32; ct = 0; }
    else if (i < 64) { src = a2; dst = a2T; R = 64;   C = 1024; rt = 0;      ct = i - 48; }
    else if (i < 96) { int k = i - 64; src = g1; dst = g1T; R = 1024; C = 128; rt = k >> 1; ct = k & 1; }
    else             { int k = i - 96; src = g2; dst = g2T; R = 128; C = 1024; rt = k & 1;  ct = k >> 1; }
    transpose_tile(src, dst, R, C, rt * 64, ct * 64, tile, tid);
  }
}

// ---------------------------------------------------------------------------
// gemm_stage1 (v9): blocks 0..1535 = r/k/v big GEMMs with 128x64 tiles
// (z = blk/512) to raise blocks/CU 3.5 -> 6.5 (stall-hiding via occupancy;
// profile showed 17% occupancy = grid-starved). 1536..1663 = lora1.
// ---------------------------------------------------------------------------
__global__ __launch_bounds__(256) void gemm_stage1_kernel(
    const unsigned short* __restrict__ xrB, const unsigned short* __restrict__ xkB,
    const unsigned short* __restrict__ xvB,
    const unsigned short* __restrict__ WrT, const unsigned short* __restrict__ WkT,
    const unsigned short* __restrict__ WvT,
    unsigned short* __restrict__ r_btc, unsigned short* __restrict__ k_btc,
    float* __restrict__ v_btc,
    const unsigned short* __restrict__ xwB, const unsigned short* __restrict__ xaB,
    const unsigned short* __restrict__ xgB,
    const unsigned short* __restrict__ w1T, const unsigned short* __restrict__ a1T,
    const unsigned short* __restrict__ g1T,
    unsigned short* __restrict__ hwB, unsigned short* __restrict__ haB,
    unsigned short* __restrict__ hgB)
{
  constexpr int K = 1024, SK = 32;
  __shared__ __align__(16) unsigned short As[128 * SK];
  __shared__ __align__(16) unsigned short Bs[64 * SK];
  const int blk = blockIdx.x;
  const int tid = threadIdx.x;
  const int wv = tid >> 6, lane = tid & 63;
  const int fr = lane & 15, q = lane >> 4;
  const int arow = tid >> 2;
  const int akc = (tid & 3) * 8;

  if (blk < 1536) {
    // ---- big3 GEMM, 128x64 tile: z selects r/k/v ----
    const int z = blk >> 9, rem = blk & 511;
    const int m0 = (rem & 31) * 128;
    const int n0 = (rem >> 5) * 64;
    const unsigned short* A = (z == 0) ? xrB : (z == 1) ? xkB : xvB;
    const unsigned short* BT = (z == 0) ? WrT : (z == 1) ? WkT : WvT;
    const int wave_m = wv >> 1, wave_n = wv & 1;   // 2x2 waves of 64x32

    f32x4 acc[4][2];
#pragma unroll
    for (int i = 0; i < 4; i++)
#pragma unroll
      for (int j = 0; j < 2; j++) acc[i][j] = (f32x4){0.f, 0.f, 0.f, 0.f};

    for (int k0 = 0; k0 < K; k0 += 32) {
#pragma unroll
      for (int i = 0; i < 2; ++i)
        gl2lds16(A + (size_t)(m0 + arow + i * 64) * K + k0 + akc, As + i * 2048 + wv * 512);
      gl2lds16(BT + (size_t)(n0 + arow) * K + k0 + akc, Bs + wv * 512);
      __syncthreads();
      bf16x8 af[4], bfv[2];
#pragma unroll
      for (int i = 0; i < 4; i++)
        af[i] = *(const bf16x8*)(&As[(wave_m * 64 + i * 16 + fr) * SK + q * 8]);
#pragma unroll
      for (int j = 0; j < 2; j++)
        bfv[j] = *(const bf16x8*)(&Bs[(wave_n * 32 + j * 16 + fr) * SK + q * 8]);
#pragma unroll
      for (int i = 0; i < 4; i++)
#pragma unroll
        for (int j = 0; j < 2; j++)
          acc[i][j] = __builtin_amdgcn_mfma_f32_16x16x32_bf16(af[i], bfv[j], acc[i][j], 0, 0, 0);
      __syncthreads();
    }
#pragma unroll
    for (int i = 0; i < 4; i++)
#pragma unroll
      for (int j = 0; j < 2; j++) {
        const int mb = m0 + wave_m * 64 + i * 16 + q * 4;
        const int n = n0 + wave_n * 32 + j * 16 + fr;
#pragma unroll
        for (int r = 0; r < 4; r++) {
          if (z == 0)      r_btc[(size_t)(mb + r) * 1024 + n] = f2bf(acc[i][j][r]);
          else if (z == 1) k_btc[(size_t)(mb + r) * 1024 + n] = f2bf(acc[i][j][r]);
          else             v_btc[(size_t)(mb + r) * 1024 + n] = acc[i][j][r];
        }
      }
  } else {
    // ---- lora1: y=0 hw=tanh, y=1 ha, y=2/3 hg sigmoid halves ----
    const int j2 = blk - 1536;
    const int y = j2 >> 5;
    const int m0 = (j2 & 31) * 128;
    const unsigned short* A  = (y == 0) ? xwB : (y == 1) ? xaB : xgB;
    const unsigned short* BT = (y == 0) ? w1T : (y == 1) ? a1T : (g1T + (size_t)(y - 2) * 64 * K);
    unsigned short* outb = (y == 0) ? hwB : (y == 1) ? haB : hgB;
    const int Nout = (y < 2) ? 64 : 128;
    const int ncol0 = (y < 2) ? 0 : (y - 2) * 64;

    f32x4 acc[2][4];
#pragma unroll
    for (int i = 0; i < 2; i++)
#pragma unroll
      for (int j = 0; j < 4; j++) acc[i][j] = (f32x4){0.f, 0.f, 0.f, 0.f};

    for (int k0 = 0; k0 < K; k0 += 32) {
#pragma unroll
      for (int i = 0; i < 2; ++i)
        gl2lds16(A + (size_t)(m0 + arow + i * 64) * K + k0 + akc, As + i * 2048 + wv * 512);
      gl2lds16(BT + (size_t)arow * K + k0 + akc, Bs + wv * 512);
      __syncthreads();
      bf16x8 af[2], bfv[4];
#pragma unroll
      for (int i = 0; i < 2; i++)
        af[i] = *(const bf16x8*)(&As[(wv * 32 + i * 16 + fr) * SK + q * 8]);
#pragma unroll
      for (int j = 0; j < 4; j++)
        bfv[j] = *(const bf16x8*)(&Bs[(j * 16 + fr) * SK + q * 8]);
#pragma unroll
      for (int i = 0; i < 2; i++)
#pragma unroll
        for (int j = 0; j < 4; j++)
          acc[i][j] = __builtin_amdgcn_mfma_f32_16x16x32_bf16(af[i], bfv[j], acc[i][j], 0, 0, 0);
      __syncthreads();
    }
#pragma unroll
    for (int i = 0; i < 2; i++)
#pragma unroll
      for (int j = 0; j < 4; j++) {
        const int mb = m0 + wv * 32 + i * 16 + q * 4;
        const int n = ncol0 + j * 16 + fr;
#pragma unroll
        for (int r = 0; r < 4; r++) {
          float val = acc[i][j][r];
          if (y == 0) val = ftanh_(val);
          else if (y >= 2) val = sigmoidf_(val);
          outb[(size_t)(mb + r) * Nout + n] = f2bf(val);
        }
      }
  }
}

// z-batched LoRA-2 GEMMs -> all bf16 outputs (wraw, araw, g).
__global__ __launch_bounds__(256) void lora2_kernel(
    const unsigned short* __restrict__ hwB, const unsigned short* __restrict__ haB,
    const unsigned short* __restrict__ hgB,
    const unsigned short* __restrict__ w2T, const unsigned short* __restrict__ a2T,
    const unsigned short* __restrict__ g2T,
    unsigned short* __restrict__ wraw, unsigned short* __restrict__ araw,
    unsigned short* __restrict__ gfB)
{
  constexpr int N = 1024, SK = 32;
  __shared__ __align__(16) unsigned short As[128 * SK];
  __shared__ __align__(16) unsigned short Bs[128 * SK];
  const int z = blockIdx.z;
  const unsigned short* A = (z == 0) ? hwB : (z == 1) ? haB : hgB;
  const unsigned short* BT = (z == 0) ? w2T : (z == 1) ? a2T : g2T;
  unsigned short* out = (z == 0) ? wraw : (z == 1) ? araw : gfB;
  const int K = (z == 2) ? 128 : 64;

  const int tid = threadIdx.x;
  const int wv = tid >> 6, lane = tid & 63;
  const int fr = lane & 15, q = lane >> 4;
  const int wave_m = wv >> 1, wave_n = wv & 1;
  const int m0 = blockIdx.x * 128;
  const int n0 = blockIdx.y * 128;

  f32x4 acc[4][4];
#pragma unroll
  for (int i = 0; i < 4; i++)
#pragma unroll
    for (int j = 0; j < 4; j++) acc[i][j] = (f32x4){0.f, 0.f, 0.f, 0.f};

  const int arow = tid >> 2;
  const int akc = (tid & 3) * 8;

  for (int k0 = 0; k0 < K; k0 += 32) {
#pragma unroll
    for (int i = 0; i < 2; ++i)
      gl2lds16(A + (size_t)(m0 + arow + i * 64) * K + k0 + akc, As + i * 2048 + wv * 512);
#pragma unroll
    for (int i = 0; i < 2; ++i)
      gl2lds16(BT + (size_t)(n0 + arow + i * 64) * K + k0 + akc, Bs + i * 2048 + wv * 512);
    __syncthreads();
    bf16x8 af[4], bfv[4];
#pragma unroll
    for (int i = 0; i < 4; i++)
      af[i] = *(const bf16x8*)(&As[(wave_m * 64 + i * 16 + fr) * SK + q * 8]);
#pragma unroll
    for (int j = 0; j < 4; j++)
      bfv[j] = *(const bf16x8*)(&Bs[(wave_n * 64 + j * 16 + fr) * SK + q * 8]);
#pragma unroll
    for (int i = 0; i < 4; i++)
#pragma unroll
      for (int j = 0; j < 4; j++)
        acc[i][j] = __builtin_amdgcn_mfma_f32_16x16x32_bf16(af[i], bfv[j], acc[i][j], 0, 0, 0);
    __syncthreads();
  }
#pragma unroll
  for (int i = 0; i < 4; i++)
#pragma unroll
    for (int j = 0; j < 4; j++) {
      const int mb = m0 + wave_m * 64 + i * 16 + q * 4;
      const int n = n0 + wave_n * 64 + j * 16 + fr;
#pragma unroll
      for (int r = 0; r < 4; r++)
        out[(size_t)(mb + r) * N + n] = f2bf(acc[i][j][r]);
    }
}

// Final projection GEMM (yg @ WoT -> out fp32)
__global__ __launch_bounds__(256) void gemm_out_kernel(
    const unsigned short* __restrict__ A,
    const unsigned short* __restrict__ BT,
    float* __restrict__ out)
{
  constexpr int K = 1024, N = 1024, SK = 32;
  __shared__ __align__(16) unsigned short As[128 * SK];
  __shared__ __align__(16) unsigned short Bs[128 * SK];
  const int tid = threadIdx.x;
  const int wv = tid >> 6, lane = tid & 63;
  const int fr = lane & 15, q = lane >> 4;
  const int wave_m = wv >> 1, wave_n = wv & 1;
  const int m0 = blockIdx.x * 128;
  const int n0 = blockIdx.y * 128;

  f32x4 acc[4][4];
#pragma unroll
  for (int i = 0; i < 4; i++)
#pragma unroll
    for (int j = 0; j < 4; j++) acc[i][j] = (f32x4){0.f, 0.f, 0.f, 0.f};

  const int arow = tid >> 2;
  const int akc = (tid & 3) * 8;

  for (int k0 = 0; k0 < K; k0 += 32) {
#pragma unroll
    for (int i = 0; i < 2; ++i)
      gl2lds16(A + (size_t)(m0 + arow + i * 64) * K + k0 + akc, As + i * 2048 + wv * 512);
#pragma unroll
    for (int i = 0; i < 2; ++i)
      gl2lds16(BT + (size_t)(n0 + arow + i * 64) * K + k0 + akc, Bs + i * 2048 + wv * 512);
    __syncthreads();
    bf16x8 af[4], bfv[4];
#pragma unroll
    for (int i = 0; i < 4; i++)
      af[i] = *(const bf16x8*)(&As[(wave_m * 64 + i * 16 + fr) * SK + q * 8]);
#pragma unroll
    for (int j = 0; j < 4; j++)
      bfv[j] = *(const bf16x8*)(&Bs[(wave_n * 64 + j * 16 + fr) * SK + q * 8]);
#pragma unroll
    for (int i = 0; i < 4; i++)
#pragma unroll
      for (int j = 0; j < 4; j++)
        acc[i][j] = __builtin_amdgcn_mfma_f32_16x16x32_bf16(af[i], bfv[j], acc[i][j], 0, 0, 0);
    __syncthreads();
  }
#pragma unroll
  for (int i = 0; i < 4; i++)
#pragma unroll
    for (int j = 0; j < 4; j++) {
      const int mb = m0 + wave_m * 64 + i * 16 + q * 4;
      const int n = n0 + wave_n * 64 + j * 16 + fr;
#pragma unroll
      for (int r = 0; r < 4; r++)
        out[(size_t)(mb + r) * N + n] = acc[i][j][r];
    }
}

// ---------------------------------------------------------------------------
// Phase 1 (MFMA): per-(bh,chunk) chunked-DPLR operators, postproc FUSED.
// v3: Y-solve eliminated via Qloc = (I-L)^-1 (LKA·V): W = LKA·V by MFMA, then
// a single dual-RHS blocked triangular solve (4x16 blocks). Cross-block terms
// via MFMA bridge reading XTb/QTb (col-major, K-contiguous); only 16x16
// diagonal recurrences stay on fp32 VALU. Solve is barrier-free (intra-wave).
// ---------------------------------------------------------------------------
__global__ __launch_bounds__(256, 2) void chunk_ops_kernel(
    const unsigned short* __restrict__ r_btc, const unsigned short* __restrict__ k_btc,
    const float* __restrict__ v_btc, const unsigned short* __restrict__ wraw,
    const unsigned short* __restrict__ araw,
    const float* __restrict__ w0, const float* __restrict__ a0,
    const float* __restrict__ k_k, const float* __restrict__ k_a,
    const float* __restrict__ r_k,
    unsigned short* __restrict__ McG, unsigned short* __restrict__ NcG,
    unsigned short* __restrict__ PcG, unsigned short* __restrict__ OlG,
    unsigned short* __restrict__ DkG, float* __restrict__ s3G)
{
  extern __shared__ char smraw[];
  unsigned short* AHb  = (unsigned short*)smraw;   // S1: Ahat -> XTb
  unsigned short* RHb  = AHb + 64 * RS;            // S2: Rhat (bf16, thru E)
  unsigned short* BPb  = RHb + 64 * RS;            // S3: Bp -> LKA -> W -> QTb
  unsigned short* KPb  = BPb + 64 * RS;            // S4: Kp -> DBR
  unsigned short* BPTb = KPb + 64 * RS;            // S5: Btil^T [i][t]
  unsigned short* KPTb = BPTb + 64 * RS;           // S6: Ktil^T [i][t]
  unsigned short* VSTb = KPTb + 64 * RS;           // S7: V^T [n][t]
  unsigned short* LBb  = VSTb + 64 * RS;           // S8: LBA bf16 (s68)
  float* GLs = (float*)(LBb + 64 * LBS);           // [64] total log-decay
  float* SS  = GLs + 64;                           // [4][64] strip sums
  unsigned short* XTb = AHb;                       // overlay after solve
  unsigned short* LKb = BPb;                       // overlay after Gram (LKA, then W)
  unsigned short* QTb = BPb;                       // overlay after Q-solve
  unsigned short* DBb = KPb;                       // overlay after Gram

  const int inst = blockIdx.x;
  const int bh = inst >> 4, c = inst & 15;
  const int b = bh >> 4, h = bh & 15;
  const int tid = threadIdx.x;
  const int lane = tid & 63;
  const int wv = tid >> 6;
  const int jl = lane;
  const int ch = h * 64 + jl;
  const size_t base = ((size_t)(b * 1024 + c * 64) * 1024) + ch;

  const float p_w0 = w0[ch], p_a0 = a0[ch];
  const float p_kk = k_k[ch], p_ka = k_a[ch], p_rk = r_k[ch];
  const float EM = 0.60653065971263342f;  // e^{-0.5}

  // ---- prefetch ALL per-token global inputs into registers (80 loads) ----
  unsigned short wr_u[16], kv_u[16], rv_u[16], ar_u[16];
  float vv_u[16];
#pragma unroll
  for (int u = 0; u < 16; ++u) {
    const size_t gi = base + (size_t)(16 * wv + u) * 1024;
    wr_u[u] = wraw[gi];
    kv_u[u] = k_btc[gi];
    rv_u[u] = r_btc[gi];
    ar_u[u] = araw[gi];
    vv_u[u] = v_btc[gi];
  }

  // ---- pass 1: inclusive log-decay prefix for my 16 rows + strip sum ----
  float lwv[16];
  {
    float run = 0.f;
#pragma unroll
    for (int u = 0; u < 16; ++u) {
      run += -EM * sigmoidf_(p_w0 + bf2f(wr_u[u]));
      lwv[u] = run;                       // inclusive prefix within strip
    }
    SS[wv * 64 + jl] = run;
  }
  __syncthreads();
  const float s0 = SS[0 * 64 + jl], s1 = SS[1 * 64 + jl];
  const float s2 = SS[2 * 64 + jl], s3s = SS[3 * 64 + jl];
  const float goff = (wv > 0 ? s0 : 0.f) + (wv > 1 ? s1 : 0.f) + (wv > 2 ? s2 : 0.f);
  const float gl = s0 + s1 + s2 + s3s;
  if (wv == 0) GLs[jl] = gl;

  // ---- pass 2: per-token transforms + factor matrices (independent u) ----
  float s3v[16];
  {
    const float e_gl = __expf(gl);
#pragma unroll
    for (int u = 0; u < 16; ++u) {
      const int t = 16 * wv + u;
      const float pre = goff + (u ? lwv[u - 1] : 0.f);   // g_{t-1}
      const float cur = goff + lwv[u];                   // g_t
      const float kv = bf2f(kv_u[u]), rv = bf2f(rv_u[u]);
      const float vv = vv_u[u];
      const float av = sigmoidf_(p_a0 + bf2f(ar_u[u]));
      const float kkx = kv * p_kk;
      float ssq = kkx * kkx;
#pragma unroll
      for (int m = 1; m < 64; m <<= 1) ssq += __shfl_xor(ssq, m);
      const float scale = __builtin_amdgcn_rsqf(fmaxf(ssq, 1e-24f));
      const float kkn = kkx * scale;
      const float bb = kkn * av;
      const float kmod = kv * (1.0f + (av - 1.0f) * p_ka);
      float s3 = rv * kmod * p_rk;
#pragma unroll
      for (int m = 1; m < 64; m <<= 1) s3 += __shfl_xor(s3, m);
      s3v[u] = s3;
      const float e_prev = __expf(pre);                  // exp(g_{t-1})
      const float e_gu   = __expf(cur);                  // exp(g_t), <= 1
      const float em     = __expf(-cur);                 // exp(-g_t)
      const float egl    = e_gl * em;                    // exp(gl-g_t) <= 1
      AHb[t * RS + jl] = f2bf(-kkn * e_prev);
      BPb[t * RS + jl] = f2bf(bb * em);
      KPb[t * RS + jl] = f2bf(kmod * em);
      BPTb[jl * RS + t] = f2bf(bb * egl);
      KPTb[jl * RS + t] = f2bf(kmod * egl);
      RHb[t * RS + jl] = f2bf(rv * e_gu);
      VSTb[jl * RS + t] = f2bf(vv);
    }
    if (jl == 0) {
      float* sp = s3G + (bh << 10) + (c << 6) + 16 * wv;
#pragma unroll
      for (int k2 = 0; k2 < 4; ++k2)
        *(float4*)(sp + 4 * k2) = make_float4(s3v[4 * k2], s3v[4 * k2 + 1],
                                              s3v[4 * k2 + 2], s3v[4 * k2 + 3]);
    }
  }
  __syncthreads();

  const int fr = lane & 15, q = lane >> 4;
  const int i0 = wv * 16;

  // ---- Gram products via MFMA: LBA, LKA, DBR, DKR(->global) ----
  {
    f32x4 aLB[4], aLK[4], aDB[4], aDK[4];
#pragma unroll
    for (int j = 0; j < 4; ++j) {
      aLB[j] = (f32x4){0.f, 0.f, 0.f, 0.f}; aLK[j] = (f32x4){0.f, 0.f, 0.f, 0.f};
      aDB[j] = (f32x4){0.f, 0.f, 0.f, 0.f}; aDK[j] = (f32x4){0.f, 0.f, 0.f, 0.f};
    }
#pragma unroll
    for (int ks = 0; ks < 2; ++ks) {
      const int ko = ks * 32 + q * 8;
      bf16x8 fA = *(const bf16x8*)(AHb + (i0 + fr) * RS + ko);
      bf16x8 fR = *(const bf16x8*)(RHb + (i0 + fr) * RS + ko);
#pragma unroll
      for (int j = 0; j < 4; ++j) {
        bf16x8 fB = *(const bf16x8*)(BPb + (j * 16 + fr) * RS + ko);
        bf16x8 fK = *(const bf16x8*)(KPb + (j * 16 + fr) * RS + ko);
        aLB[j] = __builtin_amdgcn_mfma_f32_16x16x32_bf16(fA, fB, aLB[j], 0, 0, 0);
        aLK[j] = __builtin_amdgcn_mfma_f32_16x16x32_bf16(fA, fK, aLK[j], 0, 0, 0);
        aDB[j] = __builtin_amdgcn_mfma_f32_16x16x32_bf16(fR, fB, aDB[j], 0, 0, 0);
        aDK[j] = __builtin_amdgcn_mfma_f32_16x16x32_bf16(fR, fK, aDK[j], 0, 0, 0);
      }
    }
    __syncthreads();   // all Gram fragment reads done before overlay stores
#pragma unroll
    for (int j = 0; j < 4; ++j) {
      const int s = j * 16 + fr;
#pragma unroll
      for (int r = 0; r < 4; ++r) {
        const int t = i0 + q * 4 + r;
        LBb[t * LBS + s] = f2bf((s < t) ? aLB[j][r] : 0.f);
        LKb[t * RS + s] = f2bf((s < t) ? aLK[j][r] : 0.f);
        DBb[t * RS + s] = f2bf((s <= t) ? aDB[j][r] : 0.f);
        DkG[(size_t)inst * 4096 + t * 64 + s] = f2bf((s <= t) ? aDK[j][r] : 0.f);
      }
    }
  }
  __syncthreads();

  // ---- W = LKA · V (MFMA, all waves; replaces Y-solve + Qloc) ----
  {
    f32x4 wacc[4];
#pragma unroll
    for (int j = 0; j < 4; ++j) wacc[j] = (f32x4){0.f, 0.f, 0.f, 0.f};
#pragma unroll
    for (int ks = 0; ks < 2; ++ks) {
      const int ko = ks * 32 + q * 8;
      bf16x8 fL = *(const bf16x8*)(LKb + (i0 + fr) * RS + ko);
#pragma unroll
      for (int j = 0; j < 4; ++j) {
        bf16x8 fV = *(const bf16x8*)(VSTb + (j * 16 + fr) * RS + ko);
        wacc[j] = __builtin_amdgcn_mfma_f32_16x16x32_bf16(fL, fV, wacc[j], 0, 0, 0);
      }
    }
#pragma unroll
    for (int j = 0; j < 4; ++j)
#pragma unroll
      for (int r = 0; r < 4; ++r)
        LKb[(i0 + q * 4 + r) * RS + j * 16 + fr] = f2bf(wacc[j][r]);
  }
  __syncthreads();

  // ---- prefetch DKR fragments from global (L2-hot: our own writes) ----
  bf16x8 fDK0, fDK1;
  {
    const unsigned short* dkp = DkG + (size_t)inst * 4096 + (i0 + fr) * 64 + q * 8;
    fDK0 = *(const bf16x8*)(dkp);
    fDK1 = *(const bf16x8*)(dkp + 32);
  }

  // ---- blocked dual triangular solve (barrier-free, intra-wave):
  //      wave0: (I-L)X = Ahat  -> XTb[jc][t];  wave1: (I-L)Q = W -> QTb[jc][t]
  if (wv < 2) {
    const int jc = lane;
    unsigned short* Sb = (wv == 0) ? AHb : LKb;    // RHS (consumed into regs)
    unsigned short* Tb = (wv == 0) ? XTb : QTb;    // col-major solution [jc][t]
    float x[64];
#pragma unroll
    for (int t = 0; t < 64; ++t) x[t] = bf2f(Sb[t * RS + jc]);
    // zero my solution row: bridge MFMAs read 0 for not-yet-solved t
#pragma unroll
    for (int z2 = 0; z2 < 8; ++z2)
      *(bf16x8*)(Tb + jc * RS + z2 * 8) = (bf16x8){0, 0, 0, 0, 0, 0, 0, 0};

    const int jf = jc & 15, tjm = jc >> 4;

#pragma unroll
    for (int I = 0; I < 4; ++I) {
      if (I > 0) {
        // bridge: x[16I+u] += sum_{s<16I} L[16I+u][s] * sol[s][jc]  (MFMA)
        f32x4 cU[4];
#pragma unroll
        for (int tj = 0; tj < 4; ++tj) cU[tj] = (f32x4){0.f, 0.f, 0.f, 0.f};
#pragma unroll
        for (int kw = 0; kw < 2; ++kw) {
          if (kw * 32 < 16 * I) {
            const int ko = kw * 32 + q * 8;
            bf16x8 fL;
            *(ushort4*)&fL = *(const ushort4*)(LBb + (16 * I + fr) * LBS + ko);
            *((ushort4*)&fL + 1) = *(const ushort4*)(LBb + (16 * I + fr) * LBS + ko + 4);
#pragma unroll
            for (int tj = 0; tj < 4; ++tj) {
              bf16x8 fX = *(const bf16x8*)(Tb + (tj * 16 + fr) * RS + ko);
              cU[tj] = __builtin_amdgcn_mfma_f32_16x16x32_bf16(fL, fX, cU[tj], 0, 0, 0);
            }
          }
        }
        // redistribute MFMA C-layout to column-owner lanes
#pragma unroll
        for (int qq = 0; qq < 4; ++qq) {
          const int saddr = (qq * 16 + jf) * 4;
#pragma unroll
          for (int r = 0; r < 4; ++r) {
            int g0 = __builtin_amdgcn_ds_bpermute(saddr, __builtin_bit_cast(int, cU[0][r]));
            int g1 = __builtin_amdgcn_ds_bpermute(saddr, __builtin_bit_cast(int, cU[1][r]));
            int g2 = __builtin_amdgcn_ds_bpermute(saddr, __builtin_bit_cast(int, cU[2][r]));
            int g3 = __builtin_amdgcn_ds_bpermute(saddr, __builtin_bit_cast(int, cU[3][r]));
            int gs = (tjm == 0) ? g0 : (tjm == 1) ? g1 : (tjm == 2) ? g2 : g3;
            x[16 * I + qq * 4 + r] += __builtin_bit_cast(float, gs);
          }
        }
      }
      // diagonal 16x16 unit-lower solve (fp32 chain, bf16 L)
#pragma unroll
      for (int u = 1; u < 16; ++u) {
        const unsigned short* lr = LBb + (16 * I + u) * LBS + 16 * I;
        float acc0 = 0.f, acc1 = 0.f;
#pragma unroll
        for (int s = 0; s + 2 <= u; s += 2) {
          acc0 = fmaf(bf2f(lr[s]), x[16 * I + s], acc0);
          acc1 = fmaf(bf2f(lr[s + 1]), x[16 * I + s + 1], acc1);
        }
        if (u & 1) acc0 = fmaf(bf2f(lr[u - 1]), x[16 * I + u - 1], acc0);
        x[16 * I + u] += acc0 + acc1;
      }
      // store solved block of my column (bf16 pairs)
#pragma unroll
      for (int t2 = 0; t2 < 16; t2 += 2) {
        unsigned int pk = (unsigned int)f2bf(x[16 * I + t2])
                        | ((unsigned int)f2bf(x[16 * I + t2 + 1]) << 16);
        *(unsigned int*)(Tb + jc * RS + 16 * I + t2) = pk;
      }
    }
  }
  __syncthreads();

  // ---- final operators: Mc, Ncc, Pc, Oloc (MFMA) -> global bf16 ----
  {
    f32x4 mA[4], nA[4], pA[4], oA[4];
#pragma unroll
    for (int j = 0; j < 4; ++j) {
      mA[j] = (f32x4){0.f, 0.f, 0.f, 0.f}; nA[j] = (f32x4){0.f, 0.f, 0.f, 0.f};
      pA[j] = (f32x4){0.f, 0.f, 0.f, 0.f}; oA[j] = (f32x4){0.f, 0.f, 0.f, 0.f};
    }
#pragma unroll
    for (int ks = 0; ks < 2; ++ks) {
      const int ko = ks * 32 + q * 8;
      bf16x8 fBT = *(const bf16x8*)(BPTb + (i0 + fr) * RS + ko);
      bf16x8 fKT = *(const bf16x8*)(KPTb + (i0 + fr) * RS + ko);
      bf16x8 fDB = *(const bf16x8*)(DBb + (i0 + fr) * RS + ko);
      bf16x8 fDK = ks ? fDK1 : fDK0;
#pragma unroll
      for (int j = 0; j < 4; ++j) {
        bf16x8 fXT = *(const bf16x8*)(XTb + (j * 16 + fr) * RS + ko);
        bf16x8 fQT = *(const bf16x8*)(QTb + (j * 16 + fr) * RS + ko);
        bf16x8 fVT = *(const bf16x8*)(VSTb + (j * 16 + fr) * RS + ko);
        mA[j] = __builtin_amdgcn_mfma_f32_16x16x32_bf16(fBT, fXT, mA[j], 0, 0, 0);
        nA[j] = __builtin_amdgcn_mfma_f32_16x16x32_bf16(fBT, fQT, nA[j], 0, 0, 0);
        nA[j] = __builtin_amdgcn_mfma_f32_16x16x32_bf16(fKT, fVT, nA[j], 0, 0, 0);
        pA[j] = __builtin_amdgcn_mfma_f32_16x16x32_bf16(fDB, fXT, pA[j], 0, 0, 0);
        oA[j] = __builtin_amdgcn_mfma_f32_16x16x32_bf16(fDB, fQT, oA[j], 0, 0, 0);
        oA[j] = __builtin_amdgcn_mfma_f32_16x16x32_bf16(fDK, fVT, oA[j], 0, 0, 0);
      }
    }
    const size_t ob = (size_t)inst * 4096;
    float eg[4];
#pragma unroll
    for (int r = 0; r < 4; ++r) eg[r] = __expf(GLs[i0 + q * 4 + r]);
#pragma unroll
    for (int j = 0; j < 4; ++j) {
      const int col = j * 16 + fr;
#pragma unroll
      for (int r = 0; r < 4; ++r) {
        const int row = i0 + q * 4 + r;
        const size_t oi = ob + (size_t)row * 64 + col;
        McG[oi] = f2bf(mA[j][r] + (row == col ? eg[r] : 0.f));
        NcG[oi] = f2bf(nA[j][r]);
        PcG[oi] = f2bf(pA[j][r] + bf2f(RHb[row * RS + col]));
        OlG[oi] = f2bf(oA[j][r]);
      }
    }
  }
}

// ---------------------------------------------------------------------------
// Phase 2 (v8, MFMA): sequential chunk-state propagation per (b,h):
// ST' = Mc ST + Ncc, state as ST^T bf16 hi/lo planes in LDS (fp32-class
// recurrence). Sch written TRANSPOSED (SchT[ch][p], packed ushort4) so
// chunk_outgn reads k-contiguous B-fragments directly.
// ---------------------------------------------------------------------------
__global__ __launch_bounds__(256) void chunk_scan_kernel(
    const unsigned short* __restrict__ McG, const unsigned short* __restrict__ NcG,
    unsigned short* __restrict__ SchT)
{
  __shared__ __align__(16) unsigned short STh[64 * RS];  // ST^T hi: [col][row]
  __shared__ __align__(16) unsigned short STl[64 * RS];  // ST^T lo
  const int bh = blockIdx.x;
  const int tid = threadIdx.x;
  const int wv = tid >> 6, lane = tid & 63;
  const int fr = lane & 15, q = lane >> 4;

  f32x4 acc[4];   // state rows [16wv,16wv+16) x cols [16j,16j+16), C-layout

  // ---- c = 0: SchT[0] = 0; acc = Nc[0]; STT not read this chunk ----
  {
    const size_t ob = ((size_t)bh << 4) << 12;
#pragma unroll
    for (int j = 0; j < 4; ++j) {
      const int col = j * 16 + fr;
      *(ushort4*)(SchT + ob + (size_t)col * 64 + wv * 16 + q * 4) =
          make_ushort4(0, 0, 0, 0);
#pragma unroll
      for (int r = 0; r < 4; ++r) {
        const int row = wv * 16 + q * 4 + r;
        acc[j][r] = bf2f(NcG[ob + (size_t)row * 64 + col]);
      }
    }
  }

  for (int c = 1; c < 16; ++c) {
    const size_t ob = ((((size_t)bh << 4) + (size_t)c) << 12);
    // barrier A: prior iteration's B-reads of STT complete before rewrite
    __syncthreads();
    // write prev state (acc) into STT hi/lo; also SchT[c] = bf16(state)^T
#pragma unroll
    for (int j = 0; j < 4; ++j) {
      const int col = j * 16 + fr;
      ushort4 hs, ls;
#pragma unroll
      for (int r = 0; r < 4; ++r) {
        const float v = acc[j][r];
        const unsigned short hi = f2bf(v);
        const unsigned short lo = f2bf(v - bf2f(hi));
        if (r == 0) { hs.x = hi; ls.x = lo; }
        else if (r == 1) { hs.y = hi; ls.y = lo; }
        else if (r == 2) { hs.z = hi; ls.z = lo; }
        else { hs.w = hi; ls.w = lo; }
      }
      *(ushort4*)(STh + col * RS + wv * 16 + q * 4) = hs;
      *(ushort4*)(STl + col * RS + wv * 16 + q * 4) = ls;
      *(ushort4*)(SchT + ob + (size_t)col * 64 + wv * 16 + q * 4) = hs;
    }
    __syncthreads();
    // A-frags: Mc rows (16wv+fr), k-contig (L2-hot global, b128)
    const bf16x8 fA0 = *(const bf16x8*)(McG + ob + (size_t)(wv * 16 + fr) * 64 + q * 8);
    const bf16x8 fA1 = *(const bf16x8*)(McG + ob + (size_t)(wv * 16 + fr) * 64 + 32 + q * 8);
#pragma unroll
    for (int j = 0; j < 4; ++j) {
      const int col = j * 16 + fr;
#pragma unroll
      for (int r = 0; r < 4; ++r)
        acc[j][r] = bf2f(NcG[ob + (size_t)(wv * 16 + q * 4 + r) * 64 + col]);
      const bf16x8 h0 = *(const bf16x8*)(STh + (j * 16 + fr) * RS + q * 8);
      const bf16x8 h1 = *(const bf16x8*)(STh + (j * 16 + fr) * RS + 32 + q * 8);
      const bf16x8 l0 = *(const bf16x8*)(STl + (j * 16 + fr) * RS + q * 8);
      const bf16x8 l1 = *(const bf16x8*)(STl + (j * 16 + fr) * RS + 32 + q * 8);
      acc[j] = __builtin_amdgcn_mfma_f32_16x16x32_bf16(fA0, h0, acc[j], 0, 0, 0);
      acc[j] = __builtin_amdgcn_mfma_f32_16x16x32_bf16(fA1, h1, acc[j], 0, 0, 0);
      acc[j] = __builtin_amdgcn_mfma_f32_16x16x32_bf16(fA0, l0, acc[j], 0, 0, 0);
      acc[j] = __builtin_amdgcn_mfma_f32_16x16x32_bf16(fA1, l1, acc[j], 0, 0, 0);
    }
  }
  // final state (after chunk 15) is not needed downstream — done.
}

// ---------------------------------------------------------------------------
// Phase 3 + GroupNorm fused (v8, MFMA, barrier-free): Out = Pc ST + Oloc via
// 8 MFMAs/wave reading Pc (A, row-contig) and SchT (B, k-contig) straight
// from L2-hot global — no LDS staging, no barriers, no 64-iter VALU loop.
// ---------------------------------------------------------------------------
__global__ __launch_bounds__(256) void chunk_outgn_kernel(
    const unsigned short* __restrict__ PcG, const unsigned short* __restrict__ OlG,
    const unsigned short* __restrict__ SchT, const float* __restrict__ s3G,
    const float* __restrict__ v_btc, const unsigned short* __restrict__ g_f,
    const float* __restrict__ gamma, const float* __restrict__ beta,
    unsigned short* __restrict__ yg)
{
  const int inst = blockIdx.x;
  const int bh = inst >> 4, c = inst & 15;
  const int b = bh >> 4, h = bh & 15;
  const int tid = threadIdx.x;
  const int wv = tid >> 6, lane = tid & 63;
  const int fr = lane & 15, q = lane >> 4;
  const int i0 = wv * 16;
  const size_t ob = (size_t)inst << 12;

  f32x4 acc[4];
#pragma unroll
  for (int j = 0; j < 4; ++j) {
    const int col = j * 16 + fr;
#pragma unroll
    for (int r = 0; r < 4; ++r)
      acc[j][r] = bf2f(OlG[ob + (size_t)(i0 + q * 4 + r) * 64 + col]);
  }
  const bf16x8 fA0 = *(const bf16x8*)(PcG + ob + (size_t)(i0 + fr) * 64 + q * 8);
  const bf16x8 fA1 = *(const bf16x8*)(PcG + ob + (size_t)(i0 + fr) * 64 + 32 + q * 8);
#pragma unroll
  for (int j = 0; j < 4; ++j) {
    const bf16x8 fB0 = *(const bf16x8*)(SchT + ob + (size_t)(j * 16 + fr) * 64 + q * 8);
    const bf16x8 fB1 = *(const bf16x8*)(SchT + ob + (size_t)(j * 16 + fr) * 64 + 32 + q * 8);
    acc[j] = __builtin_amdgcn_mfma_f32_16x16x32_bf16(fA0, fB0, acc[j], 0, 0, 0);
    acc[j] = __builtin_amdgcn_mfma_f32_16x16x32_bf16(fA1, fB1, acc[j], 0, 0, 0);
  }

  const int colb = h * 64;
  float ga[4], be[4];
#pragma unroll
  for (int j = 0; j < 4; ++j) {
    ga[j] = gamma[colb + j * 16 + fr];
    be[j] = beta[colb + j * 16 + fr];
  }

#pragma unroll
  for (int r = 0; r < 4; ++r) {
    float s1 = (acc[0][r] + acc[1][r]) + (acc[2][r] + acc[3][r]);
    float s2 = (acc[0][r] * acc[0][r] + acc[1][r] * acc[1][r])
             + (acc[2][r] * acc[2][r] + acc[3][r] * acc[3][r]);
#pragma unroll
    for (int m = 1; m < 16; m <<= 1) {
      s1 += __shfl_xor(s1, m);
      s2 += __shfl_xor(s2, m);
    }
    const float mean = s1 * (1.0f / 64.0f);
    const float var = s2 * (1.0f / 64.0f) - mean * mean;
    const float rstd = __builtin_amdgcn_rsqf(var + 0.00064f);
    const int row = i0 + q * 4 + r;
    const int tok = c * 64 + row;
    const float s3 = s3G[(bh << 10) + tok];
    const size_t gaddr = ((size_t)(b * 1024 + tok) * 1024) + colb;
#pragma unroll
    for (int j = 0; j < 4; ++j) {
      const int col = j * 16 + fr;
      const float vv = v_btc[gaddr + col];
      const float gg = bf2f(g_f[gaddr + col]);
      yg[gaddr + col] =
          f2bf(((acc[j][r] - mean) * rstd * ga[j] + be[j] + s3 * vv) * gg);
    }
  }
}

// ---------------------------------------------------------------------------
extern "C" void kernel_launch(void* const* d_in, const int* in_sizes, int n_in,
                              void* d_out, int out_size, void* d_ws, size_t ws_size,
                              hipStream_t stream)
{
  (void)in_sizes; (void)n_in; (void)out_size;
  const float* x    = (const float*)d_in[0];
  const float* x_r  = (const float*)d_in[1];
  const float* x_w  = (const float*)d_in[2];
  const float* x_k  = (const float*)d_in[3];
  const float* x_v  = (const float*)d_in[4];
  const float* x_a  = (const float*)d_in[5];
  const float* x_g  = (const float*)d_in[6];
  const float* w0   = (const float*)d_in[7];
  const float* w1   = (const float*)d_in[8];
  const float* w2   = (const float*)d_in[9];
  const float* a0   = (const float*)d_in[10];
  const float* a1   = (const float*)d_in[11];
  const float* a2   = (const float*)d_in[12];
  const float* g1   = (const float*)d_in[16];
  const float* g2   = (const float*)d_in[17];
  const float* k_k  = (const float*)d_in[18];
  const float* k_a  = (const float*)d_in[19];
  const float* r_k  = (const float*)d_in[20];
  const float* Wr   = (const float*)d_in[21];
  const float* Wk   = (const float*)d_in[22];
  const float* Wv   = (const float*)d_in[23];
  const float* Wo   = (const float*)d_in[24];
  const float* ln_g = (const float*)d_in[25];
  const float* ln_b = (const float*)d_in[26];

  float* outp = (float*)d_out;
  float* vfirst = outp + (size_t)BB * TT * CCH;

  char* ws = (char*)d_ws;
  size_t off = 0;
  auto alloc = [&](size_t bytes) -> char* {
    char* p = ws + off;
    off += (bytes + 255) & ~(size_t)255;
    return p;
  };

  unsigned short* WrT = (unsigned short*)alloc(2097152);
  unsigned short* WkT = (unsigned short*)alloc(2097152);
  unsigned short* WvT = (unsigned short*)alloc(2097152);
  unsigned short* WoT = (unsigned short*)alloc(2097152);
  unsigned short* w1T = (unsigned short*)alloc(131072);
  unsigned short* w2T = (unsigned short*)alloc(131072);
  unsigned short* a1T = (unsigned short*)alloc(131072);
  unsigned short* a2T = (unsigned short*)alloc(131072);
  unsigned short* g1T = (unsigned short*)alloc(262144);
  unsigned short* g2T = (unsigned short*)alloc(262144);
  unsigned short* xrB = (unsigned short*)alloc(8388608);
  unsigned short* xwB = (unsigned short*)alloc(8388608);
  unsigned short* xkB = (unsigned short*)alloc(8388608);
  unsigned short* xvB = (unsigned short*)alloc(8388608);
  unsigned short* xaB = (unsigned short*)alloc(8388608);
  unsigned short* xgB = (unsigned short*)alloc(8388608);
  unsigned short* r_btc = (unsigned short*)alloc(8388608);
  unsigned short* k_btc = (unsigned short*)alloc(8388608);
  unsigned short* wraw  = (unsigned short*)alloc(8388608);
  unsigned short* araw  = (unsigned short*)alloc(8388608);
  unsigned short* gfB = (unsigned short*)alloc(8388608);
  unsigned short* OlG = (unsigned short*)alloc(8388608);
  unsigned short* DkG = (unsigned short*)alloc(8388608);
  float* s3G   = (float*)alloc(262144);
  unsigned short* hwB = (unsigned short*)alloc(524288);
  unsigned short* haB = (unsigned short*)alloc(524288);
  unsigned short* hgB = (unsigned short*)alloc(1048576);
  unsigned short* ygB = (unsigned short*)alloc(8388608);

  // overlays (owners dead before the writer runs)
  unsigned short* McG = xrB;          // over xrB (dead after gemm_stage1)
  unsigned short* NcG = xkB;          // over xkB
  unsigned short* PcG = xaB;          // over xaB
  unsigned short* Sch = k_btc;        // k_btc dead after chunk_ops (SchT layout)

  if (off > ws_size) return;

  dim3 blk(256);

  // transposes + mix in one launch
  prep_kernel<<<5248, blk, 0, stream>>>(
      x, x_r, x_w, x_k, x_v, x_a, x_g,
      xrB, xwB, xkB, xvB, xaB, xgB,
      Wr, Wk, Wv, Wo, WrT, WkT, WvT, WoT,
      w1, w2, a1, a2, g1, g2, w1T, w2T, a1T, a2T, g1T, g2T);

  // r/k/v GEMMs (128x64 tiles, 1536 blocks) + lora1; v into vfirst
  gemm_stage1_kernel<<<1664, blk, 0, stream>>>(
      xrB, xkB, xvB, WrT, WkT, WvT, r_btc, k_btc, vfirst,
      xwB, xaB, xgB, w1T, a1T, g1T, hwB, haB, hgB);

  // LoRA stage 2 (w/a/g) in one launch
  lora2_kernel<<<dim3(32, 8, 3), blk, 0, stream>>>(
      hwB, haB, hgB, w2T, a2T, g2T, wraw, araw, gfB);

  // chunked-DPLR scan phase 1 (postproc fused, 2 blocks/CU)
  constexpr int CHUNK_LDS = 7 * 64 * RS * 2 + 64 * LBS * 2 + 64 * 4 + 4 * 64 * 4;
  hipFuncSetAttribute((const void*)chunk_ops_kernel,
                      hipFuncAttributeMaxDynamicSharedMemorySize, CHUNK_LDS);
  chunk_ops_kernel<<<1024, blk, CHUNK_LDS, stream>>>(
      r_btc, k_btc, vfirst, wraw, araw, w0, a0, k_k, k_a, r_k,
      McG, NcG, PcG, OlG, DkG, s3G);

  chunk_scan_kernel<<<64, blk, 0, stream>>>(McG, NcG, Sch);

  chunk_outgn_kernel<<<1024, blk, 0, stream>>>(PcG, OlG, Sch, s3G, vfirst, gfB,
                                               ln_g, ln_b, ygB);

  gemm_out_kernel<<<dim3(32, 8), blk, 0, stream>>>(ygB, WoT, outp);
}